// Round 2
// baseline (662.728 us; speedup 1.0000x reference)
//
#include <hip/hip_runtime.h>
#include <cstdint>

// ---------- types & helpers ----------
typedef unsigned short u16;
typedef __bf16 bf16x8 __attribute__((ext_vector_type(8)));
typedef float  f32x4  __attribute__((ext_vector_type(4)));

struct alignas(16) F4 { float v[4]; };
struct alignas(8)  U4 { u16 v[4]; };
struct alignas(16) U8 { u16 v[8]; };

__device__ __forceinline__ u16 f2bf(float f) {
    union { float f; unsigned int u; } x; x.f = f;
    unsigned int r = x.u + 0x7fffu + ((x.u >> 16) & 1u);   // RNE
    return (u16)(r >> 16);
}
__device__ __forceinline__ float bf2f(u16 u) {
    union { unsigned int u; float f; } x; x.u = ((unsigned int)u) << 16;
    return x.f;
}
__device__ __forceinline__ f32x4 mfma16(bf16x8 a, bf16x8 b, f32x4 c) {
    return __builtin_amdgcn_mfma_f32_16x16x32_bf16(a, b, c, 0, 0, 0);
}
// async global->LDS, 16B per lane, dest = wave-uniform base + lane*16
__device__ __forceinline__ void gload_lds16(const void* g, void* l) {
    auto* gp = reinterpret_cast<const __attribute__((address_space(1))) unsigned int*>(
        reinterpret_cast<uintptr_t>(g));
    auto* lp = reinterpret_cast<__attribute__((address_space(3))) unsigned int*>(
        reinterpret_cast<uintptr_t>(l));
    __builtin_amdgcn_global_load_lds(gp, lp, 16, 0, 0);
}

// ---------- generic f32 -> bf16 cast (vector) ----------
__global__ __launch_bounds__(256) void cast_bf16_k(const float* __restrict__ in,
                                                   u16* __restrict__ out, int n4) {
    int i = blockIdx.x * 256 + threadIdx.x;
    if (i >= n4) return;
    F4 v = *(const F4*)(in + (size_t)i * 4);
    U4 o;
    #pragma unroll
    for (int j = 0; j < 4; ++j) o.v[j] = f2bf(v.v[j]);
    *(U4*)(out + (size_t)i * 4) = o;
}

// ---------- LayerNorm (C=1024), f32 in -> bf16 out ----------
__global__ __launch_bounds__(256) void ln_fwd_k(const float* __restrict__ x,
                                                const float* __restrict__ w,
                                                const float* __restrict__ b,
                                                u16* __restrict__ h) {
    const int row = blockIdx.x, tid = threadIdx.x;
    const float* xr = x + (size_t)row * 1024;
    F4 v = *(const F4*)(xr + tid * 4);
    float s  = v.v[0] + v.v[1] + v.v[2] + v.v[3];
    float ss = v.v[0]*v.v[0] + v.v[1]*v.v[1] + v.v[2]*v.v[2] + v.v[3]*v.v[3];
    #pragma unroll
    for (int o = 32; o > 0; o >>= 1) { s += __shfl_down(s, o); ss += __shfl_down(ss, o); }
    __shared__ float red[8];
    const int wave = tid >> 6, lane = tid & 63;
    if (lane == 0) { red[wave] = s; red[4 + wave] = ss; }
    __syncthreads();
    s  = red[0] + red[1] + red[2] + red[3];
    ss = red[4] + red[5] + red[6] + red[7];
    const float mu   = s * (1.0f / 1024.0f);
    const float var  = ss * (1.0f / 1024.0f) - mu * mu;
    const float rstd = rsqrtf(var + 1e-5f);
    U4 o;
    #pragma unroll
    for (int j = 0; j < 4; ++j)
        o.v[j] = f2bf((v.v[j] - mu) * rstd * w[tid * 4 + j] + b[tid * 4 + j]);
    *(U4*)(h + (size_t)row * 1024 + tid * 4) = o;
}

// ---------- GEMM: C[M,N] = A[M,K] * B[N,K]^T (both bf16 row-major, K-contiguous) ----------
// m97 structure: 128x128 tile, BK=32, 4 waves (2x2), 4x4 16x16 frags/wave, global_load_lds.
// MODE 0: store bf16 to Cout.  MODE 1: store f32 (resid[row,col] + acc) to Cout.
template <int MODE>
__global__ __launch_bounds__(256) void gemm_bt_k(const u16* __restrict__ A,
                                                 const u16* __restrict__ Bm,
                                                 void* __restrict__ Cout,
                                                 const float* __restrict__ resid,
                                                 int M, int N, int K) {
    __shared__ u16 Alds[128 * 32];
    __shared__ u16 Blds[128 * 32];
    const int tid  = threadIdx.x;
    const int lane = tid & 63, wave = tid >> 6;
    const int wr = wave >> 1, wc = wave & 1;
    const int r16 = lane & 15, g16 = lane >> 4;
    const int bn = blockIdx.x, bm = blockIdx.y;

    const int srow = lane >> 2;          // 0..15 within 16-row chunk
    const int scol = (lane & 3) * 8;     // 0,8,16,24

    f32x4 acc[4][4] = {};

    for (int k0 = 0; k0 < K; k0 += 32) {
        #pragma unroll
        for (int c = 0; c < 2; ++c) {
            const int ch = wave * 2 + c;                    // 0..7 (16 rows each)
            const u16* ga = A  + ((size_t)bm * 128 + ch * 16 + srow) * K + k0 + scol;
            gload_lds16(ga, &Alds[ch * 512]);
            const u16* gb = Bm + ((size_t)bn * 128 + ch * 16 + srow) * K + k0 + scol;
            gload_lds16(gb, &Blds[ch * 512]);
        }
        __syncthreads();
        bf16x8 af[4], bfr[4];
        #pragma unroll
        for (int m = 0; m < 4; ++m)
            af[m] = *(const bf16x8*)&Alds[(wr * 64 + m * 16 + r16) * 32 + g16 * 8];
        #pragma unroll
        for (int n = 0; n < 4; ++n)
            bfr[n] = *(const bf16x8*)&Blds[(wc * 64 + n * 16 + r16) * 32 + g16 * 8];
        #pragma unroll
        for (int m = 0; m < 4; ++m)
            #pragma unroll
            for (int n = 0; n < 4; ++n)
                acc[m][n] = mfma16(af[m], bfr[n], acc[m][n]);
        __syncthreads();
    }

    #pragma unroll
    for (int m = 0; m < 4; ++m) {
        #pragma unroll
        for (int n = 0; n < 4; ++n) {
            #pragma unroll
            for (int r = 0; r < 4; ++r) {
                const int row = bm * 128 + wr * 64 + m * 16 + g16 * 4 + r;
                const int col = bn * 128 + wc * 64 + n * 16 + r16;
                const float v = acc[m][n][r];
                if (MODE == 0) {
                    ((u16*)Cout)[(size_t)row * N + col] = f2bf(v);
                } else {
                    ((float*)Cout)[(size_t)row * N + col] =
                        resid[(size_t)row * N + col] + v;
                }
            }
        }
    }
}

// ---------- flash attention (causal), transpose-world, LDS-free / sync-free ----------
// qk: [4096][2048] bf16 (Q cols 0..1023, K cols 1024..2047)
// vt: [1024][4096] bf16 = V^T (row = h*64+d, col = b*2048+kv)
// Ob: [4096][1024] bf16 attention output
// grid = 1024 blocks, 4 waves; wave owns 16 q-rows. KV step = 32.
// S^T = mfma(K, Q): lane holds S[kv=kv0+16t+4*g16+r][q=r16] -> row softmax is
// in-lane (8 vals) + shfl_xor(16,32). P stays in registers; PV is
// O^T += mfma(V^T-frag, P-frag) with k-slot order {4g..4g+3, 16+4g..16+4g+3}.
__global__ __launch_bounds__(256) void attn_fwd_k(const u16* __restrict__ qk,
                                                  const u16* __restrict__ vt,
                                                  u16* __restrict__ Ob) {
    const int tid  = threadIdx.x;
    const int wave = tid >> 6, lane = tid & 63;
    const int r16  = lane & 15, g16 = lane >> 4;

    // XCD-chunk swizzle: 8 chunks of 128 blocks = 4 whole heads per XCD L2.
    // Descending qb inside chunk -> long (late-causal) blocks dispatch first.
    const int blk = blockIdx.x;
    const int swz = (blk & 7) * 128 + (blk >> 3);
    const int bh  = swz >> 5;            // 0..31 = b*16+h
    const int qb  = 31 - (swz & 31);     // 0..31
    const int h   = bh & 15, b = bh >> 4;

    const int q0w = qb * 64 + wave * 16;          // wave's first q row
    const size_t seqb = (size_t)b * 2048;

    // Q B-frag: lane holds Q[q=q0w+r16][k-slice g16*8 .. +7] (+32 for hi half)
    const u16* qp = qk + (seqb + q0w + r16) * 2048 + h * 64 + g16 * 8;
    const bf16x8 qf0 = *(const bf16x8*)qp;
    const bf16x8 qf1 = *(const bf16x8*)(qp + 32);

    f32x4 o[4] = {};                   // o[t]: O^T[d=16t+4*g16+r][q=r16]
    float mreg = -3.0e38f, lreg = 0.0f;

    const u16* kbase = qk + seqb * 2048 + 1024 + (size_t)h * 64;
    const u16* vbase = vt + (size_t)(h * 64) * 4096 + seqb;

    const int steps = (q0w + 47) >> 5;            // ceil((q0w+16)/32)
    constexpr float SC = 0.125f * 1.44269504088896341f;  // Dh^-0.5 * log2(e)

    for (int it = 0; it < steps; ++it) {
        const int kv0 = it << 5;

        // K A-frags: lane holds K[kv=kv0+16*tile+r16][k-slice g16*8 (+32)]
        const u16* kp0 = kbase + (size_t)(kv0 + r16) * 2048 + g16 * 8;
        const u16* kp1 = kp0 + (size_t)16 * 2048;
        bf16x8 k00 = *(const bf16x8*)(kp0);
        bf16x8 k01 = *(const bf16x8*)(kp0 + 32);
        bf16x8 k10 = *(const bf16x8*)(kp1);
        bf16x8 k11 = *(const bf16x8*)(kp1 + 32);

        // V^T frags, issued early so latency hides under QK^T + softmax.
        // A-frag k-slot j for lane g16: kv = kv0 + 4*g16 + j (j<4), 16+4*g16+j-4 (j>=4)
        U4 vl[4], vh[4];
        #pragma unroll
        for (int t = 0; t < 4; ++t) {
            const u16* vp = vbase + (size_t)(16 * t + r16) * 4096 + kv0 + 4 * g16;
            vl[t] = *(const U4*)vp;
            vh[t] = *(const U4*)(vp + 16);
        }

        f32x4 s0 = {0.f, 0.f, 0.f, 0.f}, s1 = {0.f, 0.f, 0.f, 0.f};
        s0 = mfma16(k00, qf0, s0);
        s0 = mfma16(k01, qf1, s0);
        s1 = mfma16(k10, qf0, s1);
        s1 = mfma16(k11, qf1, s1);
        // s_t[r] = S[kv=kv0+16t+4*g16+r][q=q0w+r16]

        float a[8];
        #pragma unroll
        for (int r = 0; r < 4; ++r) { a[r] = s0[r] * SC; a[4 + r] = s1[r] * SC; }

        if (kv0 + 31 > q0w) {                      // wave-uniform mask branch
            const int qg = q0w + r16;
            #pragma unroll
            for (int r = 0; r < 4; ++r) {
                if (kv0 + 4 * g16 + r      > qg) a[r]     = -1.0e30f;
                if (kv0 + 16 + 4 * g16 + r > qg) a[4 + r] = -1.0e30f;
            }
        }

        float mx = fmaxf(fmaxf(fmaxf(a[0], a[1]), fmaxf(a[2], a[3])),
                         fmaxf(fmaxf(a[4], a[5]), fmaxf(a[6], a[7])));
        mx = fmaxf(mx, __shfl_xor(mx, 16));
        mx = fmaxf(mx, __shfl_xor(mx, 32));
        const float mn = fmaxf(mreg, mx);
        const float al = exp2f(mreg - mn);
        float p[8], rs = 0.0f;
        #pragma unroll
        for (int j = 0; j < 8; ++j) { p[j] = exp2f(a[j] - mn); rs += p[j]; }
        rs += __shfl_xor(rs, 16);
        rs += __shfl_xor(rs, 32);
        lreg = lreg * al + rs;
        mreg = mn;

        bf16x8 pf;
        #pragma unroll
        for (int j = 0; j < 8; ++j) pf[j] = (__bf16)p[j];

        #pragma unroll
        for (int t = 0; t < 4; ++t) {
            #pragma unroll
            for (int r = 0; r < 4; ++r) o[t][r] *= al;
            bf16x8 vf;
            #pragma unroll
            for (int j = 0; j < 4; ++j) {
                vf[j]     = ((const __bf16*)&vl[t])[j];
                vf[4 + j] = ((const __bf16*)&vh[t])[j];
            }
            o[t] = mfma16(vf, pf, o[t]);
        }
    }

    const float inv = 1.0f / lreg;
    u16* op = Ob + (seqb + q0w + r16) * 1024 + h * 64 + 4 * g16;
    #pragma unroll
    for (int t = 0; t < 4; ++t) {
        U4 st;
        #pragma unroll
        for (int r = 0; r < 4; ++r) st.v[r] = f2bf(o[t][r] * inv);
        *(U4*)(op + 16 * t) = st;
    }
}

// ---------- SwiGLU elementwise: out = silu(a) * g (bf16) ----------
__global__ __launch_bounds__(256) void swiglu_k(const u16* __restrict__ a,
                                                const u16* __restrict__ g,
                                                u16* __restrict__ o, int n8) {
    int i = blockIdx.x * 256 + threadIdx.x;
    if (i >= n8) return;
    U8 av = *(const U8*)(a + (size_t)i * 8);
    U8 gv = *(const U8*)(g + (size_t)i * 8);
    U8 ov;
    #pragma unroll
    for (int j = 0; j < 8; ++j) {
        const float fa = bf2f(av.v[j]);
        const float fg = bf2f(gv.v[j]);
        const float s  = fa / (1.0f + __expf(-fa));
        ov.v[j] = f2bf(s * fg);
    }
    *(U8*)(o + (size_t)i * 8) = ov;
}

// ---------- launch ----------
extern "C" void kernel_launch(void* const* d_in, const int* in_sizes, int n_in,
                              void* d_out, int out_size, void* d_ws, size_t ws_size,
                              hipStream_t stream) {
    (void)in_sizes; (void)n_in; (void)out_size; (void)ws_size;
    constexpr int C = 1024, FF = 4096, M = 2 * 2048;   // B*T = 4096

    const float* x      = (const float*)d_in[0];
    const float* ln1_w  = (const float*)d_in[1];
    const float* ln1_b  = (const float*)d_in[2];
    const float* qkv_w  = (const float*)d_in[3];
    const float* atto_w = (const float*)d_in[4];
    const float* ln2_w  = (const float*)d_in[5];
    const float* ln2_b  = (const float*)d_in[6];
    const float* mlpi_w = (const float*)d_in[7];
    const float* mlpg_w = (const float*)d_in[8];
    const float* mlpo_w = (const float*)d_in[9];
    float* out = (float*)d_out;

    char* ws = (char*)d_ws;
    size_t off = 0;
    auto alloc = [&](size_t bytes) {
        char* p = ws + off;
        off += (bytes + 255) & ~(size_t)255;
        return p;
    };
    u16*   wq   = (u16*)  alloc((size_t)3 * C * C * 2);   // qkv_w bf16 (rows: Q,K then V)
    u16*   wo   = (u16*)  alloc((size_t)C * C * 2);
    u16*   wi   = (u16*)  alloc((size_t)FF * C * 2);
    u16*   wg   = (u16*)  alloc((size_t)FF * C * 2);
    u16*   wm   = (u16*)  alloc((size_t)C * FF * 2);
    u16*   h1   = (u16*)  alloc((size_t)M * C * 2);
    u16*   qk_b = (u16*)  alloc((size_t)M * 2 * C * 2);   // [4096][2048] Q|K
    u16*   vt_b = (u16*)  alloc((size_t)C * M * 2);       // [1024][4096] V^T
    u16*   Ob   = (u16*)  alloc((size_t)M * C * 2);
    float* x1   = (float*)alloc((size_t)M * C * 4);
    u16*   h2   = (u16*)  alloc((size_t)M * C * 2);
    u16*   ab   = (u16*)  alloc((size_t)M * FF * 2);
    u16*   gb   = (u16*)  alloc((size_t)M * FF * 2);

    // weight casts (f32 -> bf16)
    cast_bf16_k<<<(3 * C * C / 4) / 256, 256, 0, stream>>>(qkv_w, wq, 3 * C * C / 4);
    cast_bf16_k<<<(C * C / 4) / 256, 256, 0, stream>>>(atto_w, wo, C * C / 4);
    cast_bf16_k<<<(FF * C / 4) / 256, 256, 0, stream>>>(mlpi_w, wi, FF * C / 4);
    cast_bf16_k<<<(FF * C / 4) / 256, 256, 0, stream>>>(mlpg_w, wg, FF * C / 4);
    cast_bf16_k<<<(C * FF / 4) / 256, 256, 0, stream>>>(mlpo_w, wm, C * FF / 4);

    // attention branch
    ln_fwd_k<<<M, 256, 0, stream>>>(x, ln1_w, ln1_b, h1);
    // Q|K = h1 @ Wqk^T  -> [4096][2048]
    gemm_bt_k<0><<<dim3(2 * C / 128, M / 128), 256, 0, stream>>>(h1, wq, qk_b, nullptr, M, 2 * C, C);
    // V^T = Wv @ h1^T   -> [1024][4096]   (Wv = rows 2C..3C of qkv_w)
    const u16* wv = wq + (size_t)2 * C * C;
    gemm_bt_k<0><<<dim3(M / 128, C / 128), 256, 0, stream>>>(wv, h1, vt_b, nullptr, C, M, C);
    attn_fwd_k<<<1024, 256, 0, stream>>>(qk_b, vt_b, Ob);
    gemm_bt_k<1><<<dim3(C / 128, M / 128), 256, 0, stream>>>(Ob, wo, x1, x, M, C, C);

    // MLP branch
    ln_fwd_k<<<M, 256, 0, stream>>>(x1, ln2_w, ln2_b, h2);
    gemm_bt_k<0><<<dim3(FF / 128, M / 128), 256, 0, stream>>>(h2, wi, ab, nullptr, M, FF, C);
    gemm_bt_k<0><<<dim3(FF / 128, M / 128), 256, 0, stream>>>(h2, wg, gb, nullptr, M, FF, C);
    swiglu_k<<<(M * FF / 8) / 256, 256, 0, stream>>>(ab, gb, ab, M * FF / 8);
    gemm_bt_k<1><<<dim3(C / 128, M / 128), 256, 0, stream>>>(ab, wm, out, x1, M, C, FF);
}

// Round 3
// 395.101 us; speedup vs baseline: 1.6774x; 1.6774x over previous
//
#include <hip/hip_runtime.h>
#include <cstdint>

// ---------- types & helpers ----------
typedef unsigned short u16;
typedef __bf16 bf16x8 __attribute__((ext_vector_type(8)));
typedef float  f32x4  __attribute__((ext_vector_type(4)));

struct alignas(16) F4 { float v[4]; };
struct alignas(8)  U4 { u16 v[4]; };
struct alignas(16) U8 { u16 v[8]; };

__device__ __forceinline__ u16 f2bf(float f) {
    union { float f; unsigned int u; } x; x.f = f;
    unsigned int r = x.u + 0x7fffu + ((x.u >> 16) & 1u);   // RNE
    return (u16)(r >> 16);
}
__device__ __forceinline__ float bf2f(u16 u) {
    union { unsigned int u; float f; } x; x.u = ((unsigned int)u) << 16;
    return x.f;
}
__device__ __forceinline__ f32x4 mfma16(bf16x8 a, bf16x8 b, f32x4 c) {
    return __builtin_amdgcn_mfma_f32_16x16x32_bf16(a, b, c, 0, 0, 0);
}
// async global->LDS, 16B per lane, dest = wave-uniform base + lane*16
__device__ __forceinline__ void gload_lds16(const void* g, void* l) {
    auto* gp = reinterpret_cast<const __attribute__((address_space(1))) unsigned int*>(
        reinterpret_cast<uintptr_t>(g));
    auto* lp = reinterpret_cast<__attribute__((address_space(3))) unsigned int*>(
        reinterpret_cast<uintptr_t>(l));
    __builtin_amdgcn_global_load_lds(gp, lp, 16, 0, 0);
}

// ---------- generic f32 -> bf16 cast (vector) ----------
__global__ __launch_bounds__(256) void cast_bf16_k(const float* __restrict__ in,
                                                   u16* __restrict__ out, int n4) {
    int i = blockIdx.x * 256 + threadIdx.x;
    if (i >= n4) return;
    F4 v = *(const F4*)(in + (size_t)i * 4);
    U4 o;
    #pragma unroll
    for (int j = 0; j < 4; ++j) o.v[j] = f2bf(v.v[j]);
    *(U4*)(out + (size_t)i * 4) = o;
}

// ---------- LayerNorm (C=1024), f32 in -> bf16 out ----------
__global__ __launch_bounds__(256) void ln_fwd_k(const float* __restrict__ x,
                                                const float* __restrict__ w,
                                                const float* __restrict__ b,
                                                u16* __restrict__ h) {
    const int row = blockIdx.x, tid = threadIdx.x;
    const float* xr = x + (size_t)row * 1024;
    F4 v = *(const F4*)(xr + tid * 4);
    float s  = v.v[0] + v.v[1] + v.v[2] + v.v[3];
    float ss = v.v[0]*v.v[0] + v.v[1]*v.v[1] + v.v[2]*v.v[2] + v.v[3]*v.v[3];
    #pragma unroll
    for (int o = 32; o > 0; o >>= 1) { s += __shfl_down(s, o); ss += __shfl_down(ss, o); }
    __shared__ float red[8];
    const int wave = tid >> 6, lane = tid & 63;
    if (lane == 0) { red[wave] = s; red[4 + wave] = ss; }
    __syncthreads();
    s  = red[0] + red[1] + red[2] + red[3];
    ss = red[4] + red[5] + red[6] + red[7];
    const float mu   = s * (1.0f / 1024.0f);
    const float var  = ss * (1.0f / 1024.0f) - mu * mu;
    const float rstd = rsqrtf(var + 1e-5f);
    U4 o;
    #pragma unroll
    for (int j = 0; j < 4; ++j)
        o.v[j] = f2bf((v.v[j] - mu) * rstd * w[tid * 4 + j] + b[tid * 4 + j]);
    *(U4*)(h + (size_t)row * 1024 + tid * 4) = o;
}

// ---------- GEMM: C[M,N] = A[M,K] * B[N,K]^T (both bf16 row-major, K-contiguous) ----------
// m97 structure: 128x128 tile, BK=32, 4 waves (2x2), 4x4 16x16 frags/wave, global_load_lds.
// MODE 0: store bf16 to Cout.  MODE 1: store f32 (resid[row,col] + acc) to Cout.
template <int MODE>
__global__ __launch_bounds__(256) void gemm_bt_k(const u16* __restrict__ A,
                                                 const u16* __restrict__ Bm,
                                                 void* __restrict__ Cout,
                                                 const float* __restrict__ resid,
                                                 int M, int N, int K) {
    __shared__ u16 Alds[128 * 32];
    __shared__ u16 Blds[128 * 32];
    const int tid  = threadIdx.x;
    const int lane = tid & 63, wave = tid >> 6;
    const int wr = wave >> 1, wc = wave & 1;
    const int r16 = lane & 15, g16 = lane >> 4;
    const int bn = blockIdx.x, bm = blockIdx.y;

    const int srow = lane >> 2;          // 0..15 within 16-row chunk
    const int scol = (lane & 3) * 8;     // 0,8,16,24

    f32x4 acc[4][4] = {};

    for (int k0 = 0; k0 < K; k0 += 32) {
        #pragma unroll
        for (int c = 0; c < 2; ++c) {
            const int ch = wave * 2 + c;                    // 0..7 (16 rows each)
            const u16* ga = A  + ((size_t)bm * 128 + ch * 16 + srow) * K + k0 + scol;
            gload_lds16(ga, &Alds[ch * 512]);
            const u16* gb = Bm + ((size_t)bn * 128 + ch * 16 + srow) * K + k0 + scol;
            gload_lds16(gb, &Blds[ch * 512]);
        }
        __syncthreads();
        bf16x8 af[4], bfr[4];
        #pragma unroll
        for (int m = 0; m < 4; ++m)
            af[m] = *(const bf16x8*)&Alds[(wr * 64 + m * 16 + r16) * 32 + g16 * 8];
        #pragma unroll
        for (int n = 0; n < 4; ++n)
            bfr[n] = *(const bf16x8*)&Blds[(wc * 64 + n * 16 + r16) * 32 + g16 * 8];
        #pragma unroll
        for (int m = 0; m < 4; ++m)
            #pragma unroll
            for (int n = 0; n < 4; ++n)
                acc[m][n] = mfma16(af[m], bfr[n], acc[m][n]);
        __syncthreads();
    }

    #pragma unroll
    for (int m = 0; m < 4; ++m) {
        #pragma unroll
        for (int n = 0; n < 4; ++n) {
            #pragma unroll
            for (int r = 0; r < 4; ++r) {
                const int row = bm * 128 + wr * 64 + m * 16 + g16 * 4 + r;
                const int col = bn * 128 + wc * 64 + n * 16 + r16;
                const float v = acc[m][n][r];
                if (MODE == 0) {
                    ((u16*)Cout)[(size_t)row * N + col] = f2bf(v);
                } else {
                    ((float*)Cout)[(size_t)row * N + col] =
                        resid[(size_t)row * N + col] + v;
                }
            }
        }
    }
}

// ---------- flash attention v3 (causal), transpose-world + LDS-staged K/V ----------
// qk: [4096][2048] bf16 (Q cols 0..1023, K cols 1024..2047)
// vt: [1024][4096] bf16 = V^T (row = h*64+d, col = b*2048+kv)
// Ob: [4096][1024] bf16
// grid = 1024 blocks x 256 thr. 4 waves share LDS K/V tiles (KVBLK=64, dbuf,
// XOR-swizzled 16B chunks: lds_chunk = glob_chunk ^ (row&7)). Wave owns 16 q rows.
// S^T = mfma(K,Q) -> lane holds 16 scores for q=r16; softmax fully in-register.
__global__ __launch_bounds__(256) void attn_fwd_k(const u16* __restrict__ qk,
                                                  const u16* __restrict__ vt,
                                                  u16* __restrict__ Ob) {
    __shared__ u16 Klds[2][64 * 64];
    __shared__ u16 Vlds[2][64 * 64];

    const int tid  = threadIdx.x;
    const int wave = tid >> 6, lane = tid & 63;
    const int r16  = lane & 15, g16 = lane >> 4;

    // XCD swizzle + per-CU qb balance: chunk pc=0..127 per XCD; 4 heads/XCD;
    // qb = (31-(pc&31)+8*(pc>>5))&31 so a CU's 4 blocks get qb {v,v+8,v+16,v+24}.
    const int blk = blockIdx.x;
    const int xcd = blk & 7;
    const int pc  = blk >> 3;
    const int hh  = pc >> 5;
    const int qb  = (31 - (pc & 31) + 8 * hh) & 31;
    const int bh  = xcd * 4 + hh;
    const int h   = bh & 15, b = bh >> 4;

    const int q0w = qb * 64 + wave * 16;
    const size_t seqb = (size_t)b * 2048;

    // Q B-frag (registers, once)
    const u16* qp = qk + (seqb + q0w + r16) * 2048 + h * 64 + g16 * 8;
    const bf16x8 qf0 = *(const bf16x8*)qp;
    const bf16x8 qf1 = *(const bf16x8*)(qp + 32);

    const u16* kbase = qk + seqb * 2048 + 1024 + (size_t)h * 64;
    const u16* vbase = vt + (size_t)(h * 64) * 4096 + seqb;

    // staging source (pre-swizzled): lane covers rows {srow, srow+32}, 16B chunk
    const int srow  = tid >> 3;                           // 0..31
    const int scol8 = ((tid & 7) ^ (srow & 7)) * 8;       // u16 offset within row
    const u16* ksrc = kbase + (size_t)srow * 2048 + scol8;
    const u16* vsrc = vbase + (size_t)srow * 4096 + scol8;

    auto stage = [&](int bufi, int kv0) {
        const u16* kp = ksrc + (size_t)kv0 * 2048;
        const u16* vp = vsrc + kv0;
        u16* kd = &Klds[bufi][wave * 512];
        u16* vd = &Vlds[bufi][wave * 512];
        gload_lds16(kp, kd);
        gload_lds16(kp + (size_t)32 * 2048, kd + 2048);
        gload_lds16(vp, vd);
        gload_lds16(vp + (size_t)32 * 4096, vd + 2048);
    };

    f32x4 o[4] = {};
    float mreg = -3.0e38f, lreg = 0.0f;
    constexpr float SC = 0.125f * 1.44269504088896341f;   // Dh^-0.5 * log2(e)

    const int nt = qb + 1;                                 // 64-kv tiles
    stage(0, 0);
    asm volatile("s_waitcnt vmcnt(0)" ::: "memory");
    __builtin_amdgcn_s_barrier();

    for (int it = 0; it < nt; ++it) {
        const int kv0 = it * 64;
        const int cur = it & 1;
        if (it + 1 < nt) stage(cur ^ 1, kv0 + 64);

        const u16* K = Klds[cur];
        const u16* V = Vlds[cur];

        // ---- S^T tiles: s[t][r] = S[kv0+16t+4*g16+r][q0w+r16] ----
        f32x4 s[4];
        #pragma unroll
        for (int t = 0; t < 4; ++t) {
            const int row = 16 * t + r16;
            const int sw  = row & 7;
            const bf16x8 k0 = *(const bf16x8*)&K[row * 64 + ((g16 ^ sw) * 8)];
            const bf16x8 k1 = *(const bf16x8*)&K[row * 64 + (((g16 + 4) ^ sw) * 8)];
            f32x4 acc = {0.f, 0.f, 0.f, 0.f};
            acc = mfma16(k0, qf0, acc);
            acc = mfma16(k1, qf1, acc);
            s[t] = acc;
        }

        // ---- online softmax over 16 in-lane values ----
        float a[16];
        #pragma unroll
        for (int t = 0; t < 4; ++t)
            #pragma unroll
            for (int r = 0; r < 4; ++r) a[4 * t + r] = s[t][r] * SC;

        if (kv0 + 63 > q0w) {                      // wave-uniform causal branch
            const int qg = q0w + r16;
            #pragma unroll
            for (int t = 0; t < 4; ++t)
                #pragma unroll
                for (int r = 0; r < 4; ++r)
                    if (kv0 + 16 * t + 4 * g16 + r > qg) a[4 * t + r] = -1.0e30f;
        }

        float mx = a[0];
        #pragma unroll
        for (int j = 1; j < 16; ++j) mx = fmaxf(mx, a[j]);
        mx = fmaxf(mx, __shfl_xor(mx, 16));
        mx = fmaxf(mx, __shfl_xor(mx, 32));
        const float mn = fmaxf(mreg, mx);
        const float al = exp2f(mreg - mn);
        float p[16], rs = 0.0f;
        #pragma unroll
        for (int j = 0; j < 16; ++j) { p[j] = exp2f(a[j] - mn); rs += p[j]; }
        rs += __shfl_xor(rs, 16);
        rs += __shfl_xor(rs, 32);
        lreg = lreg * al + rs;
        mreg = mn;

        bf16x8 pf0, pf1;
        #pragma unroll
        for (int j = 0; j < 8; ++j) { pf0[j] = (__bf16)p[j]; pf1[j] = (__bf16)p[8 + j]; }

        // ---- PV: o[t] (d rows 16t+4*g16+r, q col r16) ----
        #pragma unroll
        for (int t = 0; t < 4; ++t) {
            const int row  = 16 * t + r16;
            const int sw   = row & 7;
            const int base = row * 64 + (g16 & 1) * 4;
            const int c0   = g16 >> 1;
            U4 a0 = *(const U4*)&V[base + (((c0 + 0) ^ sw) * 8)];
            U4 a1 = *(const U4*)&V[base + (((c0 + 2) ^ sw) * 8)];
            U4 b0 = *(const U4*)&V[base + (((c0 + 4) ^ sw) * 8)];
            U4 b1 = *(const U4*)&V[base + (((c0 + 6) ^ sw) * 8)];
            #pragma unroll
            for (int r = 0; r < 4; ++r) o[t][r] *= al;
            bf16x8 v0, v1;
            #pragma unroll
            for (int j = 0; j < 4; ++j) {
                v0[j]     = ((const __bf16*)&a0)[j];
                v0[4 + j] = ((const __bf16*)&a1)[j];
                v1[j]     = ((const __bf16*)&b0)[j];
                v1[4 + j] = ((const __bf16*)&b1)[j];
            }
            o[t] = mfma16(v0, pf0, o[t]);
            o[t] = mfma16(v1, pf1, o[t]);
        }

        if (it + 1 < nt) {                 // next-tile loads done; protect buffers
            asm volatile("s_waitcnt vmcnt(0)" ::: "memory");
            __builtin_amdgcn_s_barrier();
        }
    }

    const float inv = 1.0f / lreg;
    u16* op = Ob + (seqb + q0w + r16) * 1024 + h * 64 + 4 * g16;
    #pragma unroll
    for (int t = 0; t < 4; ++t) {
        U4 st;
        #pragma unroll
        for (int r = 0; r < 4; ++r) st.v[r] = f2bf(o[t][r] * inv);
        *(U4*)(op + 16 * t) = st;
    }
}

// ---------- SwiGLU elementwise: out = silu(a) * g (bf16) ----------
__global__ __launch_bounds__(256) void swiglu_k(const u16* __restrict__ a,
                                                const u16* __restrict__ g,
                                                u16* __restrict__ o, int n8) {
    int i = blockIdx.x * 256 + threadIdx.x;
    if (i >= n8) return;
    U8 av = *(const U8*)(a + (size_t)i * 8);
    U8 gv = *(const U8*)(g + (size_t)i * 8);
    U8 ov;
    #pragma unroll
    for (int j = 0; j < 8; ++j) {
        const float fa = bf2f(av.v[j]);
        const float fg = bf2f(gv.v[j]);
        const float s  = fa / (1.0f + __expf(-fa));
        ov.v[j] = f2bf(s * fg);
    }
    *(U8*)(o + (size_t)i * 8) = ov;
}

// ---------- launch ----------
extern "C" void kernel_launch(void* const* d_in, const int* in_sizes, int n_in,
                              void* d_out, int out_size, void* d_ws, size_t ws_size,
                              hipStream_t stream) {
    (void)in_sizes; (void)n_in; (void)out_size; (void)ws_size;
    constexpr int C = 1024, FF = 4096, M = 2 * 2048;   // B*T = 4096

    const float* x      = (const float*)d_in[0];
    const float* ln1_w  = (const float*)d_in[1];
    const float* ln1_b  = (const float*)d_in[2];
    const float* qkv_w  = (const float*)d_in[3];
    const float* atto_w = (const float*)d_in[4];
    const float* ln2_w  = (const float*)d_in[5];
    const float* ln2_b  = (const float*)d_in[6];
    const float* mlpi_w = (const float*)d_in[7];
    const float* mlpg_w = (const float*)d_in[8];
    const float* mlpo_w = (const float*)d_in[9];
    float* out = (float*)d_out;

    char* ws = (char*)d_ws;
    size_t off = 0;
    auto alloc = [&](size_t bytes) {
        char* p = ws + off;
        off += (bytes + 255) & ~(size_t)255;
        return p;
    };
    u16*   wq   = (u16*)  alloc((size_t)3 * C * C * 2);   // qkv_w bf16 (rows: Q,K then V)
    u16*   wo   = (u16*)  alloc((size_t)C * C * 2);
    u16*   wi   = (u16*)  alloc((size_t)FF * C * 2);
    u16*   wg   = (u16*)  alloc((size_t)FF * C * 2);
    u16*   wm   = (u16*)  alloc((size_t)C * FF * 2);
    u16*   h1   = (u16*)  alloc((size_t)M * C * 2);
    u16*   qk_b = (u16*)  alloc((size_t)M * 2 * C * 2);   // [4096][2048] Q|K
    u16*   vt_b = (u16*)  alloc((size_t)C * M * 2);       // [1024][4096] V^T
    u16*   Ob   = (u16*)  alloc((size_t)M * C * 2);
    float* x1   = (float*)alloc((size_t)M * C * 4);
    u16*   h2   = (u16*)  alloc((size_t)M * C * 2);
    u16*   ab   = (u16*)  alloc((size_t)M * FF * 2);
    u16*   gb   = (u16*)  alloc((size_t)M * FF * 2);

    // weight casts (f32 -> bf16)
    cast_bf16_k<<<(3 * C * C / 4) / 256, 256, 0, stream>>>(qkv_w, wq, 3 * C * C / 4);
    cast_bf16_k<<<(C * C / 4) / 256, 256, 0, stream>>>(atto_w, wo, C * C / 4);
    cast_bf16_k<<<(FF * C / 4) / 256, 256, 0, stream>>>(mlpi_w, wi, FF * C / 4);
    cast_bf16_k<<<(FF * C / 4) / 256, 256, 0, stream>>>(mlpg_w, wg, FF * C / 4);
    cast_bf16_k<<<(C * FF / 4) / 256, 256, 0, stream>>>(mlpo_w, wm, C * FF / 4);

    // attention branch
    ln_fwd_k<<<M, 256, 0, stream>>>(x, ln1_w, ln1_b, h1);
    // Q|K = h1 @ Wqk^T  -> [4096][2048]
    gemm_bt_k<0><<<dim3(2 * C / 128, M / 128), 256, 0, stream>>>(h1, wq, qk_b, nullptr, M, 2 * C, C);
    // V^T = Wv @ h1^T   -> [1024][4096]   (Wv = rows 2C..3C of qkv_w)
    const u16* wv = wq + (size_t)2 * C * C;
    gemm_bt_k<0><<<dim3(M / 128, C / 128), 256, 0, stream>>>(wv, h1, vt_b, nullptr, C, M, C);
    attn_fwd_k<<<1024, 256, 0, stream>>>(qk_b, vt_b, Ob);
    gemm_bt_k<1><<<dim3(C / 128, M / 128), 256, 0, stream>>>(Ob, wo, x1, x, M, C, C);

    // MLP branch
    ln_fwd_k<<<M, 256, 0, stream>>>(x1, ln2_w, ln2_b, h2);
    gemm_bt_k<0><<<dim3(FF / 128, M / 128), 256, 0, stream>>>(h2, wi, ab, nullptr, M, FF, C);
    gemm_bt_k<0><<<dim3(FF / 128, M / 128), 256, 0, stream>>>(h2, wg, gb, nullptr, M, FF, C);
    swiglu_k<<<(M * FF / 8) / 256, 256, 0, stream>>>(ab, gb, ab, M * FF / 8);
    gemm_bt_k<1><<<dim3(C / 128, M / 128), 256, 0, stream>>>(ab, wm, out, x1, M, C, FF);
}

// Round 4
// 335.582 us; speedup vs baseline: 1.9749x; 1.1774x over previous
//
#include <hip/hip_runtime.h>
#include <cstdint>

// ---------- types & helpers ----------
typedef unsigned short u16;
typedef __bf16 bf16x8 __attribute__((ext_vector_type(8)));
typedef float  f32x4  __attribute__((ext_vector_type(4)));

struct alignas(16) F4 { float v[4]; };
struct alignas(8)  U4 { u16 v[4]; };
struct alignas(16) U8 { u16 v[8]; };

__device__ __forceinline__ u16 f2bf(float f) {
    union { float f; unsigned int u; } x; x.f = f;
    unsigned int r = x.u + 0x7fffu + ((x.u >> 16) & 1u);   // RNE
    return (u16)(r >> 16);
}
__device__ __forceinline__ float bf2f(u16 u) {
    union { unsigned int u; float f; } x; x.u = ((unsigned int)u) << 16;
    return x.f;
}
__device__ __forceinline__ f32x4 mfma16(bf16x8 a, bf16x8 b, f32x4 c) {
    return __builtin_amdgcn_mfma_f32_16x16x32_bf16(a, b, c, 0, 0, 0);
}
// async global->LDS, 16B per lane, dest = wave-uniform base + lane*16
__device__ __forceinline__ void gload_lds16(const void* g, void* l) {
    auto* gp = reinterpret_cast<const __attribute__((address_space(1))) unsigned int*>(
        reinterpret_cast<uintptr_t>(g));
    auto* lp = reinterpret_cast<__attribute__((address_space(3))) unsigned int*>(
        reinterpret_cast<uintptr_t>(l));
    __builtin_amdgcn_global_load_lds(gp, lp, 16, 0, 0);
}

// ---------- generic f32 -> bf16 cast (vector) ----------
__global__ __launch_bounds__(256) void cast_bf16_k(const float* __restrict__ in,
                                                   u16* __restrict__ out, int n4) {
    int i = blockIdx.x * 256 + threadIdx.x;
    if (i >= n4) return;
    F4 v = *(const F4*)(in + (size_t)i * 4);
    U4 o;
    #pragma unroll
    for (int j = 0; j < 4; ++j) o.v[j] = f2bf(v.v[j]);
    *(U4*)(out + (size_t)i * 4) = o;
}

// ---------- build row-interleaved wig: rows (p*128+0..63)=wi[p*64+..], (+64..127)=wg ----------
__global__ __launch_bounds__(256) void cast_wig_k(const float* __restrict__ wi,
                                                  const float* __restrict__ wg,
                                                  u16* __restrict__ wig) {
    int i = blockIdx.x * 256 + threadIdx.x;          // over 8192 rows * 128 groups-of-8
    const int w  = i >> 7;
    const int c8 = (i & 127) * 8;
    const int f  = ((w >> 7) << 6) + (w & 63);
    const float* src = ((w & 64) ? wg : wi) + (size_t)f * 1024 + c8;
    F4 a = *(const F4*)src;
    F4 b = *(const F4*)(src + 4);
    U8 o;
    #pragma unroll
    for (int j = 0; j < 4; ++j) { o.v[j] = f2bf(a.v[j]); o.v[4 + j] = f2bf(b.v[j]); }
    *(U8*)(wig + (size_t)w * 1024 + c8) = o;
}

// ---------- LayerNorm (C=1024), f32 in -> bf16 out ----------
__global__ __launch_bounds__(256) void ln_fwd_k(const float* __restrict__ x,
                                                const float* __restrict__ w,
                                                const float* __restrict__ b,
                                                u16* __restrict__ h) {
    const int row = blockIdx.x, tid = threadIdx.x;
    const float* xr = x + (size_t)row * 1024;
    F4 v = *(const F4*)(xr + tid * 4);
    float s  = v.v[0] + v.v[1] + v.v[2] + v.v[3];
    float ss = v.v[0]*v.v[0] + v.v[1]*v.v[1] + v.v[2]*v.v[2] + v.v[3]*v.v[3];
    #pragma unroll
    for (int o = 32; o > 0; o >>= 1) { s += __shfl_down(s, o); ss += __shfl_down(ss, o); }
    __shared__ float red[8];
    const int wave = tid >> 6, lane = tid & 63;
    if (lane == 0) { red[wave] = s; red[4 + wave] = ss; }
    __syncthreads();
    s  = red[0] + red[1] + red[2] + red[3];
    ss = red[4] + red[5] + red[6] + red[7];
    const float mu   = s * (1.0f / 1024.0f);
    const float var  = ss * (1.0f / 1024.0f) - mu * mu;
    const float rstd = rsqrtf(var + 1e-5f);
    U4 o;
    #pragma unroll
    for (int j = 0; j < 4; ++j)
        o.v[j] = f2bf((v.v[j] - mu) * rstd * w[tid * 4 + j] + b[tid * 4 + j]);
    *(U4*)(h + (size_t)row * 1024 + tid * 4) = o;
}

// ---------- GEMM: C[M,N] = A[M,K] * B[N,K]^T (both bf16 row-major, K-contiguous) ----------
// m97 structure: 128x128 tile, BK=32, 4 waves (2x2), 4x4 16x16 frags/wave, global_load_lds.
// MODE 0: bf16 store. MODE 1: f32 store resid+acc. MODE 2: f32 partial store
//         (split-K: blockIdx.z selects K-chunk, plane blockIdx.z*M*N).
template <int MODE>
__global__ __launch_bounds__(256) void gemm_bt_k(const u16* __restrict__ A,
                                                 const u16* __restrict__ Bm,
                                                 void* __restrict__ Cout,
                                                 const float* __restrict__ resid,
                                                 int M, int N, int K, int kchunk) {
    __shared__ u16 Alds[128 * 32];
    __shared__ u16 Blds[128 * 32];
    const int tid  = threadIdx.x;
    const int lane = tid & 63, wave = tid >> 6;
    const int wr = wave >> 1, wc = wave & 1;
    const int r16 = lane & 15, g16 = lane >> 4;
    const int bn = blockIdx.x, bm = blockIdx.y;
    const int kBeg = blockIdx.z * kchunk;
    const int kEnd = kBeg + kchunk;

    const int srow = lane >> 2;          // 0..15 within 16-row chunk
    const int scol = (lane & 3) * 8;     // 0,8,16,24

    f32x4 acc[4][4] = {};

    for (int k0 = kBeg; k0 < kEnd; k0 += 32) {
        #pragma unroll
        for (int c = 0; c < 2; ++c) {
            const int ch = wave * 2 + c;                    // 0..7 (16 rows each)
            const u16* ga = A  + ((size_t)bm * 128 + ch * 16 + srow) * K + k0 + scol;
            gload_lds16(ga, &Alds[ch * 512]);
            const u16* gb = Bm + ((size_t)bn * 128 + ch * 16 + srow) * K + k0 + scol;
            gload_lds16(gb, &Blds[ch * 512]);
        }
        __syncthreads();
        bf16x8 af[4], bfr[4];
        #pragma unroll
        for (int m = 0; m < 4; ++m)
            af[m] = *(const bf16x8*)&Alds[(wr * 64 + m * 16 + r16) * 32 + g16 * 8];
        #pragma unroll
        for (int n = 0; n < 4; ++n)
            bfr[n] = *(const bf16x8*)&Blds[(wc * 64 + n * 16 + r16) * 32 + g16 * 8];
        #pragma unroll
        for (int m = 0; m < 4; ++m)
            #pragma unroll
            for (int n = 0; n < 4; ++n)
                acc[m][n] = mfma16(af[m], bfr[n], acc[m][n]);
        __syncthreads();
    }

    float* Pf = (MODE == 2) ? ((float*)Cout + (size_t)blockIdx.z * M * N) : (float*)Cout;
    #pragma unroll
    for (int m = 0; m < 4; ++m) {
        #pragma unroll
        for (int n = 0; n < 4; ++n) {
            #pragma unroll
            for (int r = 0; r < 4; ++r) {
                const int row = bm * 128 + wr * 64 + m * 16 + g16 * 4 + r;
                const int col = bn * 128 + wc * 64 + n * 16 + r16;
                const float v = acc[m][n][r];
                if (MODE == 0) {
                    ((u16*)Cout)[(size_t)row * N + col] = f2bf(v);
                } else if (MODE == 1) {
                    ((float*)Cout)[(size_t)row * N + col] =
                        resid[(size_t)row * N + col] + v;
                } else {
                    Pf[(size_t)row * N + col] = v;
                }
            }
        }
    }
}

// ---------- fused FF GEMM + SwiGLU: ab[M][4096] from h2[M][1024] x wig[8192][1024]^T ----------
// wig rows interleaved (64 in / 64 gate per 128-panel) so a thread holds the
// (in, gate) pair for one ff index: acc[m][n] (in), acc[m][n+4] (gate).
// 4 waves stacked in M: wave tile 32x128, frags 2(M) x 8(N).
__global__ __launch_bounds__(256) void gemm_ff_swiglu_k(const u16* __restrict__ A,
                                                        const u16* __restrict__ W,
                                                        u16* __restrict__ ab) {
    __shared__ u16 Alds[128 * 32];
    __shared__ u16 Blds[128 * 32];
    const int tid  = threadIdx.x;
    const int lane = tid & 63, wave = tid >> 6;
    const int r16 = lane & 15, g16 = lane >> 4;
    const int bn = blockIdx.x, bm = blockIdx.y;     // bn: 0..63 (ff/64), bm: 0..31

    const int srow = lane >> 2;
    const int scol = (lane & 3) * 8;

    f32x4 acc[2][8] = {};

    for (int k0 = 0; k0 < 1024; k0 += 32) {
        #pragma unroll
        for (int c = 0; c < 2; ++c) {
            const int ch = wave * 2 + c;
            const u16* ga = A + ((size_t)bm * 128 + ch * 16 + srow) * 1024 + k0 + scol;
            gload_lds16(ga, &Alds[ch * 512]);
            const u16* gb = W + ((size_t)bn * 128 + ch * 16 + srow) * 1024 + k0 + scol;
            gload_lds16(gb, &Blds[ch * 512]);
        }
        __syncthreads();
        bf16x8 af[2], bfr[8];
        #pragma unroll
        for (int m = 0; m < 2; ++m)
            af[m] = *(const bf16x8*)&Alds[(wave * 32 + m * 16 + r16) * 32 + g16 * 8];
        #pragma unroll
        for (int n = 0; n < 8; ++n)
            bfr[n] = *(const bf16x8*)&Blds[(n * 16 + r16) * 32 + g16 * 8];
        #pragma unroll
        for (int m = 0; m < 2; ++m)
            #pragma unroll
            for (int n = 0; n < 8; ++n)
                acc[m][n] = mfma16(af[m], bfr[n], acc[m][n]);
        __syncthreads();
    }

    #pragma unroll
    for (int m = 0; m < 2; ++m) {
        #pragma unroll
        for (int n = 0; n < 4; ++n) {
            #pragma unroll
            for (int r = 0; r < 4; ++r) {
                const int row = bm * 128 + wave * 32 + m * 16 + g16 * 4 + r;
                const int col = bn * 64 + n * 16 + r16;
                const float vi = acc[m][n][r];
                const float vg = acc[m][n + 4][r];
                const float s  = vi / (1.0f + __expf(-vi));
                ab[(size_t)row * 4096 + col] = f2bf(s * vg);
            }
        }
    }
}

// ---------- split-K reduce: out = resid + p0 + p1 (f32, vectorized, grid-stride) ----------
__global__ __launch_bounds__(256) void addreduce_k(const float* __restrict__ resid,
                                                   const float* __restrict__ p,
                                                   float* __restrict__ out,
                                                   int n4, int planeEls) {
    for (int i = blockIdx.x * 256 + threadIdx.x; i < n4; i += gridDim.x * 256) {
        F4 a = *(const F4*)(resid + (size_t)i * 4);
        F4 b = *(const F4*)(p + (size_t)i * 4);
        F4 c = *(const F4*)(p + (size_t)planeEls + (size_t)i * 4);
        F4 o;
        #pragma unroll
        for (int j = 0; j < 4; ++j) o.v[j] = a.v[j] + b.v[j] + c.v[j];
        *(F4*)(out + (size_t)i * 4) = o;
    }
}

// ---------- flash attention v3 (causal), transpose-world + LDS-staged K/V ----------
__global__ __launch_bounds__(256) void attn_fwd_k(const u16* __restrict__ qk,
                                                  const u16* __restrict__ vt,
                                                  u16* __restrict__ Ob) {
    __shared__ u16 Klds[2][64 * 64];
    __shared__ u16 Vlds[2][64 * 64];

    const int tid  = threadIdx.x;
    const int wave = tid >> 6, lane = tid & 63;
    const int r16  = lane & 15, g16 = lane >> 4;

    const int blk = blockIdx.x;
    const int xcd = blk & 7;
    const int pc  = blk >> 3;
    const int hh  = pc >> 5;
    const int qb  = (31 - (pc & 31) + 8 * hh) & 31;
    const int bh  = xcd * 4 + hh;
    const int h   = bh & 15, b = bh >> 4;

    const int q0w = qb * 64 + wave * 16;
    const size_t seqb = (size_t)b * 2048;

    const u16* qp = qk + (seqb + q0w + r16) * 2048 + h * 64 + g16 * 8;
    const bf16x8 qf0 = *(const bf16x8*)qp;
    const bf16x8 qf1 = *(const bf16x8*)(qp + 32);

    const u16* kbase = qk + seqb * 2048 + 1024 + (size_t)h * 64;
    const u16* vbase = vt + (size_t)(h * 64) * 4096 + seqb;

    const int srow  = tid >> 3;                           // 0..31
    const int scol8 = ((tid & 7) ^ (srow & 7)) * 8;
    const u16* ksrc = kbase + (size_t)srow * 2048 + scol8;
    const u16* vsrc = vbase + (size_t)srow * 4096 + scol8;

    auto stage = [&](int bufi, int kv0) {
        const u16* kp = ksrc + (size_t)kv0 * 2048;
        const u16* vp = vsrc + kv0;
        u16* kd = &Klds[bufi][wave * 512];
        u16* vd = &Vlds[bufi][wave * 512];
        gload_lds16(kp, kd);
        gload_lds16(kp + (size_t)32 * 2048, kd + 2048);
        gload_lds16(vp, vd);
        gload_lds16(vp + (size_t)32 * 4096, vd + 2048);
    };

    f32x4 o[4] = {};
    float mreg = -3.0e38f, lreg = 0.0f;
    constexpr float SC = 0.125f * 1.44269504088896341f;   // Dh^-0.5 * log2(e)

    const int nt = qb + 1;
    stage(0, 0);
    asm volatile("s_waitcnt vmcnt(0)" ::: "memory");
    __builtin_amdgcn_s_barrier();

    for (int it = 0; it < nt; ++it) {
        const int kv0 = it * 64;
        const int cur = it & 1;
        if (it + 1 < nt) stage(cur ^ 1, kv0 + 64);

        const u16* K = Klds[cur];
        const u16* V = Vlds[cur];

        f32x4 s[4];
        #pragma unroll
        for (int t = 0; t < 4; ++t) {
            const int row = 16 * t + r16;
            const int sw  = row & 7;
            const bf16x8 k0 = *(const bf16x8*)&K[row * 64 + ((g16 ^ sw) * 8)];
            const bf16x8 k1 = *(const bf16x8*)&K[row * 64 + (((g16 + 4) ^ sw) * 8)];
            f32x4 acc = {0.f, 0.f, 0.f, 0.f};
            acc = mfma16(k0, qf0, acc);
            acc = mfma16(k1, qf1, acc);
            s[t] = acc;
        }

        float a[16];
        #pragma unroll
        for (int t = 0; t < 4; ++t)
            #pragma unroll
            for (int r = 0; r < 4; ++r) a[4 * t + r] = s[t][r] * SC;

        if (kv0 + 63 > q0w) {
            const int qg = q0w + r16;
            #pragma unroll
            for (int t = 0; t < 4; ++t)
                #pragma unroll
                for (int r = 0; r < 4; ++r)
                    if (kv0 + 16 * t + 4 * g16 + r > qg) a[4 * t + r] = -1.0e30f;
        }

        float mx = a[0];
        #pragma unroll
        for (int j = 1; j < 16; ++j) mx = fmaxf(mx, a[j]);
        mx = fmaxf(mx, __shfl_xor(mx, 16));
        mx = fmaxf(mx, __shfl_xor(mx, 32));
        const float mn = fmaxf(mreg, mx);
        const float al = exp2f(mreg - mn);
        float p[16], rs = 0.0f;
        #pragma unroll
        for (int j = 0; j < 16; ++j) { p[j] = exp2f(a[j] - mn); rs += p[j]; }
        rs += __shfl_xor(rs, 16);
        rs += __shfl_xor(rs, 32);
        lreg = lreg * al + rs;
        mreg = mn;

        bf16x8 pf0, pf1;
        #pragma unroll
        for (int j = 0; j < 8; ++j) { pf0[j] = (__bf16)p[j]; pf1[j] = (__bf16)p[8 + j]; }

        #pragma unroll
        for (int t = 0; t < 4; ++t) {
            const int row  = 16 * t + r16;
            const int sw   = row & 7;
            const int base = row * 64 + (g16 & 1) * 4;
            const int c0   = g16 >> 1;
            U4 a0 = *(const U4*)&V[base + (((c0 + 0) ^ sw) * 8)];
            U4 a1 = *(const U4*)&V[base + (((c0 + 2) ^ sw) * 8)];
            U4 b0 = *(const U4*)&V[base + (((c0 + 4) ^ sw) * 8)];
            U4 b1 = *(const U4*)&V[base + (((c0 + 6) ^ sw) * 8)];
            #pragma unroll
            for (int r = 0; r < 4; ++r) o[t][r] *= al;
            bf16x8 v0, v1;
            #pragma unroll
            for (int j = 0; j < 4; ++j) {
                v0[j]     = ((const __bf16*)&a0)[j];
                v0[4 + j] = ((const __bf16*)&a1)[j];
                v1[j]     = ((const __bf16*)&b0)[j];
                v1[4 + j] = ((const __bf16*)&b1)[j];
            }
            o[t] = mfma16(v0, pf0, o[t]);
            o[t] = mfma16(v1, pf1, o[t]);
        }

        if (it + 1 < nt) {
            asm volatile("s_waitcnt vmcnt(0)" ::: "memory");
            __builtin_amdgcn_s_barrier();
        }
    }

    const float inv = 1.0f / lreg;
    u16* op = Ob + (seqb + q0w + r16) * 1024 + h * 64 + 4 * g16;
    #pragma unroll
    for (int t = 0; t < 4; ++t) {
        U4 st;
        #pragma unroll
        for (int r = 0; r < 4; ++r) st.v[r] = f2bf(o[t][r] * inv);
        *(U4*)(op + 16 * t) = st;
    }
}

// ---------- launch ----------
extern "C" void kernel_launch(void* const* d_in, const int* in_sizes, int n_in,
                              void* d_out, int out_size, void* d_ws, size_t ws_size,
                              hipStream_t stream) {
    (void)in_sizes; (void)n_in; (void)out_size; (void)ws_size;
    constexpr int C = 1024, FF = 4096, M = 2 * 2048;   // B*T = 4096

    const float* x      = (const float*)d_in[0];
    const float* ln1_w  = (const float*)d_in[1];
    const float* ln1_b  = (const float*)d_in[2];
    const float* qkv_w  = (const float*)d_in[3];
    const float* atto_w = (const float*)d_in[4];
    const float* ln2_w  = (const float*)d_in[5];
    const float* ln2_b  = (const float*)d_in[6];
    const float* mlpi_w = (const float*)d_in[7];
    const float* mlpg_w = (const float*)d_in[8];
    const float* mlpo_w = (const float*)d_in[9];
    float* out = (float*)d_out;

    char* ws = (char*)d_ws;
    size_t off = 0;
    auto alloc = [&](size_t bytes) {
        char* p = ws + off;
        off += (bytes + 255) & ~(size_t)255;
        return p;
    };
    u16*   wq   = (u16*)  alloc((size_t)3 * C * C * 2);   // qkv_w bf16 (rows: Q,K then V)
    u16*   wo   = (u16*)  alloc((size_t)C * C * 2);
    u16*   wig  = (u16*)  alloc((size_t)2 * FF * C * 2);  // interleaved wi/wg [8192][1024]
    u16*   wm   = (u16*)  alloc((size_t)C * FF * 2);
    u16*   h1   = (u16*)  alloc((size_t)M * C * 2);
    u16*   qk_b = (u16*)  alloc((size_t)M * 2 * C * 2);   // [4096][2048] Q|K
    u16*   vt_b = (u16*)  alloc((size_t)C * M * 2);       // [1024][4096] V^T
    u16*   Ob   = (u16*)  alloc((size_t)M * C * 2);
    float* x1   = (float*)alloc((size_t)M * C * 4);
    u16*   h2   = (u16*)  alloc((size_t)M * C * 2);
    u16*   ab   = (u16*)  alloc((size_t)M * FF * 2);
    float* pscr = (float*)alloc((size_t)2 * M * C * 4);   // split-K partials (2 planes)

    // weight casts
    cast_bf16_k<<<(3 * C * C / 4) / 256, 256, 0, stream>>>(qkv_w, wq, 3 * C * C / 4);
    cast_bf16_k<<<(C * C / 4) / 256, 256, 0, stream>>>(atto_w, wo, C * C / 4);
    cast_bf16_k<<<(C * FF / 4) / 256, 256, 0, stream>>>(mlpo_w, wm, C * FF / 4);
    cast_wig_k<<<(2 * FF * C / 8) / 256, 256, 0, stream>>>(mlpi_w, mlpg_w, wig);

    // attention branch
    ln_fwd_k<<<M, 256, 0, stream>>>(x, ln1_w, ln1_b, h1);
    gemm_bt_k<0><<<dim3(2 * C / 128, M / 128), 256, 0, stream>>>(h1, wq, qk_b, nullptr, M, 2 * C, C, C);
    const u16* wv = wq + (size_t)2 * C * C;
    gemm_bt_k<0><<<dim3(M / 128, C / 128), 256, 0, stream>>>(wv, h1, vt_b, nullptr, C, M, C, C);
    attn_fwd_k<<<1024, 256, 0, stream>>>(qk_b, vt_b, Ob);
    gemm_bt_k<1><<<dim3(C / 128, M / 128), 256, 0, stream>>>(Ob, wo, x1, x, M, C, C, C);

    // MLP branch
    ln_fwd_k<<<M, 256, 0, stream>>>(x1, ln2_w, ln2_b, h2);
    gemm_ff_swiglu_k<<<dim3(2 * FF / 128, M / 128), 256, 0, stream>>>(h2, wig, ab);
    // mlp_out split-K=2: partials then reduce with resid x1
    gemm_bt_k<2><<<dim3(C / 128, M / 128, 2), 256, 0, stream>>>(ab, wm, pscr, nullptr, M, C, FF, FF / 2);
    addreduce_k<<<2048, 256, 0, stream>>>(x1, pscr, out, M * C / 4, M * C);
}

// Round 5
// 309.251 us; speedup vs baseline: 2.1430x; 1.0851x over previous
//
#include <hip/hip_runtime.h>
#include <cstdint>

// ---------- types & helpers ----------
typedef unsigned short u16;
typedef __bf16 bf16x8 __attribute__((ext_vector_type(8)));
typedef float  f32x4  __attribute__((ext_vector_type(4)));

struct alignas(16) F4 { float v[4]; };
struct alignas(8)  U4 { u16 v[4]; };
struct alignas(16) U8 { u16 v[8]; };

__device__ __forceinline__ u16 f2bf(float f) {
    union { float f; unsigned int u; } x; x.f = f;
    unsigned int r = x.u + 0x7fffu + ((x.u >> 16) & 1u);   // RNE
    return (u16)(r >> 16);
}
__device__ __forceinline__ float bf2f(u16 u) {
    union { unsigned int u; float f; } x; x.u = ((unsigned int)u) << 16;
    return x.f;
}
__device__ __forceinline__ f32x4 mfma16(bf16x8 a, bf16x8 b, f32x4 c) {
    return __builtin_amdgcn_mfma_f32_16x16x32_bf16(a, b, c, 0, 0, 0);
}
// async global->LDS, 16B per lane, dest = wave-uniform base + lane*16
__device__ __forceinline__ void gload_lds16(const void* g, void* l) {
    auto* gp = reinterpret_cast<const __attribute__((address_space(1))) unsigned int*>(
        reinterpret_cast<uintptr_t>(g));
    auto* lp = reinterpret_cast<__attribute__((address_space(3))) unsigned int*>(
        reinterpret_cast<uintptr_t>(l));
    __builtin_amdgcn_global_load_lds(gp, lp, 16, 0, 0);
}

// ---------- generic f32 -> bf16 cast (vector) ----------
__global__ __launch_bounds__(256) void cast_bf16_k(const float* __restrict__ in,
                                                   u16* __restrict__ out, int n4) {
    int i = blockIdx.x * 256 + threadIdx.x;
    if (i >= n4) return;
    F4 v = *(const F4*)(in + (size_t)i * 4);
    U4 o;
    #pragma unroll
    for (int j = 0; j < 4; ++j) o.v[j] = f2bf(v.v[j]);
    *(U4*)(out + (size_t)i * 4) = o;
}

// ---------- build interleaved wig: per 64-row group: 32 in rows then 32 gate rows ----------
// wig row w -> f = (w>>6)*32 + (w&31), type = (w>>5)&1 (0=in,1=gate)
__global__ __launch_bounds__(256) void cast_wig_k(const float* __restrict__ wi,
                                                  const float* __restrict__ wg,
                                                  u16* __restrict__ wig) {
    int i = blockIdx.x * 256 + threadIdx.x;          // over 8192 rows * 128 groups-of-8
    const int w  = i >> 7;
    const int c8 = (i & 127) * 8;
    const int f  = ((w >> 6) << 5) | (w & 31);
    const float* src = ((w & 32) ? wg : wi) + (size_t)f * 1024 + c8;
    F4 a = *(const F4*)src;
    F4 b = *(const F4*)(src + 4);
    U8 o;
    #pragma unroll
    for (int j = 0; j < 4; ++j) { o.v[j] = f2bf(a.v[j]); o.v[4 + j] = f2bf(b.v[j]); }
    *(U8*)(wig + (size_t)w * 1024 + c8) = o;
}

// ---------- LayerNorm (C=1024), f32 in -> bf16 out ----------
__global__ __launch_bounds__(256) void ln_fwd_k(const float* __restrict__ x,
                                                const float* __restrict__ w,
                                                const float* __restrict__ b,
                                                u16* __restrict__ h) {
    const int row = blockIdx.x, tid = threadIdx.x;
    const float* xr = x + (size_t)row * 1024;
    F4 v = *(const F4*)(xr + tid * 4);
    float s  = v.v[0] + v.v[1] + v.v[2] + v.v[3];
    float ss = v.v[0]*v.v[0] + v.v[1]*v.v[1] + v.v[2]*v.v[2] + v.v[3]*v.v[3];
    #pragma unroll
    for (int o = 32; o > 0; o >>= 1) { s += __shfl_down(s, o); ss += __shfl_down(ss, o); }
    __shared__ float red[8];
    const int wave = tid >> 6, lane = tid & 63;
    if (lane == 0) { red[wave] = s; red[4 + wave] = ss; }
    __syncthreads();
    s  = red[0] + red[1] + red[2] + red[3];
    ss = red[4] + red[5] + red[6] + red[7];
    const float mu   = s * (1.0f / 1024.0f);
    const float var  = ss * (1.0f / 1024.0f) - mu * mu;
    const float rstd = rsqrtf(var + 1e-5f);
    U4 o;
    #pragma unroll
    for (int j = 0; j < 4; ++j)
        o.v[j] = f2bf((v.v[j] - mu) * rstd * w[tid * 4 + j] + b[tid * 4 + j]);
    *(U4*)(h + (size_t)row * 1024 + tid * 4) = o;
}

// ---------- 128x128 GEMM (m97 structure), kept for qk / vt / attn_out ----------
// MODE 0: bf16 store. MODE 1: f32 store resid+acc.
template <int MODE>
__global__ __launch_bounds__(256) void gemm_bt_k(const u16* __restrict__ A,
                                                 const u16* __restrict__ Bm,
                                                 void* __restrict__ Cout,
                                                 const float* __restrict__ resid,
                                                 int M, int N, int K) {
    __shared__ u16 Alds[128 * 32];
    __shared__ u16 Blds[128 * 32];
    const int tid  = threadIdx.x;
    const int lane = tid & 63, wave = tid >> 6;
    const int wr = wave >> 1, wc = wave & 1;
    const int r16 = lane & 15, g16 = lane >> 4;
    const int bn = blockIdx.x, bm = blockIdx.y;

    const int srow = lane >> 2;
    const int scol = (lane & 3) * 8;

    f32x4 acc[4][4] = {};

    for (int k0 = 0; k0 < K; k0 += 32) {
        #pragma unroll
        for (int c = 0; c < 2; ++c) {
            const int ch = wave * 2 + c;
            const u16* ga = A  + ((size_t)bm * 128 + ch * 16 + srow) * K + k0 + scol;
            gload_lds16(ga, &Alds[ch * 512]);
            const u16* gb = Bm + ((size_t)bn * 128 + ch * 16 + srow) * K + k0 + scol;
            gload_lds16(gb, &Blds[ch * 512]);
        }
        __syncthreads();
        bf16x8 af[4], bfr[4];
        #pragma unroll
        for (int m = 0; m < 4; ++m)
            af[m] = *(const bf16x8*)&Alds[(wr * 64 + m * 16 + r16) * 32 + g16 * 8];
        #pragma unroll
        for (int n = 0; n < 4; ++n)
            bfr[n] = *(const bf16x8*)&Blds[(wc * 64 + n * 16 + r16) * 32 + g16 * 8];
        #pragma unroll
        for (int m = 0; m < 4; ++m)
            #pragma unroll
            for (int n = 0; n < 4; ++n)
                acc[m][n] = mfma16(af[m], bfr[n], acc[m][n]);
        __syncthreads();
    }

    #pragma unroll
    for (int m = 0; m < 4; ++m) {
        #pragma unroll
        for (int n = 0; n < 4; ++n) {
            #pragma unroll
            for (int r = 0; r < 4; ++r) {
                const int row = bm * 128 + wr * 64 + m * 16 + g16 * 4 + r;
                const int col = bn * 128 + wc * 64 + n * 16 + r16;
                const float v = acc[m][n][r];
                if (MODE == 0) {
                    ((u16*)Cout)[(size_t)row * N + col] = f2bf(v);
                } else {
                    ((float*)Cout)[(size_t)row * N + col] =
                        resid[(size_t)row * N + col] + v;
                }
            }
        }
    }
}

// ---------- 256x256 counted-vmcnt pipelined GEMM (T2+T3+T4+T5) ----------
// C[M,N] = A[M,K]*B[N,K]^T. 512 thr = 8 waves (2M x 4N); wave tile 128x64.
// LDS: 4-slot circular K=32 half-tiles (A 16KB + B 16KB per slot = 128 KiB).
// Phase g: ds_read frags(slot g&3) + stage(g+3 -> slot (g-1)&3) | barrier |
//          setprio(1) 32xMFMA setprio(0) | vmcnt(8) barrier.  Loads never drain to 0.
// Swizzle: 16B chunk c of row r stored at c ^ ((r>>1)&3) (inverse-swizzled global src).
// EPI 1: f32 partials (plane blockIdx.z).  EPI 2: fused SwiGLU bf16 (wig interleave).
template <int EPI>
__global__ __launch_bounds__(512, 2)
void gemm256_k(const u16* __restrict__ A, const u16* __restrict__ Bm,
               void* __restrict__ Cout, int lda, int ldb, int kLen,
               int nx, int outLd, int planeEls) {
    __shared__ u16 lds[4][2][8192];

    const int tid  = threadIdx.x;
    const int wave = tid >> 6, lane = tid & 63;
    const int wm = wave >> 2, wn = wave & 3;
    const int r16 = lane & 15, g16 = lane >> 4;

    // XCD swizzle over flat grid (gridDim.x % 8 == 0)
    const int cpx = gridDim.x >> 3;
    const int swz = (blockIdx.x & 7) * cpx + (blockIdx.x >> 3);
    const int bn = swz % nx, bm = swz / nx;
    const int kBeg = blockIdx.z * kLen;

    // staging sources (pre-swizzled): lane covers row w*32 + (lane>>2) (+16 for issue 1)
    const int sr0 = wave * 32 + (lane >> 2);
    const int sw0 = ((lane & 3) ^ ((sr0 >> 1) & 3)) * 8;
    const int sw1 = ((lane & 3) ^ (((sr0 + 16) >> 1) & 3)) * 8;
    const u16* aS0 = A  + (size_t)(bm * 256 + sr0) * lda + kBeg + sw0;
    const u16* aS1 = A  + (size_t)(bm * 256 + sr0 + 16) * lda + kBeg + sw1;
    const u16* bS0 = Bm + (size_t)(bn * 256 + sr0) * ldb + kBeg + sw0;
    const u16* bS1 = Bm + (size_t)(bn * 256 + sr0 + 16) * ldb + kBeg + sw1;

    auto stage = [&](int g) {
        const int s  = g & 3;
        const int ko = g * 32;
        gload_lds16(aS0 + ko, &lds[s][0][wave * 1024]);
        gload_lds16(aS1 + ko, &lds[s][0][wave * 1024 + 512]);
        gload_lds16(bS0 + ko, &lds[s][1][wave * 1024]);
        gload_lds16(bS1 + ko, &lds[s][1][wave * 1024 + 512]);
    };

    // fragment read offsets (swizzled), lane-constant
    int offA[8], offB[4];
    #pragma unroll
    for (int m = 0; m < 8; ++m) {
        const int r = wm * 128 + m * 16 + r16;
        offA[m] = r * 32 + ((g16 ^ ((r >> 1) & 3)) * 8);
    }
    #pragma unroll
    for (int n = 0; n < 4; ++n) {
        const int r = wn * 64 + n * 16 + r16;
        offB[n] = r * 32 + ((g16 ^ ((r >> 1) & 3)) * 8);
    }

    f32x4 acc[8][4] = {};
    const int G = kLen >> 5;

    stage(0); stage(1); stage(2);
    asm volatile("s_waitcnt vmcnt(8)" ::: "memory");
    __builtin_amdgcn_s_barrier();

    for (int g = 0; g < G; ++g) {
        const int s = g & 3;
        bf16x8 af[8], bfr[4];
        #pragma unroll
        for (int m = 0; m < 8; ++m) af[m] = *(const bf16x8*)&lds[s][0][offA[m]];
        #pragma unroll
        for (int n = 0; n < 4; ++n) bfr[n] = *(const bf16x8*)&lds[s][1][offB[n]];
        if (g + 3 < G) stage(g + 3);          // -> slot (g-1)&3, consumed last phase
        __builtin_amdgcn_s_barrier();
        __builtin_amdgcn_s_setprio(1);
        #pragma unroll
        for (int m = 0; m < 8; ++m)
            #pragma unroll
            for (int n = 0; n < 4; ++n)
                acc[m][n] = mfma16(af[m], bfr[n], acc[m][n]);
        __builtin_amdgcn_s_setprio(0);
        if (g + 1 < G) {
            if (g + 4 < G)      asm volatile("s_waitcnt vmcnt(8)" ::: "memory");
            else if (g + 2 < G) asm volatile("s_waitcnt vmcnt(4)" ::: "memory");
            else                asm volatile("s_waitcnt vmcnt(0)" ::: "memory");
            __builtin_amdgcn_s_barrier();
        }
    }

    if constexpr (EPI == 1) {
        float* P = (float*)Cout + (size_t)blockIdx.z * planeEls;
        #pragma unroll
        for (int m = 0; m < 8; ++m) {
            #pragma unroll
            for (int n = 0; n < 4; ++n) {
                #pragma unroll
                for (int r = 0; r < 4; ++r) {
                    const int row = bm * 256 + wm * 128 + m * 16 + g16 * 4 + r;
                    const int col = bn * 256 + wn * 64 + n * 16 + r16;
                    P[(size_t)row * outLd + col] = acc[m][n][r];
                }
            }
        }
    } else {
        (void)planeEls;
        u16* O = (u16*)Cout;
        #pragma unroll
        for (int m = 0; m < 8; ++m) {
            #pragma unroll
            for (int n = 0; n < 2; ++n) {
                #pragma unroll
                for (int r = 0; r < 4; ++r) {
                    const int row = bm * 256 + wm * 128 + m * 16 + g16 * 4 + r;
                    const int col = (bn * 4 + wn) * 32 + n * 16 + r16;
                    const float vi = acc[m][n][r];
                    const float vg = acc[m][n + 2][r];
                    const float sl = vi / (1.0f + __expf(-vi));
                    O[(size_t)row * outLd + col] = f2bf(sl * vg);
                }
            }
        }
    }
}

// ---------- split-K reduce: out = resid + p0+p1+p2+p3 ----------
__global__ __launch_bounds__(256) void addreduce4_k(const float* __restrict__ resid,
                                                    const float* __restrict__ p,
                                                    float* __restrict__ out,
                                                    int n4, int planeEls) {
    for (int i = blockIdx.x * 256 + threadIdx.x; i < n4; i += gridDim.x * 256) {
        F4 a = *(const F4*)(resid + (size_t)i * 4);
        F4 b = *(const F4*)(p + (size_t)i * 4);
        F4 c = *(const F4*)(p + (size_t)planeEls + (size_t)i * 4);
        F4 d = *(const F4*)(p + (size_t)2 * planeEls + (size_t)i * 4);
        F4 e = *(const F4*)(p + (size_t)3 * planeEls + (size_t)i * 4);
        F4 o;
        #pragma unroll
        for (int j = 0; j < 4; ++j) o.v[j] = a.v[j] + b.v[j] + c.v[j] + d.v[j] + e.v[j];
        *(F4*)(out + (size_t)i * 4) = o;
    }
}

// ---------- flash attention v3 (causal), transpose-world + LDS-staged K/V ----------
__global__ __launch_bounds__(256) void attn_fwd_k(const u16* __restrict__ qk,
                                                  const u16* __restrict__ vt,
                                                  u16* __restrict__ Ob) {
    __shared__ u16 Klds[2][64 * 64];
    __shared__ u16 Vlds[2][64 * 64];

    const int tid  = threadIdx.x;
    const int wave = tid >> 6, lane = tid & 63;
    const int r16  = lane & 15, g16 = lane >> 4;

    const int blk = blockIdx.x;
    const int xcd = blk & 7;
    const int pc  = blk >> 3;
    const int hh  = pc >> 5;
    const int qb  = (31 - (pc & 31) + 8 * hh) & 31;
    const int bh  = xcd * 4 + hh;
    const int h   = bh & 15, b = bh >> 4;

    const int q0w = qb * 64 + wave * 16;
    const size_t seqb = (size_t)b * 2048;

    const u16* qp = qk + (seqb + q0w + r16) * 2048 + h * 64 + g16 * 8;
    const bf16x8 qf0 = *(const bf16x8*)qp;
    const bf16x8 qf1 = *(const bf16x8*)(qp + 32);

    const u16* kbase = qk + seqb * 2048 + 1024 + (size_t)h * 64;
    const u16* vbase = vt + (size_t)(h * 64) * 4096 + seqb;

    const int srow  = tid >> 3;                           // 0..31
    const int scol8 = ((tid & 7) ^ (srow & 7)) * 8;
    const u16* ksrc = kbase + (size_t)srow * 2048 + scol8;
    const u16* vsrc = vbase + (size_t)srow * 4096 + scol8;

    auto stage = [&](int bufi, int kv0) {
        const u16* kp = ksrc + (size_t)kv0 * 2048;
        const u16* vp = vsrc + kv0;
        u16* kd = &Klds[bufi][wave * 512];
        u16* vd = &Vlds[bufi][wave * 512];
        gload_lds16(kp, kd);
        gload_lds16(kp + (size_t)32 * 2048, kd + 2048);
        gload_lds16(vp, vd);
        gload_lds16(vp + (size_t)32 * 4096, vd + 2048);
    };

    f32x4 o[4] = {};
    float mreg = -3.0e38f, lreg = 0.0f;
    constexpr float SC = 0.125f * 1.44269504088896341f;   // Dh^-0.5 * log2(e)

    const int nt = qb + 1;
    stage(0, 0);
    asm volatile("s_waitcnt vmcnt(0)" ::: "memory");
    __builtin_amdgcn_s_barrier();

    for (int it = 0; it < nt; ++it) {
        const int kv0 = it * 64;
        const int cur = it & 1;
        if (it + 1 < nt) stage(cur ^ 1, kv0 + 64);

        const u16* K = Klds[cur];
        const u16* V = Vlds[cur];

        f32x4 s[4];
        #pragma unroll
        for (int t = 0; t < 4; ++t) {
            const int row = 16 * t + r16;
            const int sw  = row & 7;
            const bf16x8 k0 = *(const bf16x8*)&K[row * 64 + ((g16 ^ sw) * 8)];
            const bf16x8 k1 = *(const bf16x8*)&K[row * 64 + (((g16 + 4) ^ sw) * 8)];
            f32x4 acc = {0.f, 0.f, 0.f, 0.f};
            acc = mfma16(k0, qf0, acc);
            acc = mfma16(k1, qf1, acc);
            s[t] = acc;
        }

        float a[16];
        #pragma unroll
        for (int t = 0; t < 4; ++t)
            #pragma unroll
            for (int r = 0; r < 4; ++r) a[4 * t + r] = s[t][r] * SC;

        if (kv0 + 63 > q0w) {
            const int qg = q0w + r16;
            #pragma unroll
            for (int t = 0; t < 4; ++t)
                #pragma unroll
                for (int r = 0; r < 4; ++r)
                    if (kv0 + 16 * t + 4 * g16 + r > qg) a[4 * t + r] = -1.0e30f;
        }

        float mx = a[0];
        #pragma unroll
        for (int j = 1; j < 16; ++j) mx = fmaxf(mx, a[j]);
        mx = fmaxf(mx, __shfl_xor(mx, 16));
        mx = fmaxf(mx, __shfl_xor(mx, 32));
        const float mn = fmaxf(mreg, mx);
        const float al = exp2f(mreg - mn);
        float p[16], rs = 0.0f;
        #pragma unroll
        for (int j = 0; j < 16; ++j) { p[j] = exp2f(a[j] - mn); rs += p[j]; }
        rs += __shfl_xor(rs, 16);
        rs += __shfl_xor(rs, 32);
        lreg = lreg * al + rs;
        mreg = mn;

        bf16x8 pf0, pf1;
        #pragma unroll
        for (int j = 0; j < 8; ++j) { pf0[j] = (__bf16)p[j]; pf1[j] = (__bf16)p[8 + j]; }

        #pragma unroll
        for (int t = 0; t < 4; ++t) {
            const int row  = 16 * t + r16;
            const int sw   = row & 7;
            const int base = row * 64 + (g16 & 1) * 4;
            const int c0   = g16 >> 1;
            U4 a0 = *(const U4*)&V[base + (((c0 + 0) ^ sw) * 8)];
            U4 a1 = *(const U4*)&V[base + (((c0 + 2) ^ sw) * 8)];
            U4 b0 = *(const U4*)&V[base + (((c0 + 4) ^ sw) * 8)];
            U4 b1 = *(const U4*)&V[base + (((c0 + 6) ^ sw) * 8)];
            #pragma unroll
            for (int r = 0; r < 4; ++r) o[t][r] *= al;
            bf16x8 v0, v1;
            #pragma unroll
            for (int j = 0; j < 4; ++j) {
                v0[j]     = ((const __bf16*)&a0)[j];
                v0[4 + j] = ((const __bf16*)&a1)[j];
                v1[j]     = ((const __bf16*)&b0)[j];
                v1[4 + j] = ((const __bf16*)&b1)[j];
            }
            o[t] = mfma16(v0, pf0, o[t]);
            o[t] = mfma16(v1, pf1, o[t]);
        }

        if (it + 1 < nt) {
            asm volatile("s_waitcnt vmcnt(0)" ::: "memory");
            __builtin_amdgcn_s_barrier();
        }
    }

    const float inv = 1.0f / lreg;
    u16* op = Ob + (seqb + q0w + r16) * 1024 + h * 64 + 4 * g16;
    #pragma unroll
    for (int t = 0; t < 4; ++t) {
        U4 st;
        #pragma unroll
        for (int r = 0; r < 4; ++r) st.v[r] = f2bf(o[t][r] * inv);
        *(U4*)(op + 16 * t) = st;
    }
}

// ---------- launch ----------
extern "C" void kernel_launch(void* const* d_in, const int* in_sizes, int n_in,
                              void* d_out, int out_size, void* d_ws, size_t ws_size,
                              hipStream_t stream) {
    (void)in_sizes; (void)n_in; (void)out_size; (void)ws_size;
    constexpr int C = 1024, FF = 4096, M = 2 * 2048;   // B*T = 4096
    constexpr size_t MB = 1024 * 1024;

    const float* x      = (const float*)d_in[0];
    const float* ln1_w  = (const float*)d_in[1];
    const float* ln1_b  = (const float*)d_in[2];
    const float* qkv_w  = (const float*)d_in[3];
    const float* atto_w = (const float*)d_in[4];
    const float* ln2_w  = (const float*)d_in[5];
    const float* ln2_b  = (const float*)d_in[6];
    const float* mlpi_w = (const float*)d_in[7];
    const float* mlpg_w = (const float*)d_in[8];
    const float* mlpo_w = (const float*)d_in[9];
    float* out = (float*)d_out;

    char* ws = (char*)d_ws;
    size_t off = 0;
    auto alloc = [&](size_t bytes) {
        char* p = ws + off;
        off += (bytes + 255) & ~(size_t)255;
        return p;
    };
    u16*   wq   = (u16*)  alloc((size_t)3 * C * C * 2);   // qkv_w bf16 (Q,K rows then V)
    u16*   wo   = (u16*)  alloc((size_t)C * C * 2);
    u16*   wig  = (u16*)  alloc((size_t)2 * FF * C * 2);  // interleaved wi/wg [8192][1024]
    u16*   wm   = (u16*)  alloc((size_t)C * FF * 2);
    float* x1   = (float*)alloc((size_t)M * C * 4);
    u16*   h2   = (u16*)  alloc((size_t)M * C * 2);
    u16*   ab   = (u16*)  alloc((size_t)M * FF * 2);
    // region R (64 MB): attn-phase buffers, later reused as split-K partials
    char*  R    = alloc(64 * MB);
    u16*   h1   = (u16*)R;                 //  8 MB
    u16*   qk_b = (u16*)(R + 8 * MB);      // 16 MB  [4096][2048] Q|K
    u16*   vt_b = (u16*)(R + 24 * MB);     //  8 MB  [1024][4096] V^T
    u16*   Ob   = (u16*)(R + 32 * MB);     //  8 MB
    float* pscr = (float*)R;               // 64 MB  (4 planes x 16 MB) — after attn

    // weight casts
    cast_bf16_k<<<(3 * C * C / 4) / 256, 256, 0, stream>>>(qkv_w, wq, 3 * C * C / 4);
    cast_bf16_k<<<(C * C / 4) / 256, 256, 0, stream>>>(atto_w, wo, C * C / 4);
    cast_bf16_k<<<(C * FF / 4) / 256, 256, 0, stream>>>(mlpo_w, wm, C * FF / 4);
    cast_wig_k<<<(2 * FF * C / 8) / 256, 256, 0, stream>>>(mlpi_w, mlpg_w, wig);

    // attention branch
    ln_fwd_k<<<M, 256, 0, stream>>>(x, ln1_w, ln1_b, h1);
    gemm_bt_k<0><<<dim3(2 * C / 128, M / 128), 256, 0, stream>>>(h1, wq, qk_b, nullptr, M, 2 * C, C);
    const u16* wv = wq + (size_t)2 * C * C;
    gemm_bt_k<0><<<dim3(M / 128, C / 128), 256, 0, stream>>>(wv, h1, vt_b, nullptr, C, M, C);
    attn_fwd_k<<<1024, 256, 0, stream>>>(qk_b, vt_b, Ob);
    gemm_bt_k<1><<<dim3(C / 128, M / 128), 256, 0, stream>>>(Ob, wo, x1, x, M, C, C);

    // MLP branch
    ln_fwd_k<<<M, 256, 0, stream>>>(x1, ln2_w, ln2_b, h2);
    // fused (in|gate) GEMM + SwiGLU: 256^2 pipelined, grid 32x16 = 512
    gemm256_k<2><<<dim3((2 * FF / 256) * (M / 256), 1, 1), 512, 0, stream>>>(
        h2, wig, ab, C, C, C, 2 * FF / 256, FF, 0);
    // mlp_out: 256^2 pipelined, split-K=4 (grid 4x16 x4 = 256), f32 partials
    gemm256_k<1><<<dim3((C / 256) * (M / 256), 1, 4), 512, 0, stream>>>(
        ab, wm, pscr, FF, FF, FF / 4, C / 256, C, M * C);
    addreduce4_k<<<2048, 256, 0, stream>>>(x1, pscr, out, M * C / 4, M * C);
}

// Round 6
// 304.772 us; speedup vs baseline: 2.1745x; 1.0147x over previous
//
#include <hip/hip_runtime.h>
#include <cstdint>

// ---------- types & helpers ----------
typedef unsigned short u16;
typedef __bf16 bf16x8 __attribute__((ext_vector_type(8)));
typedef float  f32x4  __attribute__((ext_vector_type(4)));

struct alignas(16) F4 { float v[4]; };
struct alignas(8)  U4 { u16 v[4]; };
struct alignas(16) U8 { u16 v[8]; };

__device__ __forceinline__ u16 f2bf(float f) {
    union { float f; unsigned int u; } x; x.f = f;
    unsigned int r = x.u + 0x7fffu + ((x.u >> 16) & 1u);   // RNE
    return (u16)(r >> 16);
}
__device__ __forceinline__ float bf2f(u16 u) {
    union { unsigned int u; float f; } x; x.u = ((unsigned int)u) << 16;
    return x.f;
}
__device__ __forceinline__ f32x4 mfma16(bf16x8 a, bf16x8 b, f32x4 c) {
    return __builtin_amdgcn_mfma_f32_16x16x32_bf16(a, b, c, 0, 0, 0);
}
__device__ __forceinline__ bf16x8 ldf(const u16* p) { return *(const bf16x8*)p; }
// async global->LDS, 16B per lane, dest = wave-uniform base + lane*16
__device__ __forceinline__ void gload_lds16(const void* g, void* l) {
    auto* gp = reinterpret_cast<const __attribute__((address_space(1))) unsigned int*>(
        reinterpret_cast<uintptr_t>(g));
    auto* lp = reinterpret_cast<__attribute__((address_space(3))) unsigned int*>(
        reinterpret_cast<uintptr_t>(l));
    __builtin_amdgcn_global_load_lds(gp, lp, 16, 0, 0);
}

// ---------- generic f32 -> bf16 cast (vector) ----------
__global__ __launch_bounds__(256) void cast_bf16_k(const float* __restrict__ in,
                                                   u16* __restrict__ out, int n4) {
    int i = blockIdx.x * 256 + threadIdx.x;
    if (i >= n4) return;
    F4 v = *(const F4*)(in + (size_t)i * 4);
    U4 o;
    #pragma unroll
    for (int j = 0; j < 4; ++j) o.v[j] = f2bf(v.v[j]);
    *(U4*)(out + (size_t)i * 4) = o;
}

// ---------- build interleaved wig: per 64-row group: 32 in rows then 32 gate rows ----------
__global__ __launch_bounds__(256) void cast_wig_k(const float* __restrict__ wi,
                                                  const float* __restrict__ wg,
                                                  u16* __restrict__ wig) {
    int i = blockIdx.x * 256 + threadIdx.x;          // over 8192 rows * 128 groups-of-8
    const int w  = i >> 7;
    const int c8 = (i & 127) * 8;
    const int f  = ((w >> 6) << 5) | (w & 31);
    const float* src = ((w & 32) ? wg : wi) + (size_t)f * 1024 + c8;
    F4 a = *(const F4*)src;
    F4 b = *(const F4*)(src + 4);
    U8 o;
    #pragma unroll
    for (int j = 0; j < 4; ++j) { o.v[j] = f2bf(a.v[j]); o.v[4 + j] = f2bf(b.v[j]); }
    *(U8*)(wig + (size_t)w * 1024 + c8) = o;
}

// ---------- LayerNorm (C=1024), f32 in -> bf16 out ----------
__global__ __launch_bounds__(256) void ln_fwd_k(const float* __restrict__ x,
                                                const float* __restrict__ w,
                                                const float* __restrict__ b,
                                                u16* __restrict__ h) {
    const int row = blockIdx.x, tid = threadIdx.x;
    const float* xr = x + (size_t)row * 1024;
    F4 v = *(const F4*)(xr + tid * 4);
    float s  = v.v[0] + v.v[1] + v.v[2] + v.v[3];
    float ss = v.v[0]*v.v[0] + v.v[1]*v.v[1] + v.v[2]*v.v[2] + v.v[3]*v.v[3];
    #pragma unroll
    for (int o = 32; o > 0; o >>= 1) { s += __shfl_down(s, o); ss += __shfl_down(ss, o); }
    __shared__ float red[8];
    const int wave = tid >> 6, lane = tid & 63;
    if (lane == 0) { red[wave] = s; red[4 + wave] = ss; }
    __syncthreads();
    s  = red[0] + red[1] + red[2] + red[3];
    ss = red[4] + red[5] + red[6] + red[7];
    const float mu   = s * (1.0f / 1024.0f);
    const float var  = ss * (1.0f / 1024.0f) - mu * mu;
    const float rstd = rsqrtf(var + 1e-5f);
    U4 o;
    #pragma unroll
    for (int j = 0; j < 4; ++j)
        o.v[j] = f2bf((v.v[j] - mu) * rstd * w[tid * 4 + j] + b[tid * 4 + j]);
    *(U4*)(h + (size_t)row * 1024 + tid * 4) = o;
}

// ---------- 128x128 GEMM (m97 structure), kept for qk / vt / attn_out ----------
template <int MODE>
__global__ __launch_bounds__(256) void gemm_bt_k(const u16* __restrict__ A,
                                                 const u16* __restrict__ Bm,
                                                 void* __restrict__ Cout,
                                                 const float* __restrict__ resid,
                                                 int M, int N, int K) {
    __shared__ u16 Alds[128 * 32];
    __shared__ u16 Blds[128 * 32];
    const int tid  = threadIdx.x;
    const int lane = tid & 63, wave = tid >> 6;
    const int wr = wave >> 1, wc = wave & 1;
    const int r16 = lane & 15, g16 = lane >> 4;
    const int bn = blockIdx.x, bm = blockIdx.y;

    const int srow = lane >> 2;
    const int scol = (lane & 3) * 8;

    f32x4 acc[4][4] = {};

    for (int k0 = 0; k0 < K; k0 += 32) {
        #pragma unroll
        for (int c = 0; c < 2; ++c) {
            const int ch = wave * 2 + c;
            const u16* ga = A  + ((size_t)bm * 128 + ch * 16 + srow) * K + k0 + scol;
            gload_lds16(ga, &Alds[ch * 512]);
            const u16* gb = Bm + ((size_t)bn * 128 + ch * 16 + srow) * K + k0 + scol;
            gload_lds16(gb, &Blds[ch * 512]);
        }
        __syncthreads();
        bf16x8 af[4], bfr[4];
        #pragma unroll
        for (int m = 0; m < 4; ++m)
            af[m] = *(const bf16x8*)&Alds[(wr * 64 + m * 16 + r16) * 32 + g16 * 8];
        #pragma unroll
        for (int n = 0; n < 4; ++n)
            bfr[n] = *(const bf16x8*)&Blds[(wc * 64 + n * 16 + r16) * 32 + g16 * 8];
        #pragma unroll
        for (int m = 0; m < 4; ++m)
            #pragma unroll
            for (int n = 0; n < 4; ++n)
                acc[m][n] = mfma16(af[m], bfr[n], acc[m][n]);
        __syncthreads();
    }

    #pragma unroll
    for (int m = 0; m < 4; ++m) {
        #pragma unroll
        for (int n = 0; n < 4; ++n) {
            #pragma unroll
            for (int r = 0; r < 4; ++r) {
                const int row = bm * 128 + wr * 64 + m * 16 + g16 * 4 + r;
                const int col = bn * 128 + wc * 64 + n * 16 + r16;
                const float v = acc[m][n][r];
                if (MODE == 0) {
                    ((u16*)Cout)[(size_t)row * N + col] = f2bf(v);
                } else {
                    ((float*)Cout)[(size_t)row * N + col] =
                        resid[(size_t)row * N + col] + v;
                }
            }
        }
    }
}

// ---------- 256x256 8-phase pipelined GEMM (T2+T3+T4+T5, m201-style) ----------
// C = A[M,K]*B[N,K]^T. 512 thr = 8 waves (2M x 4N); wave tile 128x64; BK=64.
// LDS: 2 dbuf x {A,B} x {half0,half1} x 16KB = 128 KiB.
//   A-half h = rows with ((row>>6)&1)==h  (each wave's m-frags h*4..h*4+3)
//   B-half h = rows with ((row>>5)&1)==h  (each wave's n-frags h*2..h*2+1)
// 4 quadrant-phases per K-tile: q0 {rd A0+B0, stage B1(kt+1), mfma m0-3 x n0-1}
//   q1 {rd B1, stage A1(kt+1), mfma m0-3 x n2-3}  q2 {rd A1, stage A0(kt+2),
//   mfma m4-7 x n0-1}  q3 {stage B0(kt+2), mfma m4-7 x n2-3, vmcnt(4)}.
// Swizzle: 16B chunk c of within-half row r stored at c ^ (r&7); staging uses
// inverse-swizzled global source (both-sides rule).
// EPI 1: f32 partials (plane blockIdx.z).  EPI 2: fused SwiGLU bf16 (wig interleave).
template <int EPI>
__global__ __launch_bounds__(512, 2)
void gemm256_k(const u16* __restrict__ A, const u16* __restrict__ Bm,
               void* __restrict__ Cout, int lda, int ldb, int kLen,
               int nx, int outLd, int planeEls) {
    __shared__ u16 lds[2][2][2][128 * 64];

    const int tid  = threadIdx.x;
    const int wave = tid >> 6, lane = tid & 63;
    const int wm = wave >> 2, wn = wave & 3;
    const int r16 = lane & 15, g16 = lane >> 4;

    const int cpx = gridDim.x >> 3;
    const int swz = (blockIdx.x & 7) * cpx + (blockIdx.x >> 3);
    const int bn = swz % nx, bm = swz / nx;
    const int kBeg = blockIdx.z * kLen;
    const int NT = kLen >> 6;

    // staging sources (pre-swizzled). lane l covers within-half rows
    // wave*16 + i*8 + (l>>3), 16B chunk (l&7) ^ (l>>3).
    const int wr0 = wave * 16 + (lane >> 3);
    const int csw = ((lane & 7) ^ (lane >> 3)) * 8;
    const u16* aP[2][2]; const u16* bP[2][2];
    #pragma unroll
    for (int h = 0; h < 2; ++h) {
        #pragma unroll
        for (int i = 0; i < 2; ++i) {
            const int wr = wr0 + i * 8;
            const int ar = (wr >> 6) * 128 + h * 64 + (wr & 63);
            const int br = (wr >> 5) * 64 + h * 32 + (wr & 31);
            aP[h][i] = A  + (size_t)(bm * 256 + ar) * lda + kBeg + csw;
            bP[h][i] = Bm + (size_t)(bn * 256 + br) * ldb + kBeg + csw;
        }
    }

    auto stA = [&](int kt, int h) {
        u16* d = &lds[kt & 1][0][h][wave * 1024];
        gload_lds16(aP[h][0] + kt * 64, d);
        gload_lds16(aP[h][1] + kt * 64, d + 512);
    };
    auto stB = [&](int kt, int h) {
        u16* d = &lds[kt & 1][1][h][wave * 1024];
        gload_lds16(bP[h][0] + kt * 64, d);
        gload_lds16(bP[h][1] + kt * 64, d + 512);
    };

    // frag read offsets within a half (u16 units); row-swizzled chunks
    int offA[4][2], offB[2][2];
    #pragma unroll
    for (int m = 0; m < 4; ++m)
        #pragma unroll
        for (int ks = 0; ks < 2; ++ks)
            offA[m][ks] = (wm * 64 + m * 16 + r16) * 64 + (((ks * 4 + g16) ^ (r16 & 7)) * 8);
    #pragma unroll
    for (int n = 0; n < 2; ++n)
        #pragma unroll
        for (int ks = 0; ks < 2; ++ks)
            offB[n][ks] = (wn * 32 + n * 16 + r16) * 64 + (((ks * 4 + g16) ^ (r16 & 7)) * 8);

    f32x4 acc[8][4] = {};

    // prologue: stage A0(0) B0(0) B1(0) A1(0) A0(1) B0(1); retire first 4 half-tiles
    stA(0, 0); stB(0, 0); stB(0, 1); stA(0, 1);
    if (NT > 1) {
        stA(1, 0); stB(1, 0);
        asm volatile("s_waitcnt vmcnt(4)" ::: "memory");
    } else {
        asm volatile("s_waitcnt vmcnt(0)" ::: "memory");
    }
    __builtin_amdgcn_s_barrier();

    for (int kt = 0; kt < NT; ++kt) {
        const int buf = kt & 1;
        const u16* A0 = &lds[buf][0][0][0];
        const u16* A1 = &lds[buf][0][1][0];
        const u16* B0 = &lds[buf][1][0][0];
        const u16* B1 = &lds[buf][1][1][0];
        bf16x8 af[4][2], b0[2][2], b1[2][2];

        // ---- q0: read A-half0 + B-half0; stage B1(kt+1); mfma m0-3 x n0-1 ----
        #pragma unroll
        for (int m = 0; m < 4; ++m) {
            af[m][0] = ldf(A0 + offA[m][0]);
            af[m][1] = ldf(A0 + offA[m][1]);
        }
        #pragma unroll
        for (int n = 0; n < 2; ++n) {
            b0[n][0] = ldf(B0 + offB[n][0]);
            b0[n][1] = ldf(B0 + offB[n][1]);
        }
        if (kt + 1 < NT) stB(kt + 1, 1);
        __builtin_amdgcn_s_barrier();
        asm volatile("s_waitcnt lgkmcnt(0)" ::: "memory");
        __builtin_amdgcn_s_setprio(1);
        #pragma unroll
        for (int m = 0; m < 4; ++m)
            #pragma unroll
            for (int n = 0; n < 2; ++n) {
                acc[m][n] = mfma16(af[m][0], b0[n][0], acc[m][n]);
                acc[m][n] = mfma16(af[m][1], b0[n][1], acc[m][n]);
            }
        __builtin_amdgcn_s_setprio(0);
        __builtin_amdgcn_s_barrier();

        // ---- q1: read B-half1; stage A1(kt+1); mfma m0-3 x n2-3 ----
        #pragma unroll
        for (int n = 0; n < 2; ++n) {
            b1[n][0] = ldf(B1 + offB[n][0]);
            b1[n][1] = ldf(B1 + offB[n][1]);
        }
        if (kt + 1 < NT) stA(kt + 1, 1);
        __builtin_amdgcn_s_barrier();
        asm volatile("s_waitcnt lgkmcnt(0)" ::: "memory");
        __builtin_amdgcn_s_setprio(1);
        #pragma unroll
        for (int m = 0; m < 4; ++m)
            #pragma unroll
            for (int n = 0; n < 2; ++n) {
                acc[m][n + 2] = mfma16(af[m][0], b1[n][0], acc[m][n + 2]);
                acc[m][n + 2] = mfma16(af[m][1], b1[n][1], acc[m][n + 2]);
            }
        __builtin_amdgcn_s_setprio(0);
        __builtin_amdgcn_s_barrier();

        // ---- q2: read A-half1; stage A0(kt+2); mfma m4-7 x n0-1 ----
        #pragma unroll
        for (int m = 0; m < 4; ++m) {
            af[m][0] = ldf(A1 + offA[m][0]);
            af[m][1] = ldf(A1 + offA[m][1]);
        }
        if (kt + 2 < NT) stA(kt + 2, 0);
        __builtin_amdgcn_s_barrier();
        asm volatile("s_waitcnt lgkmcnt(0)" ::: "memory");
        __builtin_amdgcn_s_setprio(1);
        #pragma unroll
        for (int m = 0; m < 4; ++m)
            #pragma unroll
            for (int n = 0; n < 2; ++n) {
                acc[m + 4][n] = mfma16(af[m][0], b0[n][0], acc[m + 4][n]);
                acc[m + 4][n] = mfma16(af[m][1], b0[n][1], acc[m + 4][n]);
            }
        __builtin_amdgcn_s_setprio(0);
        __builtin_amdgcn_s_barrier();

        // ---- q3: stage B0(kt+2); mfma m4-7 x n2-3; counted vmcnt ----
        if (kt + 2 < NT) stB(kt + 2, 0);
        __builtin_amdgcn_s_barrier();
        __builtin_amdgcn_s_setprio(1);
        #pragma unroll
        for (int m = 0; m < 4; ++m)
            #pragma unroll
            for (int n = 0; n < 2; ++n) {
                acc[m + 4][n + 2] = mfma16(af[m][0], b1[n][0], acc[m + 4][n + 2]);
                acc[m + 4][n + 2] = mfma16(af[m][1], b1[n][1], acc[m + 4][n + 2]);
            }
        __builtin_amdgcn_s_setprio(0);
        if (kt + 2 < NT) { asm volatile("s_waitcnt vmcnt(4)" ::: "memory"); }
        else             { asm volatile("s_waitcnt vmcnt(0)" ::: "memory"); }
        __builtin_amdgcn_s_barrier();
    }

    if constexpr (EPI == 1) {
        float* P = (float*)Cout + (size_t)blockIdx.z * planeEls;
        #pragma unroll
        for (int m = 0; m < 8; ++m) {
            #pragma unroll
            for (int n = 0; n < 4; ++n) {
                #pragma unroll
                for (int r = 0; r < 4; ++r) {
                    const int row = bm * 256 + wm * 128 + m * 16 + g16 * 4 + r;
                    const int col = bn * 256 + wn * 64 + n * 16 + r16;
                    P[(size_t)row * outLd + col] = acc[m][n][r];
                }
            }
        }
    } else {
        (void)planeEls;
        u16* O = (u16*)Cout;
        #pragma unroll
        for (int m = 0; m < 8; ++m) {
            #pragma unroll
            for (int n = 0; n < 2; ++n) {
                #pragma unroll
                for (int r = 0; r < 4; ++r) {
                    const int row = bm * 256 + wm * 128 + m * 16 + g16 * 4 + r;
                    const int col = (bn * 4 + wn) * 32 + n * 16 + r16;
                    const float vi = acc[m][n][r];
                    const float vg = acc[m][n + 2][r];
                    const float sl = vi / (1.0f + __expf(-vi));
                    O[(size_t)row * outLd + col] = f2bf(sl * vg);
                }
            }
        }
    }
}

// ---------- split-K reduce: out = resid + p0+p1+p2+p3 ----------
__global__ __launch_bounds__(256) void addreduce4_k(const float* __restrict__ resid,
                                                    const float* __restrict__ p,
                                                    float* __restrict__ out,
                                                    int n4, int planeEls) {
    for (int i = blockIdx.x * 256 + threadIdx.x; i < n4; i += gridDim.x * 256) {
        F4 a = *(const F4*)(resid + (size_t)i * 4);
        F4 b = *(const F4*)(p + (size_t)i * 4);
        F4 c = *(const F4*)(p + (size_t)planeEls + (size_t)i * 4);
        F4 d = *(const F4*)(p + (size_t)2 * planeEls + (size_t)i * 4);
        F4 e = *(const F4*)(p + (size_t)3 * planeEls + (size_t)i * 4);
        F4 o;
        #pragma unroll
        for (int j = 0; j < 4; ++j) o.v[j] = a.v[j] + b.v[j] + c.v[j] + d.v[j] + e.v[j];
        *(F4*)(out + (size_t)i * 4) = o;
    }
}

// ---------- flash attention v3 (causal), transpose-world + LDS-staged K/V ----------
__global__ __launch_bounds__(256) void attn_fwd_k(const u16* __restrict__ qk,
                                                  const u16* __restrict__ vt,
                                                  u16* __restrict__ Ob) {
    __shared__ u16 Klds[2][64 * 64];
    __shared__ u16 Vlds[2][64 * 64];

    const int tid  = threadIdx.x;
    const int wave = tid >> 6, lane = tid & 63;
    const int r16  = lane & 15, g16 = lane >> 4;

    const int blk = blockIdx.x;
    const int xcd = blk & 7;
    const int pc  = blk >> 3;
    const int hh  = pc >> 5;
    const int qb  = (31 - (pc & 31) + 8 * hh) & 31;
    const int bh  = xcd * 4 + hh;
    const int h   = bh & 15, b = bh >> 4;

    const int q0w = qb * 64 + wave * 16;
    const size_t seqb = (size_t)b * 2048;

    const u16* qp = qk + (seqb + q0w + r16) * 2048 + h * 64 + g16 * 8;
    const bf16x8 qf0 = *(const bf16x8*)qp;
    const bf16x8 qf1 = *(const bf16x8*)(qp + 32);

    const u16* kbase = qk + seqb * 2048 + 1024 + (size_t)h * 64;
    const u16* vbase = vt + (size_t)(h * 64) * 4096 + seqb;

    const int srow  = tid >> 3;                           // 0..31
    const int scol8 = ((tid & 7) ^ (srow & 7)) * 8;
    const u16* ksrc = kbase + (size_t)srow * 2048 + scol8;
    const u16* vsrc = vbase + (size_t)srow * 4096 + scol8;

    auto stage = [&](int bufi, int kv0) {
        const u16* kp = ksrc + (size_t)kv0 * 2048;
        const u16* vp = vsrc + kv0;
        u16* kd = &Klds[bufi][wave * 512];
        u16* vd = &Vlds[bufi][wave * 512];
        gload_lds16(kp, kd);
        gload_lds16(kp + (size_t)32 * 2048, kd + 2048);
        gload_lds16(vp, vd);
        gload_lds16(vp + (size_t)32 * 4096, vd + 2048);
    };

    f32x4 o[4] = {};
    float mreg = -3.0e38f, lreg = 0.0f;
    constexpr float SC = 0.125f * 1.44269504088896341f;   // Dh^-0.5 * log2(e)

    const int nt = qb + 1;
    stage(0, 0);
    asm volatile("s_waitcnt vmcnt(0)" ::: "memory");
    __builtin_amdgcn_s_barrier();

    for (int it = 0; it < nt; ++it) {
        const int kv0 = it * 64;
        const int cur = it & 1;
        if (it + 1 < nt) stage(cur ^ 1, kv0 + 64);

        const u16* K = Klds[cur];
        const u16* V = Vlds[cur];

        f32x4 s[4];
        #pragma unroll
        for (int t = 0; t < 4; ++t) {
            const int row = 16 * t + r16;
            const int sw  = row & 7;
            const bf16x8 k0 = *(const bf16x8*)&K[row * 64 + ((g16 ^ sw) * 8)];
            const bf16x8 k1 = *(const bf16x8*)&K[row * 64 + (((g16 + 4) ^ sw) * 8)];
            f32x4 acc = {0.f, 0.f, 0.f, 0.f};
            acc = mfma16(k0, qf0, acc);
            acc = mfma16(k1, qf1, acc);
            s[t] = acc;
        }

        float a[16];
        #pragma unroll
        for (int t = 0; t < 4; ++t)
            #pragma unroll
            for (int r = 0; r < 4; ++r) a[4 * t + r] = s[t][r] * SC;

        if (kv0 + 63 > q0w) {
            const int qg = q0w + r16;
            #pragma unroll
            for (int t = 0; t < 4; ++t)
                #pragma unroll
                for (int r = 0; r < 4; ++r)
                    if (kv0 + 16 * t + 4 * g16 + r > qg) a[4 * t + r] = -1.0e30f;
        }

        float mx = a[0];
        #pragma unroll
        for (int j = 1; j < 16; ++j) mx = fmaxf(mx, a[j]);
        mx = fmaxf(mx, __shfl_xor(mx, 16));
        mx = fmaxf(mx, __shfl_xor(mx, 32));
        const float mn = fmaxf(mreg, mx);
        const float al = exp2f(mreg - mn);
        float p[16], rs = 0.0f;
        #pragma unroll
        for (int j = 0; j < 16; ++j) { p[j] = exp2f(a[j] - mn); rs += p[j]; }
        rs += __shfl_xor(rs, 16);
        rs += __shfl_xor(rs, 32);
        lreg = lreg * al + rs;
        mreg = mn;

        bf16x8 pf0, pf1;
        #pragma unroll
        for (int j = 0; j < 8; ++j) { pf0[j] = (__bf16)p[j]; pf1[j] = (__bf16)p[8 + j]; }

        #pragma unroll
        for (int t = 0; t < 4; ++t) {
            const int row  = 16 * t + r16;
            const int sw   = row & 7;
            const int base = row * 64 + (g16 & 1) * 4;
            const int c0   = g16 >> 1;
            U4 a0 = *(const U4*)&V[base + (((c0 + 0) ^ sw) * 8)];
            U4 a1 = *(const U4*)&V[base + (((c0 + 2) ^ sw) * 8)];
            U4 b0 = *(const U4*)&V[base + (((c0 + 4) ^ sw) * 8)];
            U4 b1 = *(const U4*)&V[base + (((c0 + 6) ^ sw) * 8)];
            #pragma unroll
            for (int r = 0; r < 4; ++r) o[t][r] *= al;
            bf16x8 v0, v1;
            #pragma unroll
            for (int j = 0; j < 4; ++j) {
                v0[j]     = ((const __bf16*)&a0)[j];
                v0[4 + j] = ((const __bf16*)&a1)[j];
                v1[j]     = ((const __bf16*)&b0)[j];
                v1[4 + j] = ((const __bf16*)&b1)[j];
            }
            o[t] = mfma16(v0, pf0, o[t]);
            o[t] = mfma16(v1, pf1, o[t]);
        }

        if (it + 1 < nt) {
            asm volatile("s_waitcnt vmcnt(0)" ::: "memory");
            __builtin_amdgcn_s_barrier();
        }
    }

    const float inv = 1.0f / lreg;
    u16* op = Ob + (seqb + q0w + r16) * 1024 + h * 64 + 4 * g16;
    #pragma unroll
    for (int t = 0; t < 4; ++t) {
        U4 st;
        #pragma unroll
        for (int r = 0; r < 4; ++r) st.v[r] = f2bf(o[t][r] * inv);
        *(U4*)(op + 16 * t) = st;
    }
}

// ---------- launch ----------
extern "C" void kernel_launch(void* const* d_in, const int* in_sizes, int n_in,
                              void* d_out, int out_size, void* d_ws, size_t ws_size,
                              hipStream_t stream) {
    (void)in_sizes; (void)n_in; (void)out_size; (void)ws_size;
    constexpr int C = 1024, FF = 4096, M = 2 * 2048;   // B*T = 4096
    constexpr size_t MB = 1024 * 1024;

    const float* x      = (const float*)d_in[0];
    const float* ln1_w  = (const float*)d_in[1];
    const float* ln1_b  = (const float*)d_in[2];
    const float* qkv_w  = (const float*)d_in[3];
    const float* atto_w = (const float*)d_in[4];
    const float* ln2_w  = (const float*)d_in[5];
    const float* ln2_b  = (const float*)d_in[6];
    const float* mlpi_w = (const float*)d_in[7];
    const float* mlpg_w = (const float*)d_in[8];
    const float* mlpo_w = (const float*)d_in[9];
    float* out = (float*)d_out;

    char* ws = (char*)d_ws;
    size_t off = 0;
    auto alloc = [&](size_t bytes) {
        char* p = ws + off;
        off += (bytes + 255) & ~(size_t)255;
        return p;
    };
    u16*   wq   = (u16*)  alloc((size_t)3 * C * C * 2);   // qkv_w bf16 (Q,K rows then V)
    u16*   wo   = (u16*)  alloc((size_t)C * C * 2);
    u16*   wig  = (u16*)  alloc((size_t)2 * FF * C * 2);  // interleaved wi/wg [8192][1024]
    u16*   wm   = (u16*)  alloc((size_t)C * FF * 2);
    float* x1   = (float*)alloc((size_t)M * C * 4);
    u16*   h2   = (u16*)  alloc((size_t)M * C * 2);
    u16*   ab   = (u16*)  alloc((size_t)M * FF * 2);
    // region R (64 MB): attn-phase buffers, later reused as split-K partials
    char*  R    = alloc(64 * MB);
    u16*   h1   = (u16*)R;                 //  8 MB
    u16*   qk_b = (u16*)(R + 8 * MB);      // 16 MB  [4096][2048] Q|K
    u16*   vt_b = (u16*)(R + 24 * MB);     //  8 MB  [1024][4096] V^T
    u16*   Ob   = (u16*)(R + 32 * MB);     //  8 MB
    float* pscr = (float*)R;               // 64 MB  (4 planes x 16 MB) — after attn

    // weight casts
    cast_bf16_k<<<(3 * C * C / 4) / 256, 256, 0, stream>>>(qkv_w, wq, 3 * C * C / 4);
    cast_bf16_k<<<(C * C / 4) / 256, 256, 0, stream>>>(atto_w, wo, C * C / 4);
    cast_bf16_k<<<(C * FF / 4) / 256, 256, 0, stream>>>(mlpo_w, wm, C * FF / 4);
    cast_wig_k<<<(2 * FF * C / 8) / 256, 256, 0, stream>>>(mlpi_w, mlpg_w, wig);

    // attention branch
    ln_fwd_k<<<M, 256, 0, stream>>>(x, ln1_w, ln1_b, h1);
    gemm_bt_k<0><<<dim3(2 * C / 128, M / 128), 256, 0, stream>>>(h1, wq, qk_b, nullptr, M, 2 * C, C);
    const u16* wv = wq + (size_t)2 * C * C;
    gemm_bt_k<0><<<dim3(M / 128, C / 128), 256, 0, stream>>>(wv, h1, vt_b, nullptr, C, M, C);
    attn_fwd_k<<<1024, 256, 0, stream>>>(qk_b, vt_b, Ob);
    gemm_bt_k<1><<<dim3(C / 128, M / 128), 256, 0, stream>>>(Ob, wo, x1, x, M, C, C);

    // MLP branch
    ln_fwd_k<<<M, 256, 0, stream>>>(x1, ln2_w, ln2_b, h2);
    // fused (in|gate) GEMM + SwiGLU: 256^2 8-phase, grid 32x16 = 512
    gemm256_k<2><<<dim3((2 * FF / 256) * (M / 256), 1, 1), 512, 0, stream>>>(
        h2, wig, ab, C, C, C, 2 * FF / 256, FF, 0);
    // mlp_out: 256^2 8-phase, split-K=4 (grid 4x16 x4 = 256), f32 partials
    gemm256_k<1><<<dim3((C / 256) * (M / 256), 1, 4), 512, 0, stream>>>(
        ab, wm, pscr, FF, FF, FF / 4, C / 256, C, M * C);
    addreduce4_k<<<2048, 256, 0, stream>>>(x1, pscr, out, M * C / 4, M * C);
}

// Round 7
// 297.416 us; speedup vs baseline: 2.2283x; 1.0247x over previous
//
#include <hip/hip_runtime.h>
#include <cstdint>

// ---------- types & helpers ----------
typedef unsigned short u16;
typedef __bf16 bf16x8 __attribute__((ext_vector_type(8)));
typedef float  f32x4  __attribute__((ext_vector_type(4)));

struct alignas(16) F4 { float v[4]; };
struct alignas(8)  U4 { u16 v[4]; };
struct alignas(16) U8 { u16 v[8]; };

__device__ __forceinline__ u16 f2bf(float f) {
    union { float f; unsigned int u; } x; x.f = f;
    unsigned int r = x.u + 0x7fffu + ((x.u >> 16) & 1u);   // RNE
    return (u16)(r >> 16);
}
__device__ __forceinline__ float bf2f(u16 u) {
    union { unsigned int u; float f; } x; x.u = ((unsigned int)u) << 16;
    return x.f;
}
__device__ __forceinline__ f32x4 mfma16(bf16x8 a, bf16x8 b, f32x4 c) {
    return __builtin_amdgcn_mfma_f32_16x16x32_bf16(a, b, c, 0, 0, 0);
}
__device__ __forceinline__ bf16x8 ldf(const u16* p) { return *(const bf16x8*)p; }
// async global->LDS, 16B per lane, dest = wave-uniform base + lane*16
__device__ __forceinline__ void gload_lds16(const void* g, void* l) {
    auto* gp = reinterpret_cast<const __attribute__((address_space(1))) unsigned int*>(
        reinterpret_cast<uintptr_t>(g));
    auto* lp = reinterpret_cast<__attribute__((address_space(3))) unsigned int*>(
        reinterpret_cast<uintptr_t>(l));
    __builtin_amdgcn_global_load_lds(gp, lp, 16, 0, 0);
}

// ---------- generic f32 -> bf16 cast (vector) ----------
__global__ __launch_bounds__(256) void cast_bf16_k(const float* __restrict__ in,
                                                   u16* __restrict__ out, int n4) {
    int i = blockIdx.x * 256 + threadIdx.x;
    if (i >= n4) return;
    F4 v = *(const F4*)(in + (size_t)i * 4);
    U4 o;
    #pragma unroll
    for (int j = 0; j < 4; ++j) o.v[j] = f2bf(v.v[j]);
    *(U4*)(out + (size_t)i * 4) = o;
}

// ---------- build interleaved wig: per 64-row group: 32 in rows then 32 gate rows ----------
__global__ __launch_bounds__(256) void cast_wig_k(const float* __restrict__ wi,
                                                  const float* __restrict__ wg,
                                                  u16* __restrict__ wig) {
    int i = blockIdx.x * 256 + threadIdx.x;          // over 8192 rows * 128 groups-of-8
    const int w  = i >> 7;
    const int c8 = (i & 127) * 8;
    const int f  = ((w >> 6) << 5) | (w & 31);
    const float* src = ((w & 32) ? wg : wi) + (size_t)f * 1024 + c8;
    F4 a = *(const F4*)src;
    F4 b = *(const F4*)(src + 4);
    U8 o;
    #pragma unroll
    for (int j = 0; j < 4; ++j) { o.v[j] = f2bf(a.v[j]); o.v[4 + j] = f2bf(b.v[j]); }
    *(U8*)(wig + (size_t)w * 1024 + c8) = o;
}

// ---------- LayerNorm (C=1024), f32 in -> bf16 out ----------
__global__ __launch_bounds__(256) void ln_fwd_k(const float* __restrict__ x,
                                                const float* __restrict__ w,
                                                const float* __restrict__ b,
                                                u16* __restrict__ h) {
    const int row = blockIdx.x, tid = threadIdx.x;
    const float* xr = x + (size_t)row * 1024;
    F4 v = *(const F4*)(xr + tid * 4);
    float s  = v.v[0] + v.v[1] + v.v[2] + v.v[3];
    float ss = v.v[0]*v.v[0] + v.v[1]*v.v[1] + v.v[2]*v.v[2] + v.v[3]*v.v[3];
    #pragma unroll
    for (int o = 32; o > 0; o >>= 1) { s += __shfl_down(s, o); ss += __shfl_down(ss, o); }
    __shared__ float red[8];
    const int wave = tid >> 6, lane = tid & 63;
    if (lane == 0) { red[wave] = s; red[4 + wave] = ss; }
    __syncthreads();
    s  = red[0] + red[1] + red[2] + red[3];
    ss = red[4] + red[5] + red[6] + red[7];
    const float mu   = s * (1.0f / 1024.0f);
    const float var  = ss * (1.0f / 1024.0f) - mu * mu;
    const float rstd = rsqrtf(var + 1e-5f);
    U4 o;
    #pragma unroll
    for (int j = 0; j < 4; ++j)
        o.v[j] = f2bf((v.v[j] - mu) * rstd * w[tid * 4 + j] + b[tid * 4 + j]);
    *(U4*)(h + (size_t)row * 1024 + tid * 4) = o;
}

// ---------- 128x128 GEMM (m97 structure), kept for qk / vt / attn_out ----------
template <int MODE>
__global__ __launch_bounds__(256) void gemm_bt_k(const u16* __restrict__ A,
                                                 const u16* __restrict__ Bm,
                                                 void* __restrict__ Cout,
                                                 const float* __restrict__ resid,
                                                 int M, int N, int K) {
    __shared__ u16 Alds[128 * 32];
    __shared__ u16 Blds[128 * 32];
    const int tid  = threadIdx.x;
    const int lane = tid & 63, wave = tid >> 6;
    const int wr = wave >> 1, wc = wave & 1;
    const int r16 = lane & 15, g16 = lane >> 4;
    const int bn = blockIdx.x, bm = blockIdx.y;

    const int srow = lane >> 2;
    const int scol = (lane & 3) * 8;

    f32x4 acc[4][4] = {};

    for (int k0 = 0; k0 < K; k0 += 32) {
        #pragma unroll
        for (int c = 0; c < 2; ++c) {
            const int ch = wave * 2 + c;
            const u16* ga = A  + ((size_t)bm * 128 + ch * 16 + srow) * K + k0 + scol;
            gload_lds16(ga, &Alds[ch * 512]);
            const u16* gb = Bm + ((size_t)bn * 128 + ch * 16 + srow) * K + k0 + scol;
            gload_lds16(gb, &Blds[ch * 512]);
        }
        __syncthreads();
        bf16x8 af[4], bfr[4];
        #pragma unroll
        for (int m = 0; m < 4; ++m)
            af[m] = *(const bf16x8*)&Alds[(wr * 64 + m * 16 + r16) * 32 + g16 * 8];
        #pragma unroll
        for (int n = 0; n < 4; ++n)
            bfr[n] = *(const bf16x8*)&Blds[(wc * 64 + n * 16 + r16) * 32 + g16 * 8];
        #pragma unroll
        for (int m = 0; m < 4; ++m)
            #pragma unroll
            for (int n = 0; n < 4; ++n)
                acc[m][n] = mfma16(af[m], bfr[n], acc[m][n]);
        __syncthreads();
    }

    #pragma unroll
    for (int m = 0; m < 4; ++m) {
        #pragma unroll
        for (int n = 0; n < 4; ++n) {
            #pragma unroll
            for (int r = 0; r < 4; ++r) {
                const int row = bm * 128 + wr * 64 + m * 16 + g16 * 4 + r;
                const int col = bn * 128 + wc * 64 + n * 16 + r16;
                const float v = acc[m][n][r];
                if (MODE == 0) {
                    ((u16*)Cout)[(size_t)row * N + col] = f2bf(v);
                } else {
                    ((float*)Cout)[(size_t)row * N + col] =
                        resid[(size_t)row * N + col] + v;
                }
            }
        }
    }
}

// ---------- 256x256 pipelined GEMM v2 (deep stage, vmcnt(8), 1 barrier/phase) ----------
// C = A[M,K]*B[N,K]^T. 512 thr = 8 waves (2M x 4N); wave tile 128x64; BK=64.
// LDS: 2 dbuf x {A,B} x {half0,half1} x 16KB = 128 KiB.
// Per kt (4 phases, ONE barrier each; per-wave data waits are compiler-auto lgkm):
//   q0: rd A0+B0 (12 b128)                 | MFMA m0-3 x n0-1 | bar
//   q1: rd B1 (4); stage A0,B0(kt+2)       | MFMA m0-3 x n2-3 | bar
//   q2: rd A1 (8); stage B1(kt+2)          | MFMA m4-7 x n0-1 | bar
//   q3: stage A1(kt+2)                     | MFMA m4-7 x n2-3 | vmcnt(8) bar
// vmcnt(8) retires kt+1's 4 half-tiles (issued during kt-1, 5-7 phases old).
// Slot-WAR safety: each slot's readers finish (per-wave data wait) before the
// end-of-phase barrier that precedes the overwrite phase.
// 2D XCD chunking: per XCD (cpx/bnCh) bm-rows x bnCh bn-cols, bm-outer.
// EPI 1: f32 partials (plane blockIdx.z).  EPI 2: fused SwiGLU bf16 (wig interleave).
template <int EPI>
__global__ __launch_bounds__(512, 2)
void gemm256_k(const u16* __restrict__ A, const u16* __restrict__ Bm,
               void* __restrict__ Cout, int lda, int ldb, int kLen,
               int nx, int bnCh, int outLd, int planeEls) {
    __shared__ u16 lds[2][2][2][128 * 64];

    const int tid  = threadIdx.x;
    const int wave = tid >> 6, lane = tid & 63;
    const int wm = wave >> 2, wn = wave & 3;
    const int r16 = lane & 15, g16 = lane >> 4;

    // 2D XCD chunking (gridDim.x % 8 == 0; nx % bnCh == 0; cpx % bnCh == 0)
    const int cpx = gridDim.x >> 3;
    const int xcd = blockIdx.x & 7, loc = blockIdx.x >> 3;
    const int mCh = cpx / bnCh;
    const int cpr = nx / bnCh;                 // chunk-cols
    const int bm = (xcd / cpr) * mCh + loc / bnCh;
    const int bn = (xcd % cpr) * bnCh + loc % bnCh;
    const int kBeg = blockIdx.z * kLen;
    const int NT = kLen >> 6;

    // staging sources (pre-swizzled). lane l covers within-half rows
    // wave*16 + i*8 + (l>>3), 16B chunk (l&7) ^ (l>>3).
    const int wr0 = wave * 16 + (lane >> 3);
    const int csw = ((lane & 7) ^ (lane >> 3)) * 8;
    const u16* aP[2][2]; const u16* bP[2][2];
    #pragma unroll
    for (int h = 0; h < 2; ++h) {
        #pragma unroll
        for (int i = 0; i < 2; ++i) {
            const int wr = wr0 + i * 8;
            const int ar = (wr >> 6) * 128 + h * 64 + (wr & 63);
            const int br = (wr >> 5) * 64 + h * 32 + (wr & 31);
            aP[h][i] = A  + (size_t)(bm * 256 + ar) * lda + kBeg + csw;
            bP[h][i] = Bm + (size_t)(bn * 256 + br) * ldb + kBeg + csw;
        }
    }

    auto stA = [&](int kt, int h) {
        u16* d = &lds[kt & 1][0][h][wave * 1024];
        gload_lds16(aP[h][0] + kt * 64, d);
        gload_lds16(aP[h][1] + kt * 64, d + 512);
    };
    auto stB = [&](int kt, int h) {
        u16* d = &lds[kt & 1][1][h][wave * 1024];
        gload_lds16(bP[h][0] + kt * 64, d);
        gload_lds16(bP[h][1] + kt * 64, d + 512);
    };

    // frag read offsets within a half (u16 units); row-swizzled chunks
    int offA[4][2], offB[2][2];
    #pragma unroll
    for (int m = 0; m < 4; ++m)
        #pragma unroll
        for (int ks = 0; ks < 2; ++ks)
            offA[m][ks] = (wm * 64 + m * 16 + r16) * 64 + (((ks * 4 + g16) ^ (r16 & 7)) * 8);
    #pragma unroll
    for (int n = 0; n < 2; ++n)
        #pragma unroll
        for (int ks = 0; ks < 2; ++ks)
            offB[n][ks] = (wn * 32 + n * 16 + r16) * 64 + (((ks * 4 + g16) ^ (r16 & 7)) * 8);

    f32x4 acc[8][4] = {};

    // prologue: all 4 halves of kt0 then kt1 (16 loads); retire kt0's 8.
    stA(0, 0); stB(0, 0); stB(0, 1); stA(0, 1);
    stA(1, 0); stB(1, 0); stB(1, 1); stA(1, 1);
    asm volatile("s_waitcnt vmcnt(8)" ::: "memory");
    __builtin_amdgcn_s_barrier();

    for (int kt = 0; kt < NT; ++kt) {
        const int buf = kt & 1;
        const u16* A0 = &lds[buf][0][0][0];
        const u16* A1 = &lds[buf][0][1][0];
        const u16* B0 = &lds[buf][1][0][0];
        const u16* B1 = &lds[buf][1][1][0];
        const bool pf = (kt + 2 < NT);
        bf16x8 af[4][2], b0[2][2], b1[2][2];

        // ---- q0: read A0 + B0; mfma m0-3 x n0-1 ----
        #pragma unroll
        for (int m = 0; m < 4; ++m) {
            af[m][0] = ldf(A0 + offA[m][0]);
            af[m][1] = ldf(A0 + offA[m][1]);
        }
        #pragma unroll
        for (int n = 0; n < 2; ++n) {
            b0[n][0] = ldf(B0 + offB[n][0]);
            b0[n][1] = ldf(B0 + offB[n][1]);
        }
        __builtin_amdgcn_s_setprio(1);
        #pragma unroll
        for (int m = 0; m < 4; ++m)
            #pragma unroll
            for (int n = 0; n < 2; ++n) {
                acc[m][n] = mfma16(af[m][0], b0[n][0], acc[m][n]);
                acc[m][n] = mfma16(af[m][1], b0[n][1], acc[m][n]);
            }
        __builtin_amdgcn_s_setprio(0);
        __builtin_amdgcn_s_barrier();

        // ---- q1: read B1; stage A0,B0(kt+2); mfma m0-3 x n2-3 ----
        #pragma unroll
        for (int n = 0; n < 2; ++n) {
            b1[n][0] = ldf(B1 + offB[n][0]);
            b1[n][1] = ldf(B1 + offB[n][1]);
        }
        if (pf) { stA(kt + 2, 0); stB(kt + 2, 0); }
        __builtin_amdgcn_s_setprio(1);
        #pragma unroll
        for (int m = 0; m < 4; ++m)
            #pragma unroll
            for (int n = 0; n < 2; ++n) {
                acc[m][n + 2] = mfma16(af[m][0], b1[n][0], acc[m][n + 2]);
                acc[m][n + 2] = mfma16(af[m][1], b1[n][1], acc[m][n + 2]);
            }
        __builtin_amdgcn_s_setprio(0);
        __builtin_amdgcn_s_barrier();

        // ---- q2: read A1; stage B1(kt+2); mfma m4-7 x n0-1 ----
        #pragma unroll
        for (int m = 0; m < 4; ++m) {
            af[m][0] = ldf(A1 + offA[m][0]);
            af[m][1] = ldf(A1 + offA[m][1]);
        }
        if (pf) stB(kt + 2, 1);
        __builtin_amdgcn_s_setprio(1);
        #pragma unroll
        for (int m = 0; m < 4; ++m)
            #pragma unroll
            for (int n = 0; n < 2; ++n) {
                acc[m + 4][n] = mfma16(af[m][0], b0[n][0], acc[m + 4][n]);
                acc[m + 4][n] = mfma16(af[m][1], b0[n][1], acc[m + 4][n]);
            }
        __builtin_amdgcn_s_setprio(0);
        __builtin_amdgcn_s_barrier();

        // ---- q3: stage A1(kt+2); mfma m4-7 x n2-3; counted vmcnt ----
        if (pf) stA(kt + 2, 1);
        __builtin_amdgcn_s_setprio(1);
        #pragma unroll
        for (int m = 0; m < 4; ++m)
            #pragma unroll
            for (int n = 0; n < 2; ++n) {
                acc[m + 4][n + 2] = mfma16(af[m][0], b1[n][0], acc[m + 4][n + 2]);
                acc[m + 4][n + 2] = mfma16(af[m][1], b1[n][1], acc[m + 4][n + 2]);
            }
        __builtin_amdgcn_s_setprio(0);
        if (pf)                   { asm volatile("s_waitcnt vmcnt(8)" ::: "memory"); }
        else if (kt + 1 < NT)     { asm volatile("s_waitcnt vmcnt(0)" ::: "memory"); }
        if (kt + 1 < NT) __builtin_amdgcn_s_barrier();
    }

    if constexpr (EPI == 1) {
        float* P = (float*)Cout + (size_t)blockIdx.z * planeEls;
        #pragma unroll
        for (int m = 0; m < 8; ++m) {
            #pragma unroll
            for (int n = 0; n < 4; ++n) {
                #pragma unroll
                for (int r = 0; r < 4; ++r) {
                    const int row = bm * 256 + wm * 128 + m * 16 + g16 * 4 + r;
                    const int col = bn * 256 + wn * 64 + n * 16 + r16;
                    P[(size_t)row * outLd + col] = acc[m][n][r];
                }
            }
        }
    } else {
        (void)planeEls;
        u16* O = (u16*)Cout;
        #pragma unroll
        for (int m = 0; m < 8; ++m) {
            #pragma unroll
            for (int n = 0; n < 2; ++n) {
                #pragma unroll
                for (int r = 0; r < 4; ++r) {
                    const int row = bm * 256 + wm * 128 + m * 16 + g16 * 4 + r;
                    const int col = (bn * 4 + wn) * 32 + n * 16 + r16;
                    const float vi = acc[m][n][r];
                    const float vg = acc[m][n + 2][r];
                    const float sl = vi / (1.0f + __expf(-vi));
                    O[(size_t)row * outLd + col] = f2bf(sl * vg);
                }
            }
        }
    }
}

// ---------- split-K reduce: out = resid + p0+p1+p2+p3 ----------
__global__ __launch_bounds__(256) void addreduce4_k(const float* __restrict__ resid,
                                                    const float* __restrict__ p,
                                                    float* __restrict__ out,
                                                    int n4, int planeEls) {
    for (int i = blockIdx.x * 256 + threadIdx.x; i < n4; i += gridDim.x * 256) {
        F4 a = *(const F4*)(resid + (size_t)i * 4);
        F4 b = *(const F4*)(p + (size_t)i * 4);
        F4 c = *(const F4*)(p + (size_t)planeEls + (size_t)i * 4);
        F4 d = *(const F4*)(p + (size_t)2 * planeEls + (size_t)i * 4);
        F4 e = *(const F4*)(p + (size_t)3 * planeEls + (size_t)i * 4);
        F4 o;
        #pragma unroll
        for (int j = 0; j < 4; ++j) o.v[j] = a.v[j] + b.v[j] + c.v[j] + d.v[j] + e.v[j];
        *(F4*)(out + (size_t)i * 4) = o;
    }
}

// ---------- flash attention v3 (causal), transpose-world + LDS-staged K/V ----------
__global__ __launch_bounds__(256) void attn_fwd_k(const u16* __restrict__ qk,
                                                  const u16* __restrict__ vt,
                                                  u16* __restrict__ Ob) {
    __shared__ u16 Klds[2][64 * 64];
    __shared__ u16 Vlds[2][64 * 64];

    const int tid  = threadIdx.x;
    const int wave = tid >> 6, lane = tid & 63;
    const int r16  = lane & 15, g16 = lane >> 4;

    const int blk = blockIdx.x;
    const int xcd = blk & 7;
    const int pc  = blk >> 3;
    const int hh  = pc >> 5;
    const int qb  = (31 - (pc & 31) + 8 * hh) & 31;
    const int bh  = xcd * 4 + hh;
    const int h   = bh & 15, b = bh >> 4;

    const int q0w = qb * 64 + wave * 16;
    const size_t seqb = (size_t)b * 2048;

    const u16* qp = qk + (seqb + q0w + r16) * 2048 + h * 64 + g16 * 8;
    const bf16x8 qf0 = *(const bf16x8*)qp;
    const bf16x8 qf1 = *(const bf16x8*)(qp + 32);

    const u16* kbase = qk + seqb * 2048 + 1024 + (size_t)h * 64;
    const u16* vbase = vt + (size_t)(h * 64) * 4096 + seqb;

    const int srow  = tid >> 3;                           // 0..31
    const int scol8 = ((tid & 7) ^ (srow & 7)) * 8;
    const u16* ksrc = kbase + (size_t)srow * 2048 + scol8;
    const u16* vsrc = vbase + (size_t)srow * 4096 + scol8;

    auto stage = [&](int bufi, int kv0) {
        const u16* kp = ksrc + (size_t)kv0 * 2048;
        const u16* vp = vsrc + kv0;
        u16* kd = &Klds[bufi][wave * 512];
        u16* vd = &Vlds[bufi][wave * 512];
        gload_lds16(kp, kd);
        gload_lds16(kp + (size_t)32 * 2048, kd + 2048);
        gload_lds16(vp, vd);
        gload_lds16(vp + (size_t)32 * 4096, vd + 2048);
    };

    f32x4 o[4] = {};
    float mreg = -3.0e38f, lreg = 0.0f;
    constexpr float SC = 0.125f * 1.44269504088896341f;   // Dh^-0.5 * log2(e)

    const int nt = qb + 1;
    stage(0, 0);
    asm volatile("s_waitcnt vmcnt(0)" ::: "memory");
    __builtin_amdgcn_s_barrier();

    for (int it = 0; it < nt; ++it) {
        const int kv0 = it * 64;
        const int cur = it & 1;
        if (it + 1 < nt) stage(cur ^ 1, kv0 + 64);

        const u16* K = Klds[cur];
        const u16* V = Vlds[cur];

        f32x4 s[4];
        #pragma unroll
        for (int t = 0; t < 4; ++t) {
            const int row = 16 * t + r16;
            const int sw  = row & 7;
            const bf16x8 k0 = *(const bf16x8*)&K[row * 64 + ((g16 ^ sw) * 8)];
            const bf16x8 k1 = *(const bf16x8*)&K[row * 64 + (((g16 + 4) ^ sw) * 8)];
            f32x4 acc = {0.f, 0.f, 0.f, 0.f};
            acc = mfma16(k0, qf0, acc);
            acc = mfma16(k1, qf1, acc);
            s[t] = acc;
        }

        float a[16];
        #pragma unroll
        for (int t = 0; t < 4; ++t)
            #pragma unroll
            for (int r = 0; r < 4; ++r) a[4 * t + r] = s[t][r] * SC;

        if (kv0 + 63 > q0w) {
            const int qg = q0w + r16;
            #pragma unroll
            for (int t = 0; t < 4; ++t)
                #pragma unroll
                for (int r = 0; r < 4; ++r)
                    if (kv0 + 16 * t + 4 * g16 + r > qg) a[4 * t + r] = -1.0e30f;
        }

        float mx = a[0];
        #pragma unroll
        for (int j = 1; j < 16; ++j) mx = fmaxf(mx, a[j]);
        mx = fmaxf(mx, __shfl_xor(mx, 16));
        mx = fmaxf(mx, __shfl_xor(mx, 32));
        const float mn = fmaxf(mreg, mx);
        const float al = exp2f(mreg - mn);
        float p[16], rs = 0.0f;
        #pragma unroll
        for (int j = 0; j < 16; ++j) { p[j] = exp2f(a[j] - mn); rs += p[j]; }
        rs += __shfl_xor(rs, 16);
        rs += __shfl_xor(rs, 32);
        lreg = lreg * al + rs;
        mreg = mn;

        bf16x8 pf0, pf1;
        #pragma unroll
        for (int j = 0; j < 8; ++j) { pf0[j] = (__bf16)p[j]; pf1[j] = (__bf16)p[8 + j]; }

        #pragma unroll
        for (int t = 0; t < 4; ++t) {
            const int row  = 16 * t + r16;
            const int sw   = row & 7;
            const int base = row * 64 + (g16 & 1) * 4;
            const int c0   = g16 >> 1;
            U4 a0 = *(const U4*)&V[base + (((c0 + 0) ^ sw) * 8)];
            U4 a1 = *(const U4*)&V[base + (((c0 + 2) ^ sw) * 8)];
            U4 b0 = *(const U4*)&V[base + (((c0 + 4) ^ sw) * 8)];
            U4 b1 = *(const U4*)&V[base + (((c0 + 6) ^ sw) * 8)];
            #pragma unroll
            for (int r = 0; r < 4; ++r) o[t][r] *= al;
            bf16x8 v0, v1;
            #pragma unroll
            for (int j = 0; j < 4; ++j) {
                v0[j]     = ((const __bf16*)&a0)[j];
                v0[4 + j] = ((const __bf16*)&a1)[j];
                v1[j]     = ((const __bf16*)&b0)[j];
                v1[4 + j] = ((const __bf16*)&b1)[j];
            }
            o[t] = mfma16(v0, pf0, o[t]);
            o[t] = mfma16(v1, pf1, o[t]);
        }

        if (it + 1 < nt) {
            asm volatile("s_waitcnt vmcnt(0)" ::: "memory");
            __builtin_amdgcn_s_barrier();
        }
    }

    const float inv = 1.0f / lreg;
    u16* op = Ob + (seqb + q0w + r16) * 1024 + h * 64 + 4 * g16;
    #pragma unroll
    for (int t = 0; t < 4; ++t) {
        U4 st;
        #pragma unroll
        for (int r = 0; r < 4; ++r) st.v[r] = f2bf(o[t][r] * inv);
        *(U4*)(op + 16 * t) = st;
    }
}

// ---------- launch ----------
extern "C" void kernel_launch(void* const* d_in, const int* in_sizes, int n_in,
                              void* d_out, int out_size, void* d_ws, size_t ws_size,
                              hipStream_t stream) {
    (void)in_sizes; (void)n_in; (void)out_size; (void)ws_size;
    constexpr int C = 1024, FF = 4096, M = 2 * 2048;   // B*T = 4096
    constexpr size_t MB = 1024 * 1024;

    const float* x      = (const float*)d_in[0];
    const float* ln1_w  = (const float*)d_in[1];
    const float* ln1_b  = (const float*)d_in[2];
    const float* qkv_w  = (const float*)d_in[3];
    const float* atto_w = (const float*)d_in[4];
    const float* ln2_w  = (const float*)d_in[5];
    const float* ln2_b  = (const float*)d_in[6];
    const float* mlpi_w = (const float*)d_in[7];
    const float* mlpg_w = (const float*)d_in[8];
    const float* mlpo_w = (const float*)d_in[9];
    float* out = (float*)d_out;

    char* ws = (char*)d_ws;
    size_t off = 0;
    auto alloc = [&](size_t bytes) {
        char* p = ws + off;
        off += (bytes + 255) & ~(size_t)255;
        return p;
    };
    u16*   wq   = (u16*)  alloc((size_t)3 * C * C * 2);   // qkv_w bf16 (Q,K rows then V)
    u16*   wo   = (u16*)  alloc((size_t)C * C * 2);
    u16*   wig  = (u16*)  alloc((size_t)2 * FF * C * 2);  // interleaved wi/wg [8192][1024]
    u16*   wm   = (u16*)  alloc((size_t)C * FF * 2);
    float* x1   = (float*)alloc((size_t)M * C * 4);
    u16*   h2   = (u16*)  alloc((size_t)M * C * 2);
    u16*   ab   = (u16*)  alloc((size_t)M * FF * 2);
    // region R (64 MB): attn-phase buffers, later reused as split-K partials
    char*  R    = alloc(64 * MB);
    u16*   h1   = (u16*)R;                 //  8 MB
    u16*   qk_b = (u16*)(R + 8 * MB);      // 16 MB  [4096][2048] Q|K
    u16*   vt_b = (u16*)(R + 24 * MB);     //  8 MB  [1024][4096] V^T
    u16*   Ob   = (u16*)(R + 32 * MB);     //  8 MB
    float* pscr = (float*)R;               // 64 MB  (4 planes x 16 MB) — after attn

    // weight casts
    cast_bf16_k<<<(3 * C * C / 4) / 256, 256, 0, stream>>>(qkv_w, wq, 3 * C * C / 4);
    cast_bf16_k<<<(C * C / 4) / 256, 256, 0, stream>>>(atto_w, wo, C * C / 4);
    cast_bf16_k<<<(C * FF / 4) / 256, 256, 0, stream>>>(mlpo_w, wm, C * FF / 4);
    cast_wig_k<<<(2 * FF * C / 8) / 256, 256, 0, stream>>>(mlpi_w, mlpg_w, wig);

    // attention branch
    ln_fwd_k<<<M, 256, 0, stream>>>(x, ln1_w, ln1_b, h1);
    gemm_bt_k<0><<<dim3(2 * C / 128, M / 128), 256, 0, stream>>>(h1, wq, qk_b, nullptr, M, 2 * C, C);
    const u16* wv = wq + (size_t)2 * C * C;
    gemm_bt_k<0><<<dim3(M / 128, C / 128), 256, 0, stream>>>(wv, h1, vt_b, nullptr, C, M, C);
    attn_fwd_k<<<1024, 256, 0, stream>>>(qk_b, vt_b, Ob);
    gemm_bt_k<1><<<dim3(C / 128, M / 128), 256, 0, stream>>>(Ob, wo, x1, x, M, C, C);

    // MLP branch
    ln_fwd_k<<<M, 256, 0, stream>>>(x1, ln2_w, ln2_b, h2);
    // fused (in|gate) GEMM + SwiGLU: grid 32x16=512; XCD chunk 8bm x 8bn
    gemm256_k<2><<<dim3((2 * FF / 256) * (M / 256), 1, 1), 512, 0, stream>>>(
        h2, wig, ab, C, C, C, 2 * FF / 256, 8, FF, 0);
    // mlp_out: split-K=4 (grid 4x16 x4 = 256), f32 partials; XCD chunk 2bm x 4bn
    gemm256_k<1><<<dim3((C / 256) * (M / 256), 1, 4), 512, 0, stream>>>(
        ab, wm, pscr, FF, FF, FF / 4, C / 256, 4, C, M * C);
    addreduce4_k<<<2048, 256, 0, stream>>>(x1, pscr, out, M * C / 4, M * C);
}

// Round 8
// 293.914 us; speedup vs baseline: 2.2548x; 1.0119x over previous
//
#include <hip/hip_runtime.h>
#include <cstdint>

// ---------- types & helpers ----------
typedef unsigned short u16;
typedef __bf16 bf16x8 __attribute__((ext_vector_type(8)));
typedef float  f32x4  __attribute__((ext_vector_type(4)));

struct alignas(16) F4 { float v[4]; };
struct alignas(8)  U4 { u16 v[4]; };
struct alignas(16) U8 { u16 v[8]; };

__device__ __forceinline__ u16 f2bf(float f) {
    union { float f; unsigned int u; } x; x.f = f;
    unsigned int r = x.u + 0x7fffu + ((x.u >> 16) & 1u);   // RNE
    return (u16)(r >> 16);
}
__device__ __forceinline__ float bf2f(u16 u) {
    union { unsigned int u; float f; } x; x.u = ((unsigned int)u) << 16;
    return x.f;
}
__device__ __forceinline__ f32x4 mfma16(bf16x8 a, bf16x8 b, f32x4 c) {
    return __builtin_amdgcn_mfma_f32_16x16x32_bf16(a, b, c, 0, 0, 0);
}
__device__ __forceinline__ bf16x8 ldf(const u16* p) { return *(const bf16x8*)p; }
// async global->LDS, 16B per lane, dest = wave-uniform base + lane*16
__device__ __forceinline__ void gload_lds16(const void* g, void* l) {
    auto* gp = reinterpret_cast<const __attribute__((address_space(1))) unsigned int*>(
        reinterpret_cast<uintptr_t>(g));
    auto* lp = reinterpret_cast<__attribute__((address_space(3))) unsigned int*>(
        reinterpret_cast<uintptr_t>(l));
    __builtin_amdgcn_global_load_lds(gp, lp, 16, 0, 0);
}

// ---------- generic f32 -> bf16 cast (vector) ----------
__global__ __launch_bounds__(256) void cast_bf16_k(const float* __restrict__ in,
                                                   u16* __restrict__ out, int n4) {
    int i = blockIdx.x * 256 + threadIdx.x;
    if (i >= n4) return;
    F4 v = *(const F4*)(in + (size_t)i * 4);
    U4 o;
    #pragma unroll
    for (int j = 0; j < 4; ++j) o.v[j] = f2bf(v.v[j]);
    *(U4*)(out + (size_t)i * 4) = o;
}

// ---------- build interleaved wig: per 64-row group: 32 in rows then 32 gate rows ----------
__global__ __launch_bounds__(256) void cast_wig_k(const float* __restrict__ wi,
                                                  const float* __restrict__ wg,
                                                  u16* __restrict__ wig) {
    int i = blockIdx.x * 256 + threadIdx.x;          // over 8192 rows * 128 groups-of-8
    const int w  = i >> 7;
    const int c8 = (i & 127) * 8;
    const int f  = ((w >> 6) << 5) | (w & 31);
    const float* src = ((w & 32) ? wg : wi) + (size_t)f * 1024 + c8;
    F4 a = *(const F4*)src;
    F4 b = *(const F4*)(src + 4);
    U8 o;
    #pragma unroll
    for (int j = 0; j < 4; ++j) { o.v[j] = f2bf(a.v[j]); o.v[4 + j] = f2bf(b.v[j]); }
    *(U8*)(wig + (size_t)w * 1024 + c8) = o;
}

// ---------- LayerNorm (C=1024), f32 in -> bf16 out ----------
__global__ __launch_bounds__(256) void ln_fwd_k(const float* __restrict__ x,
                                                const float* __restrict__ w,
                                                const float* __restrict__ b,
                                                u16* __restrict__ h) {
    const int row = blockIdx.x, tid = threadIdx.x;
    const float* xr = x + (size_t)row * 1024;
    F4 v = *(const F4*)(xr + tid * 4);
    float s  = v.v[0] + v.v[1] + v.v[2] + v.v[3];
    float ss = v.v[0]*v.v[0] + v.v[1]*v.v[1] + v.v[2]*v.v[2] + v.v[3]*v.v[3];
    #pragma unroll
    for (int o = 32; o > 0; o >>= 1) { s += __shfl_down(s, o); ss += __shfl_down(ss, o); }
    __shared__ float red[8];
    const int wave = tid >> 6, lane = tid & 63;
    if (lane == 0) { red[wave] = s; red[4 + wave] = ss; }
    __syncthreads();
    s  = red[0] + red[1] + red[2] + red[3];
    ss = red[4] + red[5] + red[6] + red[7];
    const float mu   = s * (1.0f / 1024.0f);
    const float var  = ss * (1.0f / 1024.0f) - mu * mu;
    const float rstd = rsqrtf(var + 1e-5f);
    U4 o;
    #pragma unroll
    for (int j = 0; j < 4; ++j)
        o.v[j] = f2bf((v.v[j] - mu) * rstd * w[tid * 4 + j] + b[tid * 4 + j]);
    *(U4*)(h + (size_t)row * 1024 + tid * 4) = o;
}

// ---------- 128x128 GEMM (m97 structure), kept for qk / vt / attn_out ----------
template <int MODE>
__global__ __launch_bounds__(256) void gemm_bt_k(const u16* __restrict__ A,
                                                 const u16* __restrict__ Bm,
                                                 void* __restrict__ Cout,
                                                 const float* __restrict__ resid,
                                                 int M, int N, int K) {
    __shared__ u16 Alds[128 * 32];
    __shared__ u16 Blds[128 * 32];
    const int tid  = threadIdx.x;
    const int lane = tid & 63, wave = tid >> 6;
    const int wr = wave >> 1, wc = wave & 1;
    const int r16 = lane & 15, g16 = lane >> 4;
    const int bn = blockIdx.x, bm = blockIdx.y;

    const int srow = lane >> 2;
    const int scol = (lane & 3) * 8;

    f32x4 acc[4][4] = {};

    for (int k0 = 0; k0 < K; k0 += 32) {
        #pragma unroll
        for (int c = 0; c < 2; ++c) {
            const int ch = wave * 2 + c;
            const u16* ga = A  + ((size_t)bm * 128 + ch * 16 + srow) * K + k0 + scol;
            gload_lds16(ga, &Alds[ch * 512]);
            const u16* gb = Bm + ((size_t)bn * 128 + ch * 16 + srow) * K + k0 + scol;
            gload_lds16(gb, &Blds[ch * 512]);
        }
        __syncthreads();
        bf16x8 af[4], bfr[4];
        #pragma unroll
        for (int m = 0; m < 4; ++m)
            af[m] = *(const bf16x8*)&Alds[(wr * 64 + m * 16 + r16) * 32 + g16 * 8];
        #pragma unroll
        for (int n = 0; n < 4; ++n)
            bfr[n] = *(const bf16x8*)&Blds[(wc * 64 + n * 16 + r16) * 32 + g16 * 8];
        #pragma unroll
        for (int m = 0; m < 4; ++m)
            #pragma unroll
            for (int n = 0; n < 4; ++n)
                acc[m][n] = mfma16(af[m], bfr[n], acc[m][n]);
        __syncthreads();
    }

    #pragma unroll
    for (int m = 0; m < 4; ++m) {
        #pragma unroll
        for (int n = 0; n < 4; ++n) {
            #pragma unroll
            for (int r = 0; r < 4; ++r) {
                const int row = bm * 128 + wr * 64 + m * 16 + g16 * 4 + r;
                const int col = bn * 128 + wc * 64 + n * 16 + r16;
                const float v = acc[m][n][r];
                if (MODE == 0) {
                    ((u16*)Cout)[(size_t)row * N + col] = f2bf(v);
                } else {
                    ((float*)Cout)[(size_t)row * N + col] =
                        resid[(size_t)row * N + col] + v;
                }
            }
        }
    }
}

// ---------- 256x256 pipelined GEMM v3 (frag-prefetch one phase ahead) ----------
// C = A[M,K]*B[N,K]^T. 512 thr = 8 waves (2M x 4N); wave tile 128x64; BK=64.
// LDS: 2 dbuf x {A,B} x {half0,half1} x 16KB = 128 KiB.
// All 24 fragment reads for kt are issued around kt-1's q3 (af0,b0 after the
// visibility vmcnt+barrier; b1,af1 after q3's MFMAs) so every MFMA cluster
// consumes registers loaded >=1 phase ago -> LDS pipe overlaps matrix pipe.
// Per kt: q0 {MFMA af0xb0} B0 | q1 {stage A0,B0(kt+2); MFMA af0xb1} B1 |
//         q2 {stage B1(kt+2); MFMA af1xb0} B2 |
//         q3 {stage A1(kt+2); vmcnt(8); B3; rd af0',b0'; MFMA af1xb1; rd b1',af1'}
// WAR: each slot staged exactly one barrier after the MFMA phase that consumed
// its reads. Visibility: vmcnt(8) at q3 retires kt+1's 8 half-tile loads.
// 2D XCD chunking. EPI 1: f32 partials (plane z). EPI 2: fused SwiGLU bf16.
template <int EPI>
__global__ __launch_bounds__(512, 2)
void gemm256_k(const u16* __restrict__ A, const u16* __restrict__ Bm,
               void* __restrict__ Cout, int lda, int ldb, int kLen,
               int nx, int bnCh, int outLd, int planeEls) {
    __shared__ u16 lds[2][2][2][128 * 64];

    const int tid  = threadIdx.x;
    const int wave = tid >> 6, lane = tid & 63;
    const int wm = wave >> 2, wn = wave & 3;
    const int r16 = lane & 15, g16 = lane >> 4;

    // 2D XCD chunking (gridDim.x % 8 == 0; nx % bnCh == 0; cpx % bnCh == 0)
    const int cpx = gridDim.x >> 3;
    const int xcd = blockIdx.x & 7, loc = blockIdx.x >> 3;
    const int mCh = cpx / bnCh;
    const int cpr = nx / bnCh;
    const int bm = (xcd / cpr) * mCh + loc / bnCh;
    const int bn = (xcd % cpr) * bnCh + loc % bnCh;
    const int kBeg = blockIdx.z * kLen;
    const int NT = kLen >> 6;

    // staging: uniform base + 32-bit lane offsets (saddr-friendly)
    const int csw = ((lane & 7) ^ (lane >> 3)) * 8;
    const u16* aU = A  + (size_t)(bm * 256) * lda + kBeg;
    const u16* bU = Bm + (size_t)(bn * 256) * ldb + kBeg;
    int aOff[2][2], bOff[2][2];
    #pragma unroll
    for (int h = 0; h < 2; ++h) {
        #pragma unroll
        for (int i = 0; i < 2; ++i) {
            const int wr = wave * 16 + (lane >> 3) + i * 8;
            const int ar = (wr >> 6) * 128 + h * 64 + (wr & 63);
            const int br = (wr >> 5) * 64 + h * 32 + (wr & 31);
            aOff[h][i] = ar * lda + csw;
            bOff[h][i] = br * ldb + csw;
        }
    }

    auto stA = [&](int kt, int h) {
        u16* d = &lds[kt & 1][0][h][wave * 1024];
        gload_lds16(aU + aOff[h][0] + kt * 64, d);
        gload_lds16(aU + aOff[h][1] + kt * 64, d + 512);
    };
    auto stB = [&](int kt, int h) {
        u16* d = &lds[kt & 1][1][h][wave * 1024];
        gload_lds16(bU + bOff[h][0] + kt * 64, d);
        gload_lds16(bU + bOff[h][1] + kt * 64, d + 512);
    };

    // frag read offsets within a half (u16 units); row-swizzled chunks
    int offA[4][2], offB[2][2];
    #pragma unroll
    for (int m = 0; m < 4; ++m)
        #pragma unroll
        for (int ks = 0; ks < 2; ++ks)
            offA[m][ks] = (wm * 64 + m * 16 + r16) * 64 + (((ks * 4 + g16) ^ (r16 & 7)) * 8);
    #pragma unroll
    for (int n = 0; n < 2; ++n)
        #pragma unroll
        for (int ks = 0; ks < 2; ++ks)
            offB[n][ks] = (wn * 32 + n * 16 + r16) * 64 + (((ks * 4 + g16) ^ (r16 & 7)) * 8);

    f32x4 acc[8][4] = {};
    bf16x8 af0[4][2], af1[4][2], b0v[2][2], b1v[2][2];

    auto rdAF0 = [&](int buf) {
        const u16* P = &lds[buf][0][0][0];
        #pragma unroll
        for (int m = 0; m < 4; ++m) {
            af0[m][0] = ldf(P + offA[m][0]);
            af0[m][1] = ldf(P + offA[m][1]);
        }
    };
    auto rdAF1 = [&](int buf) {
        const u16* P = &lds[buf][0][1][0];
        #pragma unroll
        for (int m = 0; m < 4; ++m) {
            af1[m][0] = ldf(P + offA[m][0]);
            af1[m][1] = ldf(P + offA[m][1]);
        }
    };
    auto rdB0 = [&](int buf) {
        const u16* P = &lds[buf][1][0][0];
        #pragma unroll
        for (int n = 0; n < 2; ++n) {
            b0v[n][0] = ldf(P + offB[n][0]);
            b0v[n][1] = ldf(P + offB[n][1]);
        }
    };
    auto rdB1 = [&](int buf) {
        const u16* P = &lds[buf][1][1][0];
        #pragma unroll
        for (int n = 0; n < 2; ++n) {
            b1v[n][0] = ldf(P + offB[n][0]);
            b1v[n][1] = ldf(P + offB[n][1]);
        }
    };

    // prologue: stage kt0 + kt1 (16 loads); retire kt0 (vmcnt 8); read kt0 frags.
    stA(0, 0); stB(0, 0); stB(0, 1); stA(0, 1);
    stA(1, 0); stB(1, 0); stB(1, 1); stA(1, 1);
    asm volatile("s_waitcnt vmcnt(8)" ::: "memory");
    __builtin_amdgcn_s_barrier();
    rdAF0(0); rdB0(0); rdB1(0); rdAF1(0);

    for (int kt = 0; kt < NT; ++kt) {
        const bool pf = (kt + 2 < NT);
        const int nb = (kt + 1) & 1;

        // ---- q0: MFMA af0 x b0 -> acc[0-3][0-1] ----
        __builtin_amdgcn_s_setprio(1);
        #pragma unroll
        for (int m = 0; m < 4; ++m)
            #pragma unroll
            for (int n = 0; n < 2; ++n) {
                acc[m][n] = mfma16(af0[m][0], b0v[n][0], acc[m][n]);
                acc[m][n] = mfma16(af0[m][1], b0v[n][1], acc[m][n]);
            }
        __builtin_amdgcn_s_setprio(0);
        __builtin_amdgcn_s_barrier();

        // ---- q1: stage A0,B0(kt+2); MFMA af0 x b1 -> acc[0-3][2-3] ----
        if (pf) { stA(kt + 2, 0); stB(kt + 2, 0); }
        __builtin_amdgcn_s_setprio(1);
        #pragma unroll
        for (int m = 0; m < 4; ++m)
            #pragma unroll
            for (int n = 0; n < 2; ++n) {
                acc[m][n + 2] = mfma16(af0[m][0], b1v[n][0], acc[m][n + 2]);
                acc[m][n + 2] = mfma16(af0[m][1], b1v[n][1], acc[m][n + 2]);
            }
        __builtin_amdgcn_s_setprio(0);
        __builtin_amdgcn_s_barrier();

        // ---- q2: stage B1(kt+2); MFMA af1 x b0 -> acc[4-7][0-1] ----
        if (pf) stB(kt + 2, 1);
        __builtin_amdgcn_s_setprio(1);
        #pragma unroll
        for (int m = 0; m < 4; ++m)
            #pragma unroll
            for (int n = 0; n < 2; ++n) {
                acc[m + 4][n] = mfma16(af1[m][0], b0v[n][0], acc[m + 4][n]);
                acc[m + 4][n] = mfma16(af1[m][1], b0v[n][1], acc[m + 4][n]);
            }
        __builtin_amdgcn_s_setprio(0);
        __builtin_amdgcn_s_barrier();

        // ---- q3: stage A1(kt+2); vmcnt; bar; prefetch next af0,b0;
        //          MFMA af1 x b1; prefetch next b1,af1 ----
        if (pf) stA(kt + 2, 1);
        if (pf)               { asm volatile("s_waitcnt vmcnt(8)" ::: "memory"); }
        else if (kt + 1 < NT) { asm volatile("s_waitcnt vmcnt(0)" ::: "memory"); }
        if (kt + 1 < NT) {
            __builtin_amdgcn_s_barrier();
            rdAF0(nb); rdB0(nb);
        }
        __builtin_amdgcn_s_setprio(1);
        #pragma unroll
        for (int m = 0; m < 4; ++m)
            #pragma unroll
            for (int n = 0; n < 2; ++n) {
                acc[m + 4][n + 2] = mfma16(af1[m][0], b1v[n][0], acc[m + 4][n + 2]);
                acc[m + 4][n + 2] = mfma16(af1[m][1], b1v[n][1], acc[m + 4][n + 2]);
            }
        __builtin_amdgcn_s_setprio(0);
        if (kt + 1 < NT) { rdB1(nb); rdAF1(nb); }
    }

    if constexpr (EPI == 1) {
        float* P = (float*)Cout + (size_t)blockIdx.z * planeEls;
        #pragma unroll
        for (int m = 0; m < 8; ++m) {
            #pragma unroll
            for (int n = 0; n < 4; ++n) {
                #pragma unroll
                for (int r = 0; r < 4; ++r) {
                    const int row = bm * 256 + wm * 128 + m * 16 + g16 * 4 + r;
                    const int col = bn * 256 + wn * 64 + n * 16 + r16;
                    P[(size_t)row * outLd + col] = acc[m][n][r];
                }
            }
        }
    } else {
        (void)planeEls;
        u16* O = (u16*)Cout;
        #pragma unroll
        for (int m = 0; m < 8; ++m) {
            #pragma unroll
            for (int n = 0; n < 2; ++n) {
                #pragma unroll
                for (int r = 0; r < 4; ++r) {
                    const int row = bm * 256 + wm * 128 + m * 16 + g16 * 4 + r;
                    const int col = (bn * 4 + wn) * 32 + n * 16 + r16;
                    const float vi = acc[m][n][r];
                    const float vg = acc[m][n + 2][r];
                    const float sl = vi / (1.0f + __expf(-vi));
                    O[(size_t)row * outLd + col] = f2bf(sl * vg);
                }
            }
        }
    }
}

// ---------- split-K reduce: out = resid + p0+p1+p2+p3 ----------
__global__ __launch_bounds__(256) void addreduce4_k(const float* __restrict__ resid,
                                                    const float* __restrict__ p,
                                                    float* __restrict__ out,
                                                    int n4, int planeEls) {
    for (int i = blockIdx.x * 256 + threadIdx.x; i < n4; i += gridDim.x * 256) {
        F4 a = *(const F4*)(resid + (size_t)i * 4);
        F4 b = *(const F4*)(p + (size_t)i * 4);
        F4 c = *(const F4*)(p + (size_t)planeEls + (size_t)i * 4);
        F4 d = *(const F4*)(p + (size_t)2 * planeEls + (size_t)i * 4);
        F4 e = *(const F4*)(p + (size_t)3 * planeEls + (size_t)i * 4);
        F4 o;
        #pragma unroll
        for (int j = 0; j < 4; ++j) o.v[j] = a.v[j] + b.v[j] + c.v[j] + d.v[j] + e.v[j];
        *(F4*)(out + (size_t)i * 4) = o;
    }
}

// ---------- flash attention v3 (causal), transpose-world + LDS-staged K/V ----------
__global__ __launch_bounds__(256) void attn_fwd_k(const u16* __restrict__ qk,
                                                  const u16* __restrict__ vt,
                                                  u16* __restrict__ Ob) {
    __shared__ u16 Klds[2][64 * 64];
    __shared__ u16 Vlds[2][64 * 64];

    const int tid  = threadIdx.x;
    const int wave = tid >> 6, lane = tid & 63;
    const int r16  = lane & 15, g16 = lane >> 4;

    const int blk = blockIdx.x;
    const int xcd = blk & 7;
    const int pc  = blk >> 3;
    const int hh  = pc >> 5;
    const int qb  = (31 - (pc & 31) + 8 * hh) & 31;
    const int bh  = xcd * 4 + hh;
    const int h   = bh & 15, b = bh >> 4;

    const int q0w = qb * 64 + wave * 16;
    const size_t seqb = (size_t)b * 2048;

    const u16* qp = qk + (seqb + q0w + r16) * 2048 + h * 64 + g16 * 8;
    const bf16x8 qf0 = *(const bf16x8*)qp;
    const bf16x8 qf1 = *(const bf16x8*)(qp + 32);

    const u16* kbase = qk + seqb * 2048 + 1024 + (size_t)h * 64;
    const u16* vbase = vt + (size_t)(h * 64) * 4096 + seqb;

    const int srow  = tid >> 3;                           // 0..31
    const int scol8 = ((tid & 7) ^ (srow & 7)) * 8;
    const u16* ksrc = kbase + (size_t)srow * 2048 + scol8;
    const u16* vsrc = vbase + (size_t)srow * 4096 + scol8;

    auto stage = [&](int bufi, int kv0) {
        const u16* kp = ksrc + (size_t)kv0 * 2048;
        const u16* vp = vsrc + kv0;
        u16* kd = &Klds[bufi][wave * 512];
        u16* vd = &Vlds[bufi][wave * 512];
        gload_lds16(kp, kd);
        gload_lds16(kp + (size_t)32 * 2048, kd + 2048);
        gload_lds16(vp, vd);
        gload_lds16(vp + (size_t)32 * 4096, vd + 2048);
    };

    f32x4 o[4] = {};
    float mreg = -3.0e38f, lreg = 0.0f;
    constexpr float SC = 0.125f * 1.44269504088896341f;   // Dh^-0.5 * log2(e)

    const int nt = qb + 1;
    stage(0, 0);
    asm volatile("s_waitcnt vmcnt(0)" ::: "memory");
    __builtin_amdgcn_s_barrier();

    for (int it = 0; it < nt; ++it) {
        const int kv0 = it * 64;
        const int cur = it & 1;
        if (it + 1 < nt) stage(cur ^ 1, kv0 + 64);

        const u16* K = Klds[cur];
        const u16* V = Vlds[cur];

        f32x4 s[4];
        #pragma unroll
        for (int t = 0; t < 4; ++t) {
            const int row = 16 * t + r16;
            const int sw  = row & 7;
            const bf16x8 k0 = *(const bf16x8*)&K[row * 64 + ((g16 ^ sw) * 8)];
            const bf16x8 k1 = *(const bf16x8*)&K[row * 64 + (((g16 + 4) ^ sw) * 8)];
            f32x4 acc = {0.f, 0.f, 0.f, 0.f};
            acc = mfma16(k0, qf0, acc);
            acc = mfma16(k1, qf1, acc);
            s[t] = acc;
        }

        float a[16];
        #pragma unroll
        for (int t = 0; t < 4; ++t)
            #pragma unroll
            for (int r = 0; r < 4; ++r) a[4 * t + r] = s[t][r] * SC;

        if (kv0 + 63 > q0w) {
            const int qg = q0w + r16;
            #pragma unroll
            for (int t = 0; t < 4; ++t)
                #pragma unroll
                for (int r = 0; r < 4; ++r)
                    if (kv0 + 16 * t + 4 * g16 + r > qg) a[4 * t + r] = -1.0e30f;
        }

        float mx = a[0];
        #pragma unroll
        for (int j = 1; j < 16; ++j) mx = fmaxf(mx, a[j]);
        mx = fmaxf(mx, __shfl_xor(mx, 16));
        mx = fmaxf(mx, __shfl_xor(mx, 32));
        const float mn = fmaxf(mreg, mx);
        const float al = exp2f(mreg - mn);
        float p[16], rs = 0.0f;
        #pragma unroll
        for (int j = 0; j < 16; ++j) { p[j] = exp2f(a[j] - mn); rs += p[j]; }
        rs += __shfl_xor(rs, 16);
        rs += __shfl_xor(rs, 32);
        lreg = lreg * al + rs;
        mreg = mn;

        bf16x8 pf0, pf1;
        #pragma unroll
        for (int j = 0; j < 8; ++j) { pf0[j] = (__bf16)p[j]; pf1[j] = (__bf16)p[8 + j]; }

        #pragma unroll
        for (int t = 0; t < 4; ++t) {
            const int row  = 16 * t + r16;
            const int sw   = row & 7;
            const int base = row * 64 + (g16 & 1) * 4;
            const int c0   = g16 >> 1;
            U4 a0 = *(const U4*)&V[base + (((c0 + 0) ^ sw) * 8)];
            U4 a1 = *(const U4*)&V[base + (((c0 + 2) ^ sw) * 8)];
            U4 b0 = *(const U4*)&V[base + (((c0 + 4) ^ sw) * 8)];
            U4 b1 = *(const U4*)&V[base + (((c0 + 6) ^ sw) * 8)];
            #pragma unroll
            for (int r = 0; r < 4; ++r) o[t][r] *= al;
            bf16x8 v0, v1;
            #pragma unroll
            for (int j = 0; j < 4; ++j) {
                v0[j]     = ((const __bf16*)&a0)[j];
                v0[4 + j] = ((const __bf16*)&a1)[j];
                v1[j]     = ((const __bf16*)&b0)[j];
                v1[4 + j] = ((const __bf16*)&b1)[j];
            }
            o[t] = mfma16(v0, pf0, o[t]);
            o[t] = mfma16(v1, pf1, o[t]);
        }

        if (it + 1 < nt) {
            asm volatile("s_waitcnt vmcnt(0)" ::: "memory");
            __builtin_amdgcn_s_barrier();
        }
    }

    const float inv = 1.0f / lreg;
    u16* op = Ob + (seqb + q0w + r16) * 1024 + h * 64 + 4 * g16;
    #pragma unroll
    for (int t = 0; t < 4; ++t) {
        U4 st;
        #pragma unroll
        for (int r = 0; r < 4; ++r) st.v[r] = f2bf(o[t][r] * inv);
        *(U4*)(op + 16 * t) = st;
    }
}

// ---------- launch ----------
extern "C" void kernel_launch(void* const* d_in, const int* in_sizes, int n_in,
                              void* d_out, int out_size, void* d_ws, size_t ws_size,
                              hipStream_t stream) {
    (void)in_sizes; (void)n_in; (void)out_size; (void)ws_size;
    constexpr int C = 1024, FF = 4096, M = 2 * 2048;   // B*T = 4096
    constexpr size_t MB = 1024 * 1024;

    const float* x      = (const float*)d_in[0];
    const float* ln1_w  = (const float*)d_in[1];
    const float* ln1_b  = (const float*)d_in[2];
    const float* qkv_w  = (const float*)d_in[3];
    const float* atto_w = (const float*)d_in[4];
    const float* ln2_w  = (const float*)d_in[5];
    const float* ln2_b  = (const float*)d_in[6];
    const float* mlpi_w = (const float*)d_in[7];
    const float* mlpg_w = (const float*)d_in[8];
    const float* mlpo_w = (const float*)d_in[9];
    float* out = (float*)d_out;

    char* ws = (char*)d_ws;
    size_t off = 0;
    auto alloc = [&](size_t bytes) {
        char* p = ws + off;
        off += (bytes + 255) & ~(size_t)255;
        return p;
    };
    u16*   wq   = (u16*)  alloc((size_t)3 * C * C * 2);   // qkv_w bf16 (Q,K rows then V)
    u16*   wo   = (u16*)  alloc((size_t)C * C * 2);
    u16*   wig  = (u16*)  alloc((size_t)2 * FF * C * 2);  // interleaved wi/wg [8192][1024]
    u16*   wm   = (u16*)  alloc((size_t)C * FF * 2);
    float* x1   = (float*)alloc((size_t)M * C * 4);
    u16*   h2   = (u16*)  alloc((size_t)M * C * 2);
    u16*   ab   = (u16*)  alloc((size_t)M * FF * 2);
    // region R (64 MB): attn-phase buffers, later reused as split-K partials
    char*  R    = alloc(64 * MB);
    u16*   h1   = (u16*)R;                 //  8 MB
    u16*   qk_b = (u16*)(R + 8 * MB);      // 16 MB  [4096][2048] Q|K
    u16*   vt_b = (u16*)(R + 24 * MB);     //  8 MB  [1024][4096] V^T
    u16*   Ob   = (u16*)(R + 32 * MB);     //  8 MB
    float* pscr = (float*)R;               // 64 MB  (4 planes x 16 MB) — after attn

    // weight casts
    cast_bf16_k<<<(3 * C * C / 4) / 256, 256, 0, stream>>>(qkv_w, wq, 3 * C * C / 4);
    cast_bf16_k<<<(C * C / 4) / 256, 256, 0, stream>>>(atto_w, wo, C * C / 4);
    cast_bf16_k<<<(C * FF / 4) / 256, 256, 0, stream>>>(mlpo_w, wm, C * FF / 4);
    cast_wig_k<<<(2 * FF * C / 8) / 256, 256, 0, stream>>>(mlpi_w, mlpg_w, wig);

    // attention branch
    ln_fwd_k<<<M, 256, 0, stream>>>(x, ln1_w, ln1_b, h1);
    gemm_bt_k<0><<<dim3(2 * C / 128, M / 128), 256, 0, stream>>>(h1, wq, qk_b, nullptr, M, 2 * C, C);
    const u16* wv = wq + (size_t)2 * C * C;
    gemm_bt_k<0><<<dim3(M / 128, C / 128), 256, 0, stream>>>(wv, h1, vt_b, nullptr, C, M, C);
    attn_fwd_k<<<1024, 256, 0, stream>>>(qk_b, vt_b, Ob);
    gemm_bt_k<1><<<dim3(C / 128, M / 128), 256, 0, stream>>>(Ob, wo, x1, x, M, C, C);

    // MLP branch
    ln_fwd_k<<<M, 256, 0, stream>>>(x1, ln2_w, ln2_b, h2);
    // fused (in|gate) GEMM + SwiGLU: grid 32x16=512; XCD chunk 8bm x 8bn
    gemm256_k<2><<<dim3((2 * FF / 256) * (M / 256), 1, 1), 512, 0, stream>>>(
        h2, wig, ab, C, C, C, 2 * FF / 256, 8, FF, 0);
    // mlp_out: split-K=4 (grid 4x16 x4 = 256), f32 partials; XCD chunk 2bm x 4bn
    gemm256_k<1><<<dim3((C / 256) * (M / 256), 1, 4), 512, 0, stream>>>(
        ab, wm, pscr, FF, FF, FF / 4, C / 256, 4, C, M * C);
    addreduce4_k<<<2048, 256, 0, stream>>>(x1, pscr, out, M * C / 4, M * C);
}

// Round 9
// 292.018 us; speedup vs baseline: 2.2695x; 1.0065x over previous
//
#include <hip/hip_runtime.h>
#include <cstdint>

// ---------- types & helpers ----------
typedef unsigned short u16;
typedef __bf16 bf16x8 __attribute__((ext_vector_type(8)));
typedef float  f32x4  __attribute__((ext_vector_type(4)));

struct alignas(16) F4 { float v[4]; };
struct alignas(8)  U4 { u16 v[4]; };
struct alignas(16) U8 { u16 v[8]; };

__device__ __forceinline__ u16 f2bf(float f) {
    union { float f; unsigned int u; } x; x.f = f;
    unsigned int r = x.u + 0x7fffu + ((x.u >> 16) & 1u);   // RNE
    return (u16)(r >> 16);
}
__device__ __forceinline__ float bf2f(u16 u) {
    union { unsigned int u; float f; } x; x.u = ((unsigned int)u) << 16;
    return x.f;
}
__device__ __forceinline__ f32x4 mfma16(bf16x8 a, bf16x8 b, f32x4 c) {
    return __builtin_amdgcn_mfma_f32_16x16x32_bf16(a, b, c, 0, 0, 0);
}
__device__ __forceinline__ bf16x8 ldf(const u16* p) { return *(const bf16x8*)p; }
// async global->LDS, 16B per lane, dest = wave-uniform base + lane*16
__device__ __forceinline__ void gload_lds16(const void* g, void* l) {
    auto* gp = reinterpret_cast<const __attribute__((address_space(1))) unsigned int*>(
        reinterpret_cast<uintptr_t>(g));
    auto* lp = reinterpret_cast<__attribute__((address_space(3))) unsigned int*>(
        reinterpret_cast<uintptr_t>(l));
    __builtin_amdgcn_global_load_lds(gp, lp, 16, 0, 0);
}

// ---------- generic f32 -> bf16 cast (vector) ----------
__global__ __launch_bounds__(256) void cast_bf16_k(const float* __restrict__ in,
                                                   u16* __restrict__ out, int n4) {
    int i = blockIdx.x * 256 + threadIdx.x;
    if (i >= n4) return;
    F4 v = *(const F4*)(in + (size_t)i * 4);
    U4 o;
    #pragma unroll
    for (int j = 0; j < 4; ++j) o.v[j] = f2bf(v.v[j]);
    *(U4*)(out + (size_t)i * 4) = o;
}

// ---------- build interleaved wig: per 64-row group: 32 in rows then 32 gate rows ----------
__global__ __launch_bounds__(256) void cast_wig_k(const float* __restrict__ wi,
                                                  const float* __restrict__ wg,
                                                  u16* __restrict__ wig) {
    int i = blockIdx.x * 256 + threadIdx.x;          // over 8192 rows * 128 groups-of-8
    const int w  = i >> 7;
    const int c8 = (i & 127) * 8;
    const int f  = ((w >> 6) << 5) | (w & 31);
    const float* src = ((w & 32) ? wg : wi) + (size_t)f * 1024 + c8;
    F4 a = *(const F4*)src;
    F4 b = *(const F4*)(src + 4);
    U8 o;
    #pragma unroll
    for (int j = 0; j < 4; ++j) { o.v[j] = f2bf(a.v[j]); o.v[4 + j] = f2bf(b.v[j]); }
    *(U8*)(wig + (size_t)w * 1024 + c8) = o;
}

// ---------- LayerNorm (C=1024), f32 in -> bf16 out ----------
__global__ __launch_bounds__(256) void ln_fwd_k(const float* __restrict__ x,
                                                const float* __restrict__ w,
                                                const float* __restrict__ b,
                                                u16* __restrict__ h) {
    const int row = blockIdx.x, tid = threadIdx.x;
    const float* xr = x + (size_t)row * 1024;
    F4 v = *(const F4*)(xr + tid * 4);
    float s  = v.v[0] + v.v[1] + v.v[2] + v.v[3];
    float ss = v.v[0]*v.v[0] + v.v[1]*v.v[1] + v.v[2]*v.v[2] + v.v[3]*v.v[3];
    #pragma unroll
    for (int o = 32; o > 0; o >>= 1) { s += __shfl_down(s, o); ss += __shfl_down(ss, o); }
    __shared__ float red[8];
    const int wave = tid >> 6, lane = tid & 63;
    if (lane == 0) { red[wave] = s; red[4 + wave] = ss; }
    __syncthreads();
    s  = red[0] + red[1] + red[2] + red[3];
    ss = red[4] + red[5] + red[6] + red[7];
    const float mu   = s * (1.0f / 1024.0f);
    const float var  = ss * (1.0f / 1024.0f) - mu * mu;
    const float rstd = rsqrtf(var + 1e-5f);
    U4 o;
    #pragma unroll
    for (int j = 0; j < 4; ++j)
        o.v[j] = f2bf((v.v[j] - mu) * rstd * w[tid * 4 + j] + b[tid * 4 + j]);
    *(U4*)(h + (size_t)row * 1024 + tid * 4) = o;
}

// ---------- 128x128 GEMM (m97 structure), kept for qk / vt / attn_out ----------
template <int MODE>
__global__ __launch_bounds__(256) void gemm_bt_k(const u16* __restrict__ A,
                                                 const u16* __restrict__ Bm,
                                                 void* __restrict__ Cout,
                                                 const float* __restrict__ resid,
                                                 int M, int N, int K) {
    __shared__ u16 Alds[128 * 32];
    __shared__ u16 Blds[128 * 32];
    const int tid  = threadIdx.x;
    const int lane = tid & 63, wave = tid >> 6;
    const int wr = wave >> 1, wc = wave & 1;
    const int r16 = lane & 15, g16 = lane >> 4;
    const int bn = blockIdx.x, bm = blockIdx.y;

    const int srow = lane >> 2;
    const int scol = (lane & 3) * 8;

    f32x4 acc[4][4] = {};

    for (int k0 = 0; k0 < K; k0 += 32) {
        #pragma unroll
        for (int c = 0; c < 2; ++c) {
            const int ch = wave * 2 + c;
            const u16* ga = A  + ((size_t)bm * 128 + ch * 16 + srow) * K + k0 + scol;
            gload_lds16(ga, &Alds[ch * 512]);
            const u16* gb = Bm + ((size_t)bn * 128 + ch * 16 + srow) * K + k0 + scol;
            gload_lds16(gb, &Blds[ch * 512]);
        }
        __syncthreads();
        bf16x8 af[4], bfr[4];
        #pragma unroll
        for (int m = 0; m < 4; ++m)
            af[m] = *(const bf16x8*)&Alds[(wr * 64 + m * 16 + r16) * 32 + g16 * 8];
        #pragma unroll
        for (int n = 0; n < 4; ++n)
            bfr[n] = *(const bf16x8*)&Blds[(wc * 64 + n * 16 + r16) * 32 + g16 * 8];
        #pragma unroll
        for (int m = 0; m < 4; ++m)
            #pragma unroll
            for (int n = 0; n < 4; ++n)
                acc[m][n] = mfma16(af[m], bfr[n], acc[m][n]);
        __syncthreads();
    }

    #pragma unroll
    for (int m = 0; m < 4; ++m) {
        #pragma unroll
        for (int n = 0; n < 4; ++n) {
            #pragma unroll
            for (int r = 0; r < 4; ++r) {
                const int row = bm * 128 + wr * 64 + m * 16 + g16 * 4 + r;
                const int col = bn * 128 + wc * 64 + n * 16 + r16;
                const float v = acc[m][n][r];
                if (MODE == 0) {
                    ((u16*)Cout)[(size_t)row * N + col] = f2bf(v);
                } else {
                    ((float*)Cout)[(size_t)row * N + col] =
                        resid[(size_t)row * N + col] + v;
                }
            }
        }
    }
}

// ---------- 256x256 pipelined GEMM v4: 2 fat phases / K-tile, 4-slot pipeline ----------
// C = A[M,K]*B[N,K]^T. 512 thr = 8 waves (2M x 4N); wave tile 128x64.
// LDS: 4 physical slots x {A[256x32] + B[256x32]} = 128 KiB. Phase p (K-half):
//   stage slot p+3 (4 gloads) ; ds_read slot p+1's 12 frags (alt reg set) ;
//   32-MFMA cluster on set read last phase ; vmcnt(4) ; barrier.
// Slot s: staged @ s-3, retired by (s-2)-end vmcnt(4)+barrier (block-wide),
// read @ s-1, consumed @ s -> every hazard crosses a barrier.
// Swizzle: 16B chunk c of row r stored at c ^ ((r>>1)&3)  (2-way banks = free);
// staging uses inverse-swizzled global source.
// EPI 1: bf16 partials (plane blockIdx.z).  EPI 2: fused SwiGLU bf16.
template <int EPI>
__global__ __launch_bounds__(512, 2)
void gemm256_k(const u16* __restrict__ A, const u16* __restrict__ Bm,
               void* __restrict__ Cout, int lda, int ldb, int kLen,
               int nx, int bnCh, int outLd, int planeEls) {
    __shared__ u16 lds[4][2][8192];     // [slot][A/B][256*32]

    const int tid  = threadIdx.x;
    const int wave = tid >> 6, lane = tid & 63;
    const int wm = wave >> 2, wn = wave & 3;
    const int r16 = lane & 15, g16 = lane >> 4;

    // 2D XCD chunking (gridDim.x % 8 == 0; nx % bnCh == 0; cpx % bnCh == 0)
    const int cpx = gridDim.x >> 3;
    const int xcd = blockIdx.x & 7, loc = blockIdx.x >> 3;
    const int mCh = cpx / bnCh;
    const int cpr = nx / bnCh;
    const int bm = (xcd / cpr) * mCh + loc / bnCh;
    const int bn = (xcd % cpr) * bnCh + loc % bnCh;
    const int kBeg = blockIdx.z * kLen;
    const int NT = kLen >> 6;           // K-tiles (2 phases each)

    // staging: linear chunk q = wave*64+lane (+512); row=q>>2,
    // storedChunk=q&3, srcChunk=(q&3)^((q>>3)&3)
    const u16* aU = A  + (size_t)(bm * 256) * lda + kBeg;
    const u16* bU = Bm + (size_t)(bn * 256) * ldb + kBeg;
    int aOf[2], bOf[2];
    #pragma unroll
    for (int i = 0; i < 2; ++i) {
        const int q = wave * 64 + lane + i * 512;
        const int row = q >> 2;
        const int sc = (q & 3) ^ ((q >> 3) & 3);
        aOf[i] = row * lda + sc * 8;
        bOf[i] = row * ldb + sc * 8;
    }

    // stage slot s (phase index): K offset = (s>>1)*64 + (s&1)*32
    auto stage = [&](int s) {
        const int ko = (s >> 1) * 64 + (s & 1) * 32;
        u16* dA = &lds[s & 3][0][wave * 512];
        u16* dB = &lds[s & 3][1][wave * 512];
        gload_lds16(aU + aOf[0] + ko, dA);
        gload_lds16(aU + aOf[1] + ko, dA + 4096);
        gload_lds16(bU + bOf[0] + ko, dB);
        gload_lds16(bU + bOf[1] + ko, dB + 4096);
    };

    // fragment read offsets within a slot plane (u16 units), swizzled
    int offA[8], offB[4];
    #pragma unroll
    for (int m = 0; m < 8; ++m) {
        const int r = wm * 128 + m * 16 + r16;
        offA[m] = r * 32 + ((g16 ^ ((r >> 1) & 3)) * 8);
    }
    #pragma unroll
    for (int n = 0; n < 4; ++n) {
        const int r = wn * 64 + n * 16 + r16;
        offB[n] = r * 32 + ((g16 ^ ((r >> 1) & 3)) * 8);
    }

    f32x4 acc[8][4] = {};
    bf16x8 af0[8], b0[4], af1[8], b1[4];   // two named register sets (rule #20)

    // prologue: stage slots 0,1,2 (12 gloads); retire slots 0,1; read slot0.
    stage(0); stage(1); stage(2);
    asm volatile("s_waitcnt vmcnt(4)" ::: "memory");
    __builtin_amdgcn_s_barrier();
    {
        const u16* PA = &lds[0][0][0]; const u16* PB = &lds[0][1][0];
        #pragma unroll
        for (int m = 0; m < 8; ++m) af0[m] = ldf(PA + offA[m]);
        #pragma unroll
        for (int n = 0; n < 4; ++n) b0[n]  = ldf(PB + offB[n]);
    }

    for (int kt = 0; kt < NT; ++kt) {
        const int pe = 2 * kt;              // even phase index
        // ---- even phase pe: stage pe+3; read slot pe+1 -> set1; MFMA set0 ----
        if (pe + 3 < 2 * NT) stage(pe + 3);
        {
            const u16* PA = &lds[(pe + 1) & 3][0][0];
            const u16* PB = &lds[(pe + 1) & 3][1][0];
            #pragma unroll
            for (int m = 0; m < 8; ++m) af1[m] = ldf(PA + offA[m]);
            #pragma unroll
            for (int n = 0; n < 4; ++n) b1[n]  = ldf(PB + offB[n]);
        }
        __builtin_amdgcn_s_setprio(1);
        #pragma unroll
        for (int m = 0; m < 8; ++m)
            #pragma unroll
            for (int n = 0; n < 4; ++n)
                acc[m][n] = mfma16(af0[m], b0[n], acc[m][n]);
        __builtin_amdgcn_s_setprio(0);
        if (pe + 2 < 2 * NT) { asm volatile("s_waitcnt vmcnt(4)" ::: "memory"); }
        __builtin_amdgcn_s_barrier();

        // ---- odd phase po = pe+1: stage po+3; read slot po+1 -> set0; MFMA set1 ----
        const int po = pe + 1;
        if (po + 3 < 2 * NT) stage(po + 3);
        if (po + 1 < 2 * NT) {
            const u16* PA = &lds[(po + 1) & 3][0][0];
            const u16* PB = &lds[(po + 1) & 3][1][0];
            #pragma unroll
            for (int m = 0; m < 8; ++m) af0[m] = ldf(PA + offA[m]);
            #pragma unroll
            for (int n = 0; n < 4; ++n) b0[n]  = ldf(PB + offB[n]);
        }
        __builtin_amdgcn_s_setprio(1);
        #pragma unroll
        for (int m = 0; m < 8; ++m)
            #pragma unroll
            for (int n = 0; n < 4; ++n)
                acc[m][n] = mfma16(af1[m], b1[n], acc[m][n]);
        __builtin_amdgcn_s_setprio(0);
        if (po + 2 < 2 * NT) {
            asm volatile("s_waitcnt vmcnt(4)" ::: "memory");
            __builtin_amdgcn_s_barrier();
        }
    }

    if constexpr (EPI == 1) {
        u16* P = (u16*)Cout + (size_t)blockIdx.z * planeEls;
        #pragma unroll
        for (int m = 0; m < 8; ++m) {
            #pragma unroll
            for (int n = 0; n < 4; ++n) {
                #pragma unroll
                for (int r = 0; r < 4; ++r) {
                    const int row = bm * 256 + wm * 128 + m * 16 + g16 * 4 + r;
                    const int col = bn * 256 + wn * 64 + n * 16 + r16;
                    P[(size_t)row * outLd + col] = f2bf(acc[m][n][r]);
                }
            }
        }
    } else {
        (void)planeEls;
        u16* O = (u16*)Cout;
        #pragma unroll
        for (int m = 0; m < 8; ++m) {
            #pragma unroll
            for (int n = 0; n < 2; ++n) {
                #pragma unroll
                for (int r = 0; r < 4; ++r) {
                    const int row = bm * 256 + wm * 128 + m * 16 + g16 * 4 + r;
                    const int col = (bn * 4 + wn) * 32 + n * 16 + r16;
                    const float vi = acc[m][n][r];
                    const float vg = acc[m][n + 2][r];
                    const float sl = vi / (1.0f + __expf(-vi));
                    O[(size_t)row * outLd + col] = f2bf(sl * vg);
                }
            }
        }
    }
}

// ---------- split-K reduce: out = resid + sum of 4 bf16 planes ----------
__global__ __launch_bounds__(256) void addreduce4_k(const float* __restrict__ resid,
                                                    const u16* __restrict__ p,
                                                    float* __restrict__ out,
                                                    int n4, int planeEls) {
    for (int i = blockIdx.x * 256 + threadIdx.x; i < n4; i += gridDim.x * 256) {
        F4 a = *(const F4*)(resid + (size_t)i * 4);
        U4 q0 = *(const U4*)(p + (size_t)i * 4);
        U4 q1 = *(const U4*)(p + (size_t)planeEls + (size_t)i * 4);
        U4 q2 = *(const U4*)(p + (size_t)2 * planeEls + (size_t)i * 4);
        U4 q3 = *(const U4*)(p + (size_t)3 * planeEls + (size_t)i * 4);
        F4 o;
        #pragma unroll
        for (int j = 0; j < 4; ++j)
            o.v[j] = a.v[j] + bf2f(q0.v[j]) + bf2f(q1.v[j]) + bf2f(q2.v[j]) + bf2f(q3.v[j]);
        *(F4*)(out + (size_t)i * 4) = o;
    }
}

// ---------- flash attention v3 (causal), transpose-world + LDS-staged K/V ----------
__global__ __launch_bounds__(256) void attn_fwd_k(const u16* __restrict__ qk,
                                                  const u16* __restrict__ vt,
                                                  u16* __restrict__ Ob) {
    __shared__ u16 Klds[2][64 * 64];
    __shared__ u16 Vlds[2][64 * 64];

    const int tid  = threadIdx.x;
    const int wave = tid >> 6, lane = tid & 63;
    const int r16  = lane & 15, g16 = lane >> 4;

    const int blk = blockIdx.x;
    const int xcd = blk & 7;
    const int pc  = blk >> 3;
    const int hh  = pc >> 5;
    const int qb  = (31 - (pc & 31) + 8 * hh) & 31;
    const int bh  = xcd * 4 + hh;
    const int h   = bh & 15, b = bh >> 4;

    const int q0w = qb * 64 + wave * 16;
    const size_t seqb = (size_t)b * 2048;

    const u16* qp = qk + (seqb + q0w + r16) * 2048 + h * 64 + g16 * 8;
    const bf16x8 qf0 = *(const bf16x8*)qp;
    const bf16x8 qf1 = *(const bf16x8*)(qp + 32);

    const u16* kbase = qk + seqb * 2048 + 1024 + (size_t)h * 64;
    const u16* vbase = vt + (size_t)(h * 64) * 4096 + seqb;

    const int srow  = tid >> 3;                           // 0..31
    const int scol8 = ((tid & 7) ^ (srow & 7)) * 8;
    const u16* ksrc = kbase + (size_t)srow * 2048 + scol8;
    const u16* vsrc = vbase + (size_t)srow * 4096 + scol8;

    auto stage = [&](int bufi, int kv0) {
        const u16* kp = ksrc + (size_t)kv0 * 2048;
        const u16* vp = vsrc + kv0;
        u16* kd = &Klds[bufi][wave * 512];
        u16* vd = &Vlds[bufi][wave * 512];
        gload_lds16(kp, kd);
        gload_lds16(kp + (size_t)32 * 2048, kd + 2048);
        gload_lds16(vp, vd);
        gload_lds16(vp + (size_t)32 * 4096, vd + 2048);
    };

    f32x4 o[4] = {};
    float mreg = -3.0e38f, lreg = 0.0f;
    constexpr float SC = 0.125f * 1.44269504088896341f;   // Dh^-0.5 * log2(e)

    const int nt = qb + 1;
    stage(0, 0);
    asm volatile("s_waitcnt vmcnt(0)" ::: "memory");
    __builtin_amdgcn_s_barrier();

    for (int it = 0; it < nt; ++it) {
        const int kv0 = it * 64;
        const int cur = it & 1;
        if (it + 1 < nt) stage(cur ^ 1, kv0 + 64);

        const u16* K = Klds[cur];
        const u16* V = Vlds[cur];

        f32x4 s[4];
        #pragma unroll
        for (int t = 0; t < 4; ++t) {
            const int row = 16 * t + r16;
            const int sw  = row & 7;
            const bf16x8 k0 = *(const bf16x8*)&K[row * 64 + ((g16 ^ sw) * 8)];
            const bf16x8 k1 = *(const bf16x8*)&K[row * 64 + (((g16 + 4) ^ sw) * 8)];
            f32x4 acc = {0.f, 0.f, 0.f, 0.f};
            acc = mfma16(k0, qf0, acc);
            acc = mfma16(k1, qf1, acc);
            s[t] = acc;
        }

        float a[16];
        #pragma unroll
        for (int t = 0; t < 4; ++t)
            #pragma unroll
            for (int r = 0; r < 4; ++r) a[4 * t + r] = s[t][r] * SC;

        if (kv0 + 63 > q0w) {
            const int qg = q0w + r16;
            #pragma unroll
            for (int t = 0; t < 4; ++t)
                #pragma unroll
                for (int r = 0; r < 4; ++r)
                    if (kv0 + 16 * t + 4 * g16 + r > qg) a[4 * t + r] = -1.0e30f;
        }

        float mx = a[0];
        #pragma unroll
        for (int j = 1; j < 16; ++j) mx = fmaxf(mx, a[j]);
        mx = fmaxf(mx, __shfl_xor(mx, 16));
        mx = fmaxf(mx, __shfl_xor(mx, 32));
        const float mn = fmaxf(mreg, mx);
        const float al = exp2f(mreg - mn);
        float p[16], rs = 0.0f;
        #pragma unroll
        for (int j = 0; j < 16; ++j) { p[j] = exp2f(a[j] - mn); rs += p[j]; }
        rs += __shfl_xor(rs, 16);
        rs += __shfl_xor(rs, 32);
        lreg = lreg * al + rs;
        mreg = mn;

        bf16x8 pf0, pf1;
        #pragma unroll
        for (int j = 0; j < 8; ++j) { pf0[j] = (__bf16)p[j]; pf1[j] = (__bf16)p[8 + j]; }

        #pragma unroll
        for (int t = 0; t < 4; ++t) {
            const int row  = 16 * t + r16;
            const int sw   = row & 7;
            const int base = row * 64 + (g16 & 1) * 4;
            const int c0   = g16 >> 1;
            U4 a0 = *(const U4*)&V[base + (((c0 + 0) ^ sw) * 8)];
            U4 a1 = *(const U4*)&V[base + (((c0 + 2) ^ sw) * 8)];
            U4 b0 = *(const U4*)&V[base + (((c0 + 4) ^ sw) * 8)];
            U4 b1 = *(const U4*)&V[base + (((c0 + 6) ^ sw) * 8)];
            #pragma unroll
            for (int r = 0; r < 4; ++r) o[t][r] *= al;
            bf16x8 v0, v1;
            #pragma unroll
            for (int j = 0; j < 4; ++j) {
                v0[j]     = ((const __bf16*)&a0)[j];
                v0[4 + j] = ((const __bf16*)&a1)[j];
                v1[j]     = ((const __bf16*)&b0)[j];
                v1[4 + j] = ((const __bf16*)&b1)[j];
            }
            o[t] = mfma16(v0, pf0, o[t]);
            o[t] = mfma16(v1, pf1, o[t]);
        }

        if (it + 1 < nt) {
            asm volatile("s_waitcnt vmcnt(0)" ::: "memory");
            __builtin_amdgcn_s_barrier();
        }
    }

    const float inv = 1.0f / lreg;
    u16* op = Ob + (seqb + q0w + r16) * 1024 + h * 64 + 4 * g16;
    #pragma unroll
    for (int t = 0; t < 4; ++t) {
        U4 st;
        #pragma unroll
        for (int r = 0; r < 4; ++r) st.v[r] = f2bf(o[t][r] * inv);
        *(U4*)(op + 16 * t) = st;
    }
}

// ---------- launch ----------
extern "C" void kernel_launch(void* const* d_in, const int* in_sizes, int n_in,
                              void* d_out, int out_size, void* d_ws, size_t ws_size,
                              hipStream_t stream) {
    (void)in_sizes; (void)n_in; (void)out_size; (void)ws_size;
    constexpr int C = 1024, FF = 4096, M = 2 * 2048;   // B*T = 4096
    constexpr size_t MB = 1024 * 1024;

    const float* x      = (const float*)d_in[0];
    const float* ln1_w  = (const float*)d_in[1];
    const float* ln1_b  = (const float*)d_in[2];
    const float* qkv_w  = (const float*)d_in[3];
    const float* atto_w = (const float*)d_in[4];
    const float* ln2_w  = (const float*)d_in[5];
    const float* ln2_b  = (const float*)d_in[6];
    const float* mlpi_w = (const float*)d_in[7];
    const float* mlpg_w = (const float*)d_in[8];
    const float* mlpo_w = (const float*)d_in[9];
    float* out = (float*)d_out;

    char* ws = (char*)d_ws;
    size_t off = 0;
    auto alloc = [&](size_t bytes) {
        char* p = ws + off;
        off += (bytes + 255) & ~(size_t)255;
        return p;
    };
    u16*   wq   = (u16*)  alloc((size_t)3 * C * C * 2);   // qkv_w bf16 (Q,K rows then V)
    u16*   wo   = (u16*)  alloc((size_t)C * C * 2);
    u16*   wig  = (u16*)  alloc((size_t)2 * FF * C * 2);  // interleaved wi/wg [8192][1024]
    u16*   wm   = (u16*)  alloc((size_t)C * FF * 2);
    float* x1   = (float*)alloc((size_t)M * C * 4);
    u16*   h2   = (u16*)  alloc((size_t)M * C * 2);
    u16*   ab   = (u16*)  alloc((size_t)M * FF * 2);
    // region R (64 MB): attn-phase buffers, later reused as split-K partials
    char*  R    = alloc(64 * MB);
    u16*   h1   = (u16*)R;                 //  8 MB
    u16*   qk_b = (u16*)(R + 8 * MB);      // 16 MB  [4096][2048] Q|K
    u16*   vt_b = (u16*)(R + 24 * MB);     //  8 MB  [1024][4096] V^T
    u16*   Ob   = (u16*)(R + 32 * MB);     //  8 MB
    u16*   pscr = (u16*)R;                 // 32 MB  (4 bf16 planes x 8 MB) — after attn

    // weight casts
    cast_bf16_k<<<(3 * C * C / 4) / 256, 256, 0, stream>>>(qkv_w, wq, 3 * C * C / 4);
    cast_bf16_k<<<(C * C / 4) / 256, 256, 0, stream>>>(atto_w, wo, C * C / 4);
    cast_bf16_k<<<(C * FF / 4) / 256, 256, 0, stream>>>(mlpo_w, wm, C * FF / 4);
    cast_wig_k<<<(2 * FF * C / 8) / 256, 256, 0, stream>>>(mlpi_w, mlpg_w, wig);

    // attention branch
    ln_fwd_k<<<M, 256, 0, stream>>>(x, ln1_w, ln1_b, h1);
    gemm_bt_k<0><<<dim3(2 * C / 128, M / 128), 256, 0, stream>>>(h1, wq, qk_b, nullptr, M, 2 * C, C);
    const u16* wv = wq + (size_t)2 * C * C;
    gemm_bt_k<0><<<dim3(M / 128, C / 128), 256, 0, stream>>>(wv, h1, vt_b, nullptr, C, M, C);
    attn_fwd_k<<<1024, 256, 0, stream>>>(qk_b, vt_b, Ob);
    gemm_bt_k<1><<<dim3(C / 128, M / 128), 256, 0, stream>>>(Ob, wo, x1, x, M, C, C);

    // MLP branch
    ln_fwd_k<<<M, 256, 0, stream>>>(x1, ln2_w, ln2_b, h2);
    // fused (in|gate) GEMM + SwiGLU: grid 32x16=512; XCD chunk 8bm x 8bn
    gemm256_k<2><<<dim3((2 * FF / 256) * (M / 256), 1, 1), 512, 0, stream>>>(
        h2, wig, ab, C, C, C, 2 * FF / 256, 8, FF, 0);
    // mlp_out: split-K=4 (grid 4x16 x4 = 256), bf16 partials; XCD chunk 2bm x 4bn
    gemm256_k<1><<<dim3((C / 256) * (M / 256), 1, 4), 512, 0, stream>>>(
        ab, wm, pscr, FF, FF, FF / 4, C / 256, 4, C, M * C);
    addreduce4_k<<<2048, 256, 0, stream>>>(x1, pscr, out, M * C / 4, M * C);
}

// Round 10
// 256.590 us; speedup vs baseline: 2.5828x; 1.1381x over previous
//
#include <hip/hip_runtime.h>
#include <cstdint>

// ---------- types & helpers ----------
typedef unsigned short u16;
typedef __bf16 bf16x8 __attribute__((ext_vector_type(8)));
typedef float  f32x4  __attribute__((ext_vector_type(4)));

struct alignas(16) F4 { float v[4]; };
struct alignas(8)  U4 { u16 v[4]; };
struct alignas(16) U8 { u16 v[8]; };

__device__ __forceinline__ u16 f2bf(float f) {
    union { float f; unsigned int u; } x; x.f = f;
    unsigned int r = x.u + 0x7fffu + ((x.u >> 16) & 1u);   // RNE
    return (u16)(r >> 16);
}
__device__ __forceinline__ float bf2f(u16 u) {
    union { unsigned int u; float f; } x; x.u = ((unsigned int)u) << 16;
    return x.f;
}
__device__ __forceinline__ f32x4 mfma16(bf16x8 a, bf16x8 b, f32x4 c) {
    return __builtin_amdgcn_mfma_f32_16x16x32_bf16(a, b, c, 0, 0, 0);
}
__device__ __forceinline__ bf16x8 ldf(const u16* p) { return *(const bf16x8*)p; }
// async global->LDS, 16B per lane, dest = wave-uniform base + lane*16
__device__ __forceinline__ void gload_lds16(const void* g, void* l) {
    auto* gp = reinterpret_cast<const __attribute__((address_space(1))) unsigned int*>(
        reinterpret_cast<uintptr_t>(g));
    auto* lp = reinterpret_cast<__attribute__((address_space(3))) unsigned int*>(
        reinterpret_cast<uintptr_t>(l));
    __builtin_amdgcn_global_load_lds(gp, lp, 16, 0, 0);
}

// ---------- ALL weight casts in one kernel ----------
// segments: wq (3C*C), wo (C*C), wm (C*FF), wig (2FF*C row-interleaved 32in/32gate)
__global__ __launch_bounds__(256) void cast_all_k(const float* __restrict__ qkvw,
                                                  const float* __restrict__ attow,
                                                  const float* __restrict__ mlpow,
                                                  const float* __restrict__ wi,
                                                  const float* __restrict__ wg,
                                                  u16* __restrict__ wq,
                                                  u16* __restrict__ wo,
                                                  u16* __restrict__ wm,
                                                  u16* __restrict__ wig) {
    constexpr int N1 = 3 * 1024 * 1024 / 8;            // wq units-of-8
    constexpr int N2 = N1 + 1024 * 1024 / 8;           // +wo
    constexpr int N3 = N2 + 1024 * 4096 / 8;           // +wm
    const int i = blockIdx.x * 256 + threadIdx.x;
    const float* src; u16* dst;
    if (i < N1)      { src = qkvw  + (size_t)i * 8;        dst = wq + (size_t)i * 8; }
    else if (i < N2) { const int j = i - N1; src = attow + (size_t)j * 8; dst = wo + (size_t)j * 8; }
    else if (i < N3) { const int j = i - N2; src = mlpow + (size_t)j * 8; dst = wm + (size_t)j * 8; }
    else {
        const int j = i - N3;
        const int w = j >> 7, c8 = (j & 127) * 8;
        const int f = ((w >> 6) << 5) | (w & 31);
        src = ((w & 32) ? wg : wi) + (size_t)f * 1024 + c8;
        dst = wig + (size_t)w * 1024 + c8;
    }
    F4 a = *(const F4*)src;
    F4 b = *(const F4*)(src + 4);
    U8 o;
    #pragma unroll
    for (int j = 0; j < 4; ++j) { o.v[j] = f2bf(a.v[j]); o.v[4 + j] = f2bf(b.v[j]); }
    *(U8*)dst = o;
}

// ---------- LayerNorm (C=1024), f32 in -> bf16 out ----------
__global__ __launch_bounds__(256) void ln_fwd_k(const float* __restrict__ x,
                                                const float* __restrict__ w,
                                                const float* __restrict__ b,
                                                u16* __restrict__ h) {
    const int row = blockIdx.x, tid = threadIdx.x;
    const float* xr = x + (size_t)row * 1024;
    F4 v = *(const F4*)(xr + tid * 4);
    float s  = v.v[0] + v.v[1] + v.v[2] + v.v[3];
    float ss = v.v[0]*v.v[0] + v.v[1]*v.v[1] + v.v[2]*v.v[2] + v.v[3]*v.v[3];
    #pragma unroll
    for (int o = 32; o > 0; o >>= 1) { s += __shfl_down(s, o); ss += __shfl_down(ss, o); }
    __shared__ float red[8];
    const int wave = tid >> 6, lane = tid & 63;
    if (lane == 0) { red[wave] = s; red[4 + wave] = ss; }
    __syncthreads();
    s  = red[0] + red[1] + red[2] + red[3];
    ss = red[4] + red[5] + red[6] + red[7];
    const float mu   = s * (1.0f / 1024.0f);
    const float var  = ss * (1.0f / 1024.0f) - mu * mu;
    const float rstd = rsqrtf(var + 1e-5f);
    U4 o;
    #pragma unroll
    for (int j = 0; j < 4; ++j)
        o.v[j] = f2bf((v.v[j] - mu) * rstd * w[tid * 4 + j] + b[tid * 4 + j]);
    *(U4*)(h + (size_t)row * 1024 + tid * 4) = o;
}

// ---------- fused residual + LN2: x1 = x + p0 + p1 (bf16 planes); h2 = LN(x1) ----------
__global__ __launch_bounds__(256) void ln_resid_k(const float* __restrict__ x,
                                                  const u16* __restrict__ p,
                                                  const float* __restrict__ w,
                                                  const float* __restrict__ b,
                                                  float* __restrict__ x1,
                                                  u16* __restrict__ h,
                                                  int planeEls) {
    const int row = blockIdx.x, tid = threadIdx.x;
    const size_t base = (size_t)row * 1024 + tid * 4;
    F4 xv = *(const F4*)(x + base);
    U4 q0 = *(const U4*)(p + base);
    U4 q1 = *(const U4*)(p + (size_t)planeEls + base);
    F4 sv;
    #pragma unroll
    for (int j = 0; j < 4; ++j) sv.v[j] = xv.v[j] + bf2f(q0.v[j]) + bf2f(q1.v[j]);
    *(F4*)(x1 + base) = sv;
    float s  = sv.v[0] + sv.v[1] + sv.v[2] + sv.v[3];
    float ss = sv.v[0]*sv.v[0] + sv.v[1]*sv.v[1] + sv.v[2]*sv.v[2] + sv.v[3]*sv.v[3];
    #pragma unroll
    for (int o = 32; o > 0; o >>= 1) { s += __shfl_down(s, o); ss += __shfl_down(ss, o); }
    __shared__ float red[8];
    const int wave = tid >> 6, lane = tid & 63;
    if (lane == 0) { red[wave] = s; red[4 + wave] = ss; }
    __syncthreads();
    s  = red[0] + red[1] + red[2] + red[3];
    ss = red[4] + red[5] + red[6] + red[7];
    const float mu   = s * (1.0f / 1024.0f);
    const float var  = ss * (1.0f / 1024.0f) - mu * mu;
    const float rstd = rsqrtf(var + 1e-5f);
    U4 o;
    #pragma unroll
    for (int j = 0; j < 4; ++j)
        o.v[j] = f2bf((sv.v[j] - mu) * rstd * w[tid * 4 + j] + b[tid * 4 + j]);
    *(U4*)(h + base) = o;
}

// ---------- combined qk + vt GEMM (one dispatch, 768 blocks) ----------
// role 0 (bid<512):  qk_b[4096][2048] = h1 @ wq^T   (bn=bid&15, bm=bid>>4)
// role 1 (bid>=512): vt_b[1024][4096] = wv @ h1^T   (bn=id&31,  bm=id>>5)
__global__ __launch_bounds__(256) void gemm_qkvt_k(const u16* __restrict__ h1,
                                                   const u16* __restrict__ wq,
                                                   u16* __restrict__ qk_b,
                                                   u16* __restrict__ vt_b) {
    __shared__ alignas(16) u16 Alds[128 * 32];
    __shared__ alignas(16) u16 Blds[128 * 32];
    const int tid  = threadIdx.x;
    const int lane = tid & 63, wave = tid >> 6;
    const int wr = wave >> 1, wc = wave & 1;
    const int r16 = lane & 15, g16 = lane >> 4;

    const u16* A; const u16* Bm; u16* Cout; int bn, bm, N;
    const int bid = blockIdx.x;
    if (bid < 512) { A = h1; Bm = wq; Cout = qk_b; N = 2048; bn = bid & 15; bm = bid >> 4; }
    else {
        const int id = bid - 512;
        A = wq + (size_t)2 * 1024 * 1024;   // wv rows
        Bm = h1; Cout = vt_b; N = 4096; bn = id & 31; bm = id >> 5;
    }
    constexpr int K = 1024;

    const int srow = lane >> 2;
    const int scol = (lane & 3) * 8;

    f32x4 acc[4][4] = {};

    for (int k0 = 0; k0 < K; k0 += 32) {
        #pragma unroll
        for (int c = 0; c < 2; ++c) {
            const int ch = wave * 2 + c;
            const u16* ga = A  + ((size_t)bm * 128 + ch * 16 + srow) * K + k0 + scol;
            gload_lds16(ga, &Alds[ch * 512]);
            const u16* gb = Bm + ((size_t)bn * 128 + ch * 16 + srow) * K + k0 + scol;
            gload_lds16(gb, &Blds[ch * 512]);
        }
        __syncthreads();
        bf16x8 af[4], bfr[4];
        #pragma unroll
        for (int m = 0; m < 4; ++m)
            af[m] = ldf(&Alds[(wr * 64 + m * 16 + r16) * 32 + g16 * 8]);
        #pragma unroll
        for (int n = 0; n < 4; ++n)
            bfr[n] = ldf(&Blds[(wc * 64 + n * 16 + r16) * 32 + g16 * 8]);
        #pragma unroll
        for (int m = 0; m < 4; ++m)
            #pragma unroll
            for (int n = 0; n < 4; ++n)
                acc[m][n] = mfma16(af[m], bfr[n], acc[m][n]);
        __syncthreads();
    }

    #pragma unroll
    for (int m = 0; m < 4; ++m)
        #pragma unroll
        for (int n = 0; n < 4; ++n)
            #pragma unroll
            for (int r = 0; r < 4; ++r) {
                const int row = bm * 128 + wr * 64 + m * 16 + g16 * 4 + r;
                const int col = bn * 128 + wc * 64 + n * 16 + r16;
                Cout[(size_t)row * N + col] = f2bf(acc[m][n][r]);
            }
}

// ---------- 128x128 GEMM, split-K bf16 partial planes (attn_out) ----------
__global__ __launch_bounds__(256) void gemm_btsplit_k(const u16* __restrict__ A,
                                                      const u16* __restrict__ Bm,
                                                      u16* __restrict__ P,
                                                      int N, int K, int kchunk,
                                                      int planeEls) {
    __shared__ alignas(16) u16 Alds[128 * 32];
    __shared__ alignas(16) u16 Blds[128 * 32];
    const int tid  = threadIdx.x;
    const int lane = tid & 63, wave = tid >> 6;
    const int wr = wave >> 1, wc = wave & 1;
    const int r16 = lane & 15, g16 = lane >> 4;
    const int bn = blockIdx.x, bm = blockIdx.y;
    const int kBeg = blockIdx.z * kchunk;

    const int srow = lane >> 2;
    const int scol = (lane & 3) * 8;

    f32x4 acc[4][4] = {};

    for (int k0 = kBeg; k0 < kBeg + kchunk; k0 += 32) {
        #pragma unroll
        for (int c = 0; c < 2; ++c) {
            const int ch = wave * 2 + c;
            const u16* ga = A  + ((size_t)bm * 128 + ch * 16 + srow) * K + k0 + scol;
            gload_lds16(ga, &Alds[ch * 512]);
            const u16* gb = Bm + ((size_t)bn * 128 + ch * 16 + srow) * K + k0 + scol;
            gload_lds16(gb, &Blds[ch * 512]);
        }
        __syncthreads();
        bf16x8 af[4], bfr[4];
        #pragma unroll
        for (int m = 0; m < 4; ++m)
            af[m] = ldf(&Alds[(wr * 64 + m * 16 + r16) * 32 + g16 * 8]);
        #pragma unroll
        for (int n = 0; n < 4; ++n)
            bfr[n] = ldf(&Blds[(wc * 64 + n * 16 + r16) * 32 + g16 * 8]);
        #pragma unroll
        for (int m = 0; m < 4; ++m)
            #pragma unroll
            for (int n = 0; n < 4; ++n)
                acc[m][n] = mfma16(af[m], bfr[n], acc[m][n]);
        __syncthreads();
    }

    u16* Pp = P + (size_t)blockIdx.z * planeEls;
    #pragma unroll
    for (int m = 0; m < 4; ++m)
        #pragma unroll
        for (int n = 0; n < 4; ++n)
            #pragma unroll
            for (int r = 0; r < 4; ++r) {
                const int row = bm * 128 + wr * 64 + m * 16 + g16 * 4 + r;
                const int col = bn * 128 + wc * 64 + n * 16 + r16;
                Pp[(size_t)row * N + col] = f2bf(acc[m][n][r]);
            }
}

// ---------- 256x256 pipelined GEMM v3 (frag-prefetch; best measured) ----------
// EPI 1: bf16 partials (plane blockIdx.z).  EPI 2: fused SwiGLU bf16.
template <int EPI>
__global__ __launch_bounds__(512, 2)
void gemm256_k(const u16* __restrict__ A, const u16* __restrict__ Bm,
               void* __restrict__ Cout, int lda, int ldb, int kLen,
               int nx, int bnCh, int outLd, int planeEls) {
    __shared__ alignas(16) u16 lds[2][2][2][128 * 64];

    const int tid  = threadIdx.x;
    const int wave = tid >> 6, lane = tid & 63;
    const int wm = wave >> 2, wn = wave & 3;
    const int r16 = lane & 15, g16 = lane >> 4;

    const int cpx = gridDim.x >> 3;
    const int xcd = blockIdx.x & 7, loc = blockIdx.x >> 3;
    const int mCh = cpx / bnCh;
    const int cpr = nx / bnCh;
    const int bm = (xcd / cpr) * mCh + loc / bnCh;
    const int bn = (xcd % cpr) * bnCh + loc % bnCh;
    const int kBeg = blockIdx.z * kLen;
    const int NT = kLen >> 6;

    const int csw = ((lane & 7) ^ (lane >> 3)) * 8;
    const u16* aU = A  + (size_t)(bm * 256) * lda + kBeg;
    const u16* bU = Bm + (size_t)(bn * 256) * ldb + kBeg;
    int aOff[2][2], bOff[2][2];
    #pragma unroll
    for (int h = 0; h < 2; ++h)
        #pragma unroll
        for (int i = 0; i < 2; ++i) {
            const int wr = wave * 16 + (lane >> 3) + i * 8;
            const int ar = (wr >> 6) * 128 + h * 64 + (wr & 63);
            const int br = (wr >> 5) * 64 + h * 32 + (wr & 31);
            aOff[h][i] = ar * lda + csw;
            bOff[h][i] = br * ldb + csw;
        }

    auto stA = [&](int kt, int h) {
        u16* d = &lds[kt & 1][0][h][wave * 1024];
        gload_lds16(aU + aOff[h][0] + kt * 64, d);
        gload_lds16(aU + aOff[h][1] + kt * 64, d + 512);
    };
    auto stB = [&](int kt, int h) {
        u16* d = &lds[kt & 1][1][h][wave * 1024];
        gload_lds16(bU + bOff[h][0] + kt * 64, d);
        gload_lds16(bU + bOff[h][1] + kt * 64, d + 512);
    };

    int offA[4][2], offB[2][2];
    #pragma unroll
    for (int m = 0; m < 4; ++m)
        #pragma unroll
        for (int ks = 0; ks < 2; ++ks)
            offA[m][ks] = (wm * 64 + m * 16 + r16) * 64 + (((ks * 4 + g16) ^ (r16 & 7)) * 8);
    #pragma unroll
    for (int n = 0; n < 2; ++n)
        #pragma unroll
        for (int ks = 0; ks < 2; ++ks)
            offB[n][ks] = (wn * 32 + n * 16 + r16) * 64 + (((ks * 4 + g16) ^ (r16 & 7)) * 8);

    f32x4 acc[8][4] = {};
    bf16x8 af0[4][2], af1[4][2], b0v[2][2], b1v[2][2];

    auto rdAF0 = [&](int buf) {
        const u16* P = &lds[buf][0][0][0];
        #pragma unroll
        for (int m = 0; m < 4; ++m) { af0[m][0] = ldf(P + offA[m][0]); af0[m][1] = ldf(P + offA[m][1]); }
    };
    auto rdAF1 = [&](int buf) {
        const u16* P = &lds[buf][0][1][0];
        #pragma unroll
        for (int m = 0; m < 4; ++m) { af1[m][0] = ldf(P + offA[m][0]); af1[m][1] = ldf(P + offA[m][1]); }
    };
    auto rdB0 = [&](int buf) {
        const u16* P = &lds[buf][1][0][0];
        #pragma unroll
        for (int n = 0; n < 2; ++n) { b0v[n][0] = ldf(P + offB[n][0]); b0v[n][1] = ldf(P + offB[n][1]); }
    };
    auto rdB1 = [&](int buf) {
        const u16* P = &lds[buf][1][1][0];
        #pragma unroll
        for (int n = 0; n < 2; ++n) { b1v[n][0] = ldf(P + offB[n][0]); b1v[n][1] = ldf(P + offB[n][1]); }
    };

    stA(0, 0); stB(0, 0); stB(0, 1); stA(0, 1);
    stA(1, 0); stB(1, 0); stB(1, 1); stA(1, 1);
    asm volatile("s_waitcnt vmcnt(8)" ::: "memory");
    __builtin_amdgcn_s_barrier();
    rdAF0(0); rdB0(0); rdB1(0); rdAF1(0);

    for (int kt = 0; kt < NT; ++kt) {
        const bool pf = (kt + 2 < NT);
        const int nb = (kt + 1) & 1;

        __builtin_amdgcn_s_setprio(1);
        #pragma unroll
        for (int m = 0; m < 4; ++m)
            #pragma unroll
            for (int n = 0; n < 2; ++n) {
                acc[m][n] = mfma16(af0[m][0], b0v[n][0], acc[m][n]);
                acc[m][n] = mfma16(af0[m][1], b0v[n][1], acc[m][n]);
            }
        __builtin_amdgcn_s_setprio(0);
        __builtin_amdgcn_s_barrier();

        if (pf) { stA(kt + 2, 0); stB(kt + 2, 0); }
        __builtin_amdgcn_s_setprio(1);
        #pragma unroll
        for (int m = 0; m < 4; ++m)
            #pragma unroll
            for (int n = 0; n < 2; ++n) {
                acc[m][n + 2] = mfma16(af0[m][0], b1v[n][0], acc[m][n + 2]);
                acc[m][n + 2] = mfma16(af0[m][1], b1v[n][1], acc[m][n + 2]);
            }
        __builtin_amdgcn_s_setprio(0);
        __builtin_amdgcn_s_barrier();

        if (pf) stB(kt + 2, 1);
        __builtin_amdgcn_s_setprio(1);
        #pragma unroll
        for (int m = 0; m < 4; ++m)
            #pragma unroll
            for (int n = 0; n < 2; ++n) {
                acc[m + 4][n] = mfma16(af1[m][0], b0v[n][0], acc[m + 4][n]);
                acc[m + 4][n] = mfma16(af1[m][1], b0v[n][1], acc[m + 4][n]);
            }
        __builtin_amdgcn_s_setprio(0);
        __builtin_amdgcn_s_barrier();

        if (pf) stA(kt + 2, 1);
        if (pf)               { asm volatile("s_waitcnt vmcnt(8)" ::: "memory"); }
        else if (kt + 1 < NT) { asm volatile("s_waitcnt vmcnt(0)" ::: "memory"); }
        if (kt + 1 < NT) {
            __builtin_amdgcn_s_barrier();
            rdAF0(nb); rdB0(nb);
        }
        __builtin_amdgcn_s_setprio(1);
        #pragma unroll
        for (int m = 0; m < 4; ++m)
            #pragma unroll
            for (int n = 0; n < 2; ++n) {
                acc[m + 4][n + 2] = mfma16(af1[m][0], b1v[n][0], acc[m + 4][n + 2]);
                acc[m + 4][n + 2] = mfma16(af1[m][1], b1v[n][1], acc[m + 4][n + 2]);
            }
        __builtin_amdgcn_s_setprio(0);
        if (kt + 1 < NT) { rdB1(nb); rdAF1(nb); }
    }

    if constexpr (EPI == 1) {
        u16* P = (u16*)Cout + (size_t)blockIdx.z * planeEls;
        #pragma unroll
        for (int m = 0; m < 8; ++m)
            #pragma unroll
            for (int n = 0; n < 4; ++n)
                #pragma unroll
                for (int r = 0; r < 4; ++r) {
                    const int row = bm * 256 + wm * 128 + m * 16 + g16 * 4 + r;
                    const int col = bn * 256 + wn * 64 + n * 16 + r16;
                    P[(size_t)row * outLd + col] = f2bf(acc[m][n][r]);
                }
    } else {
        (void)planeEls;
        u16* O = (u16*)Cout;
        #pragma unroll
        for (int m = 0; m < 8; ++m)
            #pragma unroll
            for (int n = 0; n < 2; ++n)
                #pragma unroll
                for (int r = 0; r < 4; ++r) {
                    const int row = bm * 256 + wm * 128 + m * 16 + g16 * 4 + r;
                    const int col = (bn * 4 + wn) * 32 + n * 16 + r16;
                    const float vi = acc[m][n][r];
                    const float vg = acc[m][n + 2][r];
                    const float sl = vi / (1.0f + __expf(-vi));
                    O[(size_t)row * outLd + col] = f2bf(sl * vg);
                }
    }
}

// ---------- split-K reduce: out = resid + sum of 4 bf16 planes ----------
__global__ __launch_bounds__(256) void addreduce4_k(const float* __restrict__ resid,
                                                    const u16* __restrict__ p,
                                                    float* __restrict__ out,
                                                    int n4, int planeEls) {
    for (int i = blockIdx.x * 256 + threadIdx.x; i < n4; i += gridDim.x * 256) {
        F4 a = *(const F4*)(resid + (size_t)i * 4);
        U4 q0 = *(const U4*)(p + (size_t)i * 4);
        U4 q1 = *(const U4*)(p + (size_t)planeEls + (size_t)i * 4);
        U4 q2 = *(const U4*)(p + (size_t)2 * planeEls + (size_t)i * 4);
        U4 q3 = *(const U4*)(p + (size_t)3 * planeEls + (size_t)i * 4);
        F4 o;
        #pragma unroll
        for (int j = 0; j < 4; ++j)
            o.v[j] = a.v[j] + bf2f(q0.v[j]) + bf2f(q1.v[j]) + bf2f(q2.v[j]) + bf2f(q3.v[j]);
        *(F4*)(out + (size_t)i * 4) = o;
    }
}

// ---------- flash attention v3 (causal), transpose-world + LDS-staged K/V ----------
__global__ __launch_bounds__(256) void attn_fwd_k(const u16* __restrict__ qk,
                                                  const u16* __restrict__ vt,
                                                  u16* __restrict__ Ob) {
    __shared__ alignas(16) u16 Klds[2][64 * 64];
    __shared__ alignas(16) u16 Vlds[2][64 * 64];

    const int tid  = threadIdx.x;
    const int wave = tid >> 6, lane = tid & 63;
    const int r16  = lane & 15, g16 = lane >> 4;

    const int blk = blockIdx.x;
    const int xcd = blk & 7;
    const int pc  = blk >> 3;
    const int hh  = pc >> 5;
    const int qb  = (31 - (pc & 31) + 8 * hh) & 31;
    const int bh  = xcd * 4 + hh;
    const int h   = bh & 15, b = bh >> 4;

    const int q0w = qb * 64 + wave * 16;
    const size_t seqb = (size_t)b * 2048;

    const u16* qp = qk + (seqb + q0w + r16) * 2048 + h * 64 + g16 * 8;
    const bf16x8 qf0 = *(const bf16x8*)qp;
    const bf16x8 qf1 = *(const bf16x8*)(qp + 32);

    const u16* kbase = qk + seqb * 2048 + 1024 + (size_t)h * 64;
    const u16* vbase = vt + (size_t)(h * 64) * 4096 + seqb;

    const int srow  = tid >> 3;                           // 0..31
    const int scol8 = ((tid & 7) ^ (srow & 7)) * 8;
    const u16* ksrc = kbase + (size_t)srow * 2048 + scol8;
    const u16* vsrc = vbase + (size_t)srow * 4096 + scol8;

    auto stage = [&](int bufi, int kv0) {
        const u16* kp = ksrc + (size_t)kv0 * 2048;
        const u16* vp = vsrc + kv0;
        u16* kd = &Klds[bufi][wave * 512];
        u16* vd = &Vlds[bufi][wave * 512];
        gload_lds16(kp, kd);
        gload_lds16(kp + (size_t)32 * 2048, kd + 2048);
        gload_lds16(vp, vd);
        gload_lds16(vp + (size_t)32 * 4096, vd + 2048);
    };

    f32x4 o[4] = {};
    float mreg = -3.0e38f, lreg = 0.0f;
    constexpr float SC = 0.125f * 1.44269504088896341f;   // Dh^-0.5 * log2(e)

    const int nt = qb + 1;
    stage(0, 0);
    asm volatile("s_waitcnt vmcnt(0)" ::: "memory");
    __builtin_amdgcn_s_barrier();

    for (int it = 0; it < nt; ++it) {
        const int kv0 = it * 64;
        const int cur = it & 1;
        if (it + 1 < nt) stage(cur ^ 1, kv0 + 64);

        const u16* K = Klds[cur];
        const u16* V = Vlds[cur];

        f32x4 s[4];
        #pragma unroll
        for (int t = 0; t < 4; ++t) {
            const int row = 16 * t + r16;
            const int sw  = row & 7;
            const bf16x8 k0 = *(const bf16x8*)&K[row * 64 + ((g16 ^ sw) * 8)];
            const bf16x8 k1 = *(const bf16x8*)&K[row * 64 + (((g16 + 4) ^ sw) * 8)];
            f32x4 acc = {0.f, 0.f, 0.f, 0.f};
            acc = mfma16(k0, qf0, acc);
            acc = mfma16(k1, qf1, acc);
            s[t] = acc;
        }

        float a[16];
        #pragma unroll
        for (int t = 0; t < 4; ++t)
            #pragma unroll
            for (int r = 0; r < 4; ++r) a[4 * t + r] = s[t][r] * SC;

        if (kv0 + 63 > q0w) {
            const int qg = q0w + r16;
            #pragma unroll
            for (int t = 0; t < 4; ++t)
                #pragma unroll
                for (int r = 0; r < 4; ++r)
                    if (kv0 + 16 * t + 4 * g16 + r > qg) a[4 * t + r] = -1.0e30f;
        }

        float mx = a[0];
        #pragma unroll
        for (int j = 1; j < 16; ++j) mx = fmaxf(mx, a[j]);
        mx = fmaxf(mx, __shfl_xor(mx, 16));
        mx = fmaxf(mx, __shfl_xor(mx, 32));
        const float mn = fmaxf(mreg, mx);
        const float al = exp2f(mreg - mn);
        float p[16], rs = 0.0f;
        #pragma unroll
        for (int j = 0; j < 16; ++j) { p[j] = exp2f(a[j] - mn); rs += p[j]; }
        rs += __shfl_xor(rs, 16);
        rs += __shfl_xor(rs, 32);
        lreg = lreg * al + rs;
        mreg = mn;

        bf16x8 pf0, pf1;
        #pragma unroll
        for (int j = 0; j < 8; ++j) { pf0[j] = (__bf16)p[j]; pf1[j] = (__bf16)p[8 + j]; }

        #pragma unroll
        for (int t = 0; t < 4; ++t) {
            const int row  = 16 * t + r16;
            const int sw   = row & 7;
            const int base = row * 64 + (g16 & 1) * 4;
            const int c0   = g16 >> 1;
            U4 a0 = *(const U4*)&V[base + (((c0 + 0) ^ sw) * 8)];
            U4 a1 = *(const U4*)&V[base + (((c0 + 2) ^ sw) * 8)];
            U4 b0 = *(const U4*)&V[base + (((c0 + 4) ^ sw) * 8)];
            U4 b1 = *(const U4*)&V[base + (((c0 + 6) ^ sw) * 8)];
            #pragma unroll
            for (int r = 0; r < 4; ++r) o[t][r] *= al;
            bf16x8 v0, v1;
            #pragma unroll
            for (int j = 0; j < 4; ++j) {
                v0[j]     = ((const __bf16*)&a0)[j];
                v0[4 + j] = ((const __bf16*)&a1)[j];
                v1[j]     = ((const __bf16*)&b0)[j];
                v1[4 + j] = ((const __bf16*)&b1)[j];
            }
            o[t] = mfma16(v0, pf0, o[t]);
            o[t] = mfma16(v1, pf1, o[t]);
        }

        if (it + 1 < nt) {
            asm volatile("s_waitcnt vmcnt(0)" ::: "memory");
            __builtin_amdgcn_s_barrier();
        }
    }

    const float inv = 1.0f / lreg;
    u16* op = Ob + (seqb + q0w + r16) * 1024 + h * 64 + 4 * g16;
    #pragma unroll
    for (int t = 0; t < 4; ++t) {
        U4 st;
        #pragma unroll
        for (int r = 0; r < 4; ++r) st.v[r] = f2bf(o[t][r] * inv);
        *(U4*)(op + 16 * t) = st;
    }
}

// ---------- launch ----------
extern "C" void kernel_launch(void* const* d_in, const int* in_sizes, int n_in,
                              void* d_out, int out_size, void* d_ws, size_t ws_size,
                              hipStream_t stream) {
    (void)in_sizes; (void)n_in; (void)out_size; (void)ws_size;
    constexpr int C = 1024, FF = 4096, M = 2 * 2048;   // B*T = 4096
    constexpr size_t MB = 1024 * 1024;

    const float* x      = (const float*)d_in[0];
    const float* ln1_w  = (const float*)d_in[1];
    const float* ln1_b  = (const float*)d_in[2];
    const float* qkv_w  = (const float*)d_in[3];
    const float* atto_w = (const float*)d_in[4];
    const float* ln2_w  = (const float*)d_in[5];
    const float* ln2_b  = (const float*)d_in[6];
    const float* mlpi_w = (const float*)d_in[7];
    const float* mlpg_w = (const float*)d_in[8];
    const float* mlpo_w = (const float*)d_in[9];
    float* out = (float*)d_out;

    char* ws = (char*)d_ws;
    size_t off = 0;
    auto alloc = [&](size_t bytes) {
        char* p = ws + off;
        off += (bytes + 255) & ~(size_t)255;
        return p;
    };
    u16*   wq   = (u16*)  alloc((size_t)3 * C * C * 2);   // qkv_w bf16 (Q,K rows then V)
    u16*   wo   = (u16*)  alloc((size_t)C * C * 2);
    u16*   wig  = (u16*)  alloc((size_t)2 * FF * C * 2);  // interleaved wi/wg [8192][1024]
    u16*   wm   = (u16*)  alloc((size_t)C * FF * 2);
    float* x1   = (float*)alloc((size_t)M * C * 4);
    u16*   h2   = (u16*)  alloc((size_t)M * C * 2);
    u16*   ab   = (u16*)  alloc((size_t)M * FF * 2);
    // region R (64 MB): attn-phase buffers; later reused for mlpo partials
    char*  R    = alloc(64 * MB);
    u16*   h1   = (u16*)R;                 //  8 MB
    u16*   qk_b = (u16*)(R + 8 * MB);      // 16 MB  [4096][2048] Q|K
    u16*   vt_b = (u16*)(R + 24 * MB);     //  8 MB  [1024][4096] V^T
    u16*   Ob   = (u16*)(R + 32 * MB);     //  8 MB
    u16*   aoP  = (u16*)(R + 40 * MB);     // 16 MB  attn_out bf16 partials (2 planes)
    u16*   pscr = (u16*)R;                 // 32 MB  mlpo bf16 partials (4 planes) — after attn

    // all weight casts (one kernel)
    cast_all_k<<<8192, 256, 0, stream>>>(qkv_w, atto_w, mlpo_w, mlpi_w, mlpg_w,
                                         wq, wo, wm, wig);

    // attention branch
    ln_fwd_k<<<M, 256, 0, stream>>>(x, ln1_w, ln1_b, h1);
    gemm_qkvt_k<<<768, 256, 0, stream>>>(h1, wq, qk_b, vt_b);
    attn_fwd_k<<<1024, 256, 0, stream>>>(qk_b, vt_b, Ob);
    // attn_out: split-K=2 bf16 partials (512 blocks = 2/CU)
    gemm_btsplit_k<<<dim3(C / 128, M / 128, 2), 256, 0, stream>>>(
        Ob, wo, aoP, C, C, C / 2, M * C);
    // fused residual+LN2: x1 = x + p0 + p1 ; h2 = LN(x1)
    ln_resid_k<<<M, 256, 0, stream>>>(x, aoP, ln2_w, ln2_b, x1, h2, M * C);

    // MLP branch
    gemm256_k<2><<<dim3((2 * FF / 256) * (M / 256), 1, 1), 512, 0, stream>>>(
        h2, wig, ab, C, C, C, 2 * FF / 256, 8, FF, 0);
    gemm256_k<1><<<dim3((C / 256) * (M / 256), 1, 4), 512, 0, stream>>>(
        ab, wm, pscr, FF, FF, FF / 4, C / 256, 4, C, M * C);
    addreduce4_k<<<2048, 256, 0, stream>>>(x1, pscr, out, M * C / 4, M * C);
}

// Round 11
// 244.095 us; speedup vs baseline: 2.7150x; 1.0512x over previous
//
#include <hip/hip_runtime.h>
#include <cstdint>

// ---------- types & helpers ----------
typedef unsigned short u16;
typedef __bf16 bf16x8 __attribute__((ext_vector_type(8)));
typedef float  f32x4  __attribute__((ext_vector_type(4)));

struct alignas(16) F4 { float v[4]; };
struct alignas(8)  U4 { u16 v[4]; };
struct alignas(16) U8 { u16 v[8]; };

__device__ __forceinline__ u16 f2bf(float f) {
    union { float f; unsigned int u; } x; x.f = f;
    unsigned int r = x.u + 0x7fffu + ((x.u >> 16) & 1u);   // RNE
    return (u16)(r >> 16);
}
__device__ __forceinline__ float bf2f(u16 u) {
    union { unsigned int u; float f; } x; x.u = ((unsigned int)u) << 16;
    return x.f;
}
__device__ __forceinline__ f32x4 mfma16(bf16x8 a, bf16x8 b, f32x4 c) {
    return __builtin_amdgcn_mfma_f32_16x16x32_bf16(a, b, c, 0, 0, 0);
}
__device__ __forceinline__ bf16x8 ldf(const u16* p) { return *(const bf16x8*)p; }
// async global->LDS, 16B per lane, dest = wave-uniform base + lane*16
__device__ __forceinline__ void gload_lds16(const void* g, void* l) {
    auto* gp = reinterpret_cast<const __attribute__((address_space(1))) unsigned int*>(
        reinterpret_cast<uintptr_t>(g));
    auto* lp = reinterpret_cast<__attribute__((address_space(3))) unsigned int*>(
        reinterpret_cast<uintptr_t>(l));
    __builtin_amdgcn_global_load_lds(gp, lp, 16, 0, 0);
}

// ---------- ALL weight casts in one kernel ----------
__global__ __launch_bounds__(256) void cast_all_k(const float* __restrict__ qkvw,
                                                  const float* __restrict__ attow,
                                                  const float* __restrict__ mlpow,
                                                  const float* __restrict__ wi,
                                                  const float* __restrict__ wg,
                                                  u16* __restrict__ wq,
                                                  u16* __restrict__ wo,
                                                  u16* __restrict__ wm,
                                                  u16* __restrict__ wig) {
    constexpr int N1 = 3 * 1024 * 1024 / 8;            // wq units-of-8
    constexpr int N2 = N1 + 1024 * 1024 / 8;           // +wo
    constexpr int N3 = N2 + 1024 * 4096 / 8;           // +wm
    const int i = blockIdx.x * 256 + threadIdx.x;
    const float* src; u16* dst;
    if (i < N1)      { src = qkvw  + (size_t)i * 8;        dst = wq + (size_t)i * 8; }
    else if (i < N2) { const int j = i - N1; src = attow + (size_t)j * 8; dst = wo + (size_t)j * 8; }
    else if (i < N3) { const int j = i - N2; src = mlpow + (size_t)j * 8; dst = wm + (size_t)j * 8; }
    else {
        const int j = i - N3;
        const int w = j >> 7, c8 = (j & 127) * 8;
        const int f = ((w >> 6) << 5) | (w & 31);
        src = ((w & 32) ? wg : wi) + (size_t)f * 1024 + c8;
        dst = wig + (size_t)w * 1024 + c8;
    }
    F4 a = *(const F4*)src;
    F4 b = *(const F4*)(src + 4);
    U8 o;
    #pragma unroll
    for (int j = 0; j < 4; ++j) { o.v[j] = f2bf(a.v[j]); o.v[4 + j] = f2bf(b.v[j]); }
    *(U8*)dst = o;
}

// ---------- LayerNorm (C=1024), f32 in -> bf16 out ----------
__global__ __launch_bounds__(256) void ln_fwd_k(const float* __restrict__ x,
                                                const float* __restrict__ w,
                                                const float* __restrict__ b,
                                                u16* __restrict__ h) {
    const int row = blockIdx.x, tid = threadIdx.x;
    const float* xr = x + (size_t)row * 1024;
    F4 v = *(const F4*)(xr + tid * 4);
    float s  = v.v[0] + v.v[1] + v.v[2] + v.v[3];
    float ss = v.v[0]*v.v[0] + v.v[1]*v.v[1] + v.v[2]*v.v[2] + v.v[3]*v.v[3];
    #pragma unroll
    for (int o = 32; o > 0; o >>= 1) { s += __shfl_down(s, o); ss += __shfl_down(ss, o); }
    __shared__ float red[8];
    const int wave = tid >> 6, lane = tid & 63;
    if (lane == 0) { red[wave] = s; red[4 + wave] = ss; }
    __syncthreads();
    s  = red[0] + red[1] + red[2] + red[3];
    ss = red[4] + red[5] + red[6] + red[7];
    const float mu   = s * (1.0f / 1024.0f);
    const float var  = ss * (1.0f / 1024.0f) - mu * mu;
    const float rstd = rsqrtf(var + 1e-5f);
    U4 o;
    #pragma unroll
    for (int j = 0; j < 4; ++j)
        o.v[j] = f2bf((v.v[j] - mu) * rstd * w[tid * 4 + j] + b[tid * 4 + j]);
    *(U4*)(h + (size_t)row * 1024 + tid * 4) = o;
}

// ---------- fused residual + LN2: x1 = x + p0 + p1 (bf16 planes); h2 = LN(x1) ----------
__global__ __launch_bounds__(256) void ln_resid_k(const float* __restrict__ x,
                                                  const u16* __restrict__ p,
                                                  const float* __restrict__ w,
                                                  const float* __restrict__ b,
                                                  float* __restrict__ x1,
                                                  u16* __restrict__ h,
                                                  int planeEls) {
    const int row = blockIdx.x, tid = threadIdx.x;
    const size_t base = (size_t)row * 1024 + tid * 4;
    F4 xv = *(const F4*)(x + base);
    U4 q0 = *(const U4*)(p + base);
    U4 q1 = *(const U4*)(p + (size_t)planeEls + base);
    F4 sv;
    #pragma unroll
    for (int j = 0; j < 4; ++j) sv.v[j] = xv.v[j] + bf2f(q0.v[j]) + bf2f(q1.v[j]);
    *(F4*)(x1 + base) = sv;
    float s  = sv.v[0] + sv.v[1] + sv.v[2] + sv.v[3];
    float ss = sv.v[0]*sv.v[0] + sv.v[1]*sv.v[1] + sv.v[2]*sv.v[2] + sv.v[3]*sv.v[3];
    #pragma unroll
    for (int o = 32; o > 0; o >>= 1) { s += __shfl_down(s, o); ss += __shfl_down(ss, o); }
    __shared__ float red[8];
    const int wave = tid >> 6, lane = tid & 63;
    if (lane == 0) { red[wave] = s; red[4 + wave] = ss; }
    __syncthreads();
    s  = red[0] + red[1] + red[2] + red[3];
    ss = red[4] + red[5] + red[6] + red[7];
    const float mu   = s * (1.0f / 1024.0f);
    const float var  = ss * (1.0f / 1024.0f) - mu * mu;
    const float rstd = rsqrtf(var + 1e-5f);
    U4 o;
    #pragma unroll
    for (int j = 0; j < 4; ++j)
        o.v[j] = f2bf((sv.v[j] - mu) * rstd * w[tid * 4 + j] + b[tid * 4 + j]);
    *(U4*)(h + base) = o;
}

// ---------- combined qk + vt GEMM (one dispatch, 768 blocks) ----------
// role 0 (bid<512):  qk_b[4096][2048] = h1 @ wq^T ; Q cols (<1024) pre-scaled
//                    by 0.125*log2e so attention softmax runs in log2 domain.
// role 1 (bid>=512): vt_b[1024][4096] = wv @ h1^T with PV-permuted columns:
//                    within each 32-col block, kv=16s+4g+r stored at 8g+4s+r
//                    (makes attention's PV A-frag one contiguous b128 read).
__global__ __launch_bounds__(256) void gemm_qkvt_k(const u16* __restrict__ h1,
                                                   const u16* __restrict__ wq,
                                                   u16* __restrict__ qk_b,
                                                   u16* __restrict__ vt_b) {
    __shared__ alignas(16) u16 Alds[128 * 32];
    __shared__ alignas(16) u16 Blds[128 * 32];
    const int tid  = threadIdx.x;
    const int lane = tid & 63, wave = tid >> 6;
    const int wr = wave >> 1, wc = wave & 1;
    const int r16 = lane & 15, g16 = lane >> 4;

    const u16* A; const u16* Bm; u16* Cout; int bn, bm, N, role;
    const int bid = blockIdx.x;
    if (bid < 512) { A = h1; Bm = wq; Cout = qk_b; N = 2048; bn = bid & 15; bm = bid >> 4; role = 0; }
    else {
        const int id = bid - 512;
        A = wq + (size_t)2 * 1024 * 1024;   // wv rows
        Bm = h1; Cout = vt_b; N = 4096; bn = id & 31; bm = id >> 5; role = 1;
    }
    constexpr int K = 1024;

    const int srow = lane >> 2;
    const int scol = (lane & 3) * 8;

    f32x4 acc[4][4] = {};

    for (int k0 = 0; k0 < K; k0 += 32) {
        #pragma unroll
        for (int c = 0; c < 2; ++c) {
            const int ch = wave * 2 + c;
            const u16* ga = A  + ((size_t)bm * 128 + ch * 16 + srow) * K + k0 + scol;
            gload_lds16(ga, &Alds[ch * 512]);
            const u16* gb = Bm + ((size_t)bn * 128 + ch * 16 + srow) * K + k0 + scol;
            gload_lds16(gb, &Blds[ch * 512]);
        }
        __syncthreads();
        bf16x8 af[4], bfr[4];
        #pragma unroll
        for (int m = 0; m < 4; ++m)
            af[m] = ldf(&Alds[(wr * 64 + m * 16 + r16) * 32 + g16 * 8]);
        #pragma unroll
        for (int n = 0; n < 4; ++n)
            bfr[n] = ldf(&Blds[(wc * 64 + n * 16 + r16) * 32 + g16 * 8]);
        #pragma unroll
        for (int m = 0; m < 4; ++m)
            #pragma unroll
            for (int n = 0; n < 4; ++n)
                acc[m][n] = mfma16(af[m], bfr[n], acc[m][n]);
        __syncthreads();
    }

    constexpr float SCQ = 0.125f * 1.44269504088896341f;
    #pragma unroll
    for (int m = 0; m < 4; ++m)
        #pragma unroll
        for (int n = 0; n < 4; ++n)
            #pragma unroll
            for (int r = 0; r < 4; ++r) {
                const int row = bm * 128 + wr * 64 + m * 16 + g16 * 4 + r;
                int col = bn * 128 + wc * 64 + n * 16 + r16;
                float v = acc[m][n][r];
                if (role == 0) {
                    if (col < 1024) v *= SCQ;                 // Q pre-scale
                } else {
                    const int c5 = col & 31;                   // PV permutation
                    const int pos = 8 * ((c5 & 15) >> 2) + 4 * (c5 >> 4) + (c5 & 3);
                    col = (col & ~31) | pos;
                }
                Cout[(size_t)row * N + col] = f2bf(v);
            }
}

// ---------- 128x128 GEMM, split-K bf16 partial planes (attn_out) ----------
__global__ __launch_bounds__(256) void gemm_btsplit_k(const u16* __restrict__ A,
                                                      const u16* __restrict__ Bm,
                                                      u16* __restrict__ P,
                                                      int N, int K, int kchunk,
                                                      int planeEls) {
    __shared__ alignas(16) u16 Alds[128 * 32];
    __shared__ alignas(16) u16 Blds[128 * 32];
    const int tid  = threadIdx.x;
    const int lane = tid & 63, wave = tid >> 6;
    const int wr = wave >> 1, wc = wave & 1;
    const int r16 = lane & 15, g16 = lane >> 4;
    const int bn = blockIdx.x, bm = blockIdx.y;
    const int kBeg = blockIdx.z * kchunk;

    const int srow = lane >> 2;
    const int scol = (lane & 3) * 8;

    f32x4 acc[4][4] = {};

    for (int k0 = kBeg; k0 < kBeg + kchunk; k0 += 32) {
        #pragma unroll
        for (int c = 0; c < 2; ++c) {
            const int ch = wave * 2 + c;
            const u16* ga = A  + ((size_t)bm * 128 + ch * 16 + srow) * K + k0 + scol;
            gload_lds16(ga, &Alds[ch * 512]);
            const u16* gb = Bm + ((size_t)bn * 128 + ch * 16 + srow) * K + k0 + scol;
            gload_lds16(gb, &Blds[ch * 512]);
        }
        __syncthreads();
        bf16x8 af[4], bfr[4];
        #pragma unroll
        for (int m = 0; m < 4; ++m)
            af[m] = ldf(&Alds[(wr * 64 + m * 16 + r16) * 32 + g16 * 8]);
        #pragma unroll
        for (int n = 0; n < 4; ++n)
            bfr[n] = ldf(&Blds[(wc * 64 + n * 16 + r16) * 32 + g16 * 8]);
        #pragma unroll
        for (int m = 0; m < 4; ++m)
            #pragma unroll
            for (int n = 0; n < 4; ++n)
                acc[m][n] = mfma16(af[m], bfr[n], acc[m][n]);
        __syncthreads();
    }

    u16* Pp = P + (size_t)blockIdx.z * planeEls;
    #pragma unroll
    for (int m = 0; m < 4; ++m)
        #pragma unroll
        for (int n = 0; n < 4; ++n)
            #pragma unroll
            for (int r = 0; r < 4; ++r) {
                const int row = bm * 128 + wr * 64 + m * 16 + g16 * 4 + r;
                const int col = bn * 128 + wc * 64 + n * 16 + r16;
                Pp[(size_t)row * N + col] = f2bf(acc[m][n][r]);
            }
}

// ---------- 256x256 pipelined GEMM v3 (frag-prefetch; best measured) ----------
template <int EPI>
__global__ __launch_bounds__(512, 2)
void gemm256_k(const u16* __restrict__ A, const u16* __restrict__ Bm,
               void* __restrict__ Cout, int lda, int ldb, int kLen,
               int nx, int bnCh, int outLd, int planeEls) {
    __shared__ alignas(16) u16 lds[2][2][2][128 * 64];

    const int tid  = threadIdx.x;
    const int wave = tid >> 6, lane = tid & 63;
    const int wm = wave >> 2, wn = wave & 3;
    const int r16 = lane & 15, g16 = lane >> 4;

    const int cpx = gridDim.x >> 3;
    const int xcd = blockIdx.x & 7, loc = blockIdx.x >> 3;
    const int mCh = cpx / bnCh;
    const int cpr = nx / bnCh;
    const int bm = (xcd / cpr) * mCh + loc / bnCh;
    const int bn = (xcd % cpr) * bnCh + loc % bnCh;
    const int kBeg = blockIdx.z * kLen;
    const int NT = kLen >> 6;

    const int csw = ((lane & 7) ^ (lane >> 3)) * 8;
    const u16* aU = A  + (size_t)(bm * 256) * lda + kBeg;
    const u16* bU = Bm + (size_t)(bn * 256) * ldb + kBeg;
    int aOff[2][2], bOff[2][2];
    #pragma unroll
    for (int h = 0; h < 2; ++h)
        #pragma unroll
        for (int i = 0; i < 2; ++i) {
            const int wr = wave * 16 + (lane >> 3) + i * 8;
            const int ar = (wr >> 6) * 128 + h * 64 + (wr & 63);
            const int br = (wr >> 5) * 64 + h * 32 + (wr & 31);
            aOff[h][i] = ar * lda + csw;
            bOff[h][i] = br * ldb + csw;
        }

    auto stA = [&](int kt, int h) {
        u16* d = &lds[kt & 1][0][h][wave * 1024];
        gload_lds16(aU + aOff[h][0] + kt * 64, d);
        gload_lds16(aU + aOff[h][1] + kt * 64, d + 512);
    };
    auto stB = [&](int kt, int h) {
        u16* d = &lds[kt & 1][1][h][wave * 1024];
        gload_lds16(bU + bOff[h][0] + kt * 64, d);
        gload_lds16(bU + bOff[h][1] + kt * 64, d + 512);
    };

    int offA[4][2], offB[2][2];
    #pragma unroll
    for (int m = 0; m < 4; ++m)
        #pragma unroll
        for (int ks = 0; ks < 2; ++ks)
            offA[m][ks] = (wm * 64 + m * 16 + r16) * 64 + (((ks * 4 + g16) ^ (r16 & 7)) * 8);
    #pragma unroll
    for (int n = 0; n < 2; ++n)
        #pragma unroll
        for (int ks = 0; ks < 2; ++ks)
            offB[n][ks] = (wn * 32 + n * 16 + r16) * 64 + (((ks * 4 + g16) ^ (r16 & 7)) * 8);

    f32x4 acc[8][4] = {};
    bf16x8 af0[4][2], af1[4][2], b0v[2][2], b1v[2][2];

    auto rdAF0 = [&](int buf) {
        const u16* P = &lds[buf][0][0][0];
        #pragma unroll
        for (int m = 0; m < 4; ++m) { af0[m][0] = ldf(P + offA[m][0]); af0[m][1] = ldf(P + offA[m][1]); }
    };
    auto rdAF1 = [&](int buf) {
        const u16* P = &lds[buf][0][1][0];
        #pragma unroll
        for (int m = 0; m < 4; ++m) { af1[m][0] = ldf(P + offA[m][0]); af1[m][1] = ldf(P + offA[m][1]); }
    };
    auto rdB0 = [&](int buf) {
        const u16* P = &lds[buf][1][0][0];
        #pragma unroll
        for (int n = 0; n < 2; ++n) { b0v[n][0] = ldf(P + offB[n][0]); b0v[n][1] = ldf(P + offB[n][1]); }
    };
    auto rdB1 = [&](int buf) {
        const u16* P = &lds[buf][1][1][0];
        #pragma unroll
        for (int n = 0; n < 2; ++n) { b1v[n][0] = ldf(P + offB[n][0]); b1v[n][1] = ldf(P + offB[n][1]); }
    };

    stA(0, 0); stB(0, 0); stB(0, 1); stA(0, 1);
    stA(1, 0); stB(1, 0); stB(1, 1); stA(1, 1);
    asm volatile("s_waitcnt vmcnt(8)" ::: "memory");
    __builtin_amdgcn_s_barrier();
    rdAF0(0); rdB0(0); rdB1(0); rdAF1(0);

    for (int kt = 0; kt < NT; ++kt) {
        const bool pf = (kt + 2 < NT);
        const int nb = (kt + 1) & 1;

        __builtin_amdgcn_s_setprio(1);
        #pragma unroll
        for (int m = 0; m < 4; ++m)
            #pragma unroll
            for (int n = 0; n < 2; ++n) {
                acc[m][n] = mfma16(af0[m][0], b0v[n][0], acc[m][n]);
                acc[m][n] = mfma16(af0[m][1], b0v[n][1], acc[m][n]);
            }
        __builtin_amdgcn_s_setprio(0);
        __builtin_amdgcn_s_barrier();

        if (pf) { stA(kt + 2, 0); stB(kt + 2, 0); }
        __builtin_amdgcn_s_setprio(1);
        #pragma unroll
        for (int m = 0; m < 4; ++m)
            #pragma unroll
            for (int n = 0; n < 2; ++n) {
                acc[m][n + 2] = mfma16(af0[m][0], b1v[n][0], acc[m][n + 2]);
                acc[m][n + 2] = mfma16(af0[m][1], b1v[n][1], acc[m][n + 2]);
            }
        __builtin_amdgcn_s_setprio(0);
        __builtin_amdgcn_s_barrier();

        if (pf) stB(kt + 2, 1);
        __builtin_amdgcn_s_setprio(1);
        #pragma unroll
        for (int m = 0; m < 4; ++m)
            #pragma unroll
            for (int n = 0; n < 2; ++n) {
                acc[m + 4][n] = mfma16(af1[m][0], b0v[n][0], acc[m + 4][n]);
                acc[m + 4][n] = mfma16(af1[m][1], b0v[n][1], acc[m + 4][n]);
            }
        __builtin_amdgcn_s_setprio(0);
        __builtin_amdgcn_s_barrier();

        if (pf) stA(kt + 2, 1);
        if (pf)               { asm volatile("s_waitcnt vmcnt(8)" ::: "memory"); }
        else if (kt + 1 < NT) { asm volatile("s_waitcnt vmcnt(0)" ::: "memory"); }
        if (kt + 1 < NT) {
            __builtin_amdgcn_s_barrier();
            rdAF0(nb); rdB0(nb);
        }
        __builtin_amdgcn_s_setprio(1);
        #pragma unroll
        for (int m = 0; m < 4; ++m)
            #pragma unroll
            for (int n = 0; n < 2; ++n) {
                acc[m + 4][n + 2] = mfma16(af1[m][0], b1v[n][0], acc[m + 4][n + 2]);
                acc[m + 4][n + 2] = mfma16(af1[m][1], b1v[n][1], acc[m + 4][n + 2]);
            }
        __builtin_amdgcn_s_setprio(0);
        if (kt + 1 < NT) { rdB1(nb); rdAF1(nb); }
    }

    if constexpr (EPI == 1) {
        u16* P = (u16*)Cout + (size_t)blockIdx.z * planeEls;
        #pragma unroll
        for (int m = 0; m < 8; ++m)
            #pragma unroll
            for (int n = 0; n < 4; ++n)
                #pragma unroll
                for (int r = 0; r < 4; ++r) {
                    const int row = bm * 256 + wm * 128 + m * 16 + g16 * 4 + r;
                    const int col = bn * 256 + wn * 64 + n * 16 + r16;
                    P[(size_t)row * outLd + col] = f2bf(acc[m][n][r]);
                }
    } else {
        (void)planeEls;
        u16* O = (u16*)Cout;
        #pragma unroll
        for (int m = 0; m < 8; ++m)
            #pragma unroll
            for (int n = 0; n < 2; ++n)
                #pragma unroll
                for (int r = 0; r < 4; ++r) {
                    const int row = bm * 256 + wm * 128 + m * 16 + g16 * 4 + r;
                    const int col = (bn * 4 + wn) * 32 + n * 16 + r16;
                    const float vi = acc[m][n][r];
                    const float vg = acc[m][n + 2][r];
                    const float sl = vi / (1.0f + __expf(-vi));
                    O[(size_t)row * outLd + col] = f2bf(sl * vg);
                }
    }
}

// ---------- split-K reduce: out = resid + sum of 4 bf16 planes ----------
__global__ __launch_bounds__(256) void addreduce4_k(const float* __restrict__ resid,
                                                    const u16* __restrict__ p,
                                                    float* __restrict__ out,
                                                    int n4, int planeEls) {
    for (int i = blockIdx.x * 256 + threadIdx.x; i < n4; i += gridDim.x * 256) {
        F4 a = *(const F4*)(resid + (size_t)i * 4);
        U4 q0 = *(const U4*)(p + (size_t)i * 4);
        U4 q1 = *(const U4*)(p + (size_t)planeEls + (size_t)i * 4);
        U4 q2 = *(const U4*)(p + (size_t)2 * planeEls + (size_t)i * 4);
        U4 q3 = *(const U4*)(p + (size_t)3 * planeEls + (size_t)i * 4);
        F4 o;
        #pragma unroll
        for (int j = 0; j < 4; ++j)
            o.v[j] = a.v[j] + bf2f(q0.v[j]) + bf2f(q1.v[j]) + bf2f(q2.v[j]) + bf2f(q3.v[j]);
        *(F4*)(out + (size_t)i * 4) = o;
    }
}

// ---------- flash attention v4: paired q-tiles (uniform work), permuted-V b128 PV,
// log2-domain softmax (scale folded into Q), defer-max rescale skip ----------
// grid = 512: block (bh, pi) does q-tile 31-pi then pi (33 kv-tile iters total).
__global__ __launch_bounds__(256) void attn_fwd_k(const u16* __restrict__ qk,
                                                  const u16* __restrict__ vt,
                                                  u16* __restrict__ Ob) {
    __shared__ alignas(16) u16 Klds[2][64 * 64];
    __shared__ alignas(16) u16 Vlds[2][64 * 64];

    const int tid  = threadIdx.x;
    const int wave = tid >> 6, lane = tid & 63;
    const int r16  = lane & 15, g16 = lane >> 4;

    const int bh = blockIdx.x >> 4, pi = blockIdx.x & 15;
    const int h  = bh & 15, b = bh >> 4;
    const size_t seqb = (size_t)b * 2048;

    const u16* kbase = qk + seqb * 2048 + 1024 + (size_t)h * 64;
    const u16* vbase = vt + (size_t)(h * 64) * 4096 + seqb;

    const int srow  = tid >> 3;                           // 0..31
    const int scol8 = ((tid & 7) ^ (srow & 7)) * 8;
    const u16* ksrc = kbase + (size_t)srow * 2048 + scol8;
    const u16* vsrc = vbase + (size_t)srow * 4096 + scol8;

    auto stage = [&](int bufi, int kv0) {
        const u16* kp = ksrc + (size_t)kv0 * 2048;
        const u16* vp = vsrc + kv0;
        u16* kd = &Klds[bufi][wave * 512];
        u16* vd = &Vlds[bufi][wave * 512];
        gload_lds16(kp, kd);
        gload_lds16(kp + (size_t)32 * 2048, kd + 2048);
        gload_lds16(vp, vd);
        gload_lds16(vp + (size_t)32 * 4096, vd + 2048);
    };

    #pragma unroll 1
    for (int half = 0; half < 2; ++half) {
        const int qb  = half ? pi : (31 - pi);            // long tile first
        const int q0w = qb * 64 + wave * 16;

        const u16* qp = qk + (seqb + q0w + r16) * 2048 + h * 64 + g16 * 8;
        const bf16x8 qf0 = *(const bf16x8*)qp;            // Q pre-scaled by 0.125*log2e
        const bf16x8 qf1 = *(const bf16x8*)(qp + 32);

        f32x4 o[4] = {};
        float mreg = -3.0e38f, lreg = 0.0f;
        const int nt = qb + 1;

        if (half) __syncthreads();                        // protect LDS vs prev half
        stage(0, 0);
        asm volatile("s_waitcnt vmcnt(0)" ::: "memory");
        __builtin_amdgcn_s_barrier();

        for (int it = 0; it < nt; ++it) {
            const int kv0 = it * 64;
            const int cur = it & 1;
            if (it + 1 < nt) stage(cur ^ 1, kv0 + 64);

            const u16* K = Klds[cur];
            const u16* V = Vlds[cur];

            f32x4 s[4];
            #pragma unroll
            for (int t = 0; t < 4; ++t) {
                const int row = 16 * t + r16;
                const int sw  = row & 7;
                const bf16x8 k0 = ldf(&K[row * 64 + ((g16 ^ sw) * 8)]);
                const bf16x8 k1 = ldf(&K[row * 64 + (((g16 + 4) ^ sw) * 8)]);
                f32x4 acc = {0.f, 0.f, 0.f, 0.f};
                acc = mfma16(k0, qf0, acc);
                acc = mfma16(k1, qf1, acc);
                s[t] = acc;
            }

            float a[16];
            #pragma unroll
            for (int t = 0; t < 4; ++t)
                #pragma unroll
                for (int r = 0; r < 4; ++r) a[4 * t + r] = s[t][r];

            if (kv0 + 63 > q0w) {                         // wave-uniform causal branch
                const int qg = q0w + r16;
                #pragma unroll
                for (int t = 0; t < 4; ++t)
                    #pragma unroll
                    for (int r = 0; r < 4; ++r)
                        if (kv0 + 16 * t + 4 * g16 + r > qg) a[4 * t + r] = -1.0e30f;
            }

            float mx = a[0];
            #pragma unroll
            for (int j = 1; j < 16; ++j) mx = fmaxf(mx, a[j]);
            mx = fmaxf(mx, __shfl_xor(mx, 16));
            mx = fmaxf(mx, __shfl_xor(mx, 32));

            const float mn = fmaxf(mreg, mx);
            float p[16], rs = 0.0f;
            #pragma unroll
            for (int j = 0; j < 16; ++j) { p[j] = exp2f(a[j] - mn); rs += p[j]; }
            rs += __shfl_xor(rs, 16);
            rs += __shfl_xor(rs, 32);

            if (__all(mx <= mreg)) {                      // defer-max: no rescale
                lreg += rs;
            } else {
                const float al = exp2f(mreg - mn);
                lreg = lreg * al + rs;
                mreg = mn;
                #pragma unroll
                for (int t = 0; t < 4; ++t)
                    #pragma unroll
                    for (int r = 0; r < 4; ++r) o[t][r] *= al;
            }

            bf16x8 pf0, pf1;
            #pragma unroll
            for (int j = 0; j < 8; ++j) { pf0[j] = (__bf16)p[j]; pf1[j] = (__bf16)p[8 + j]; }

            // PV: permuted-V layout -> one b128 per (t, half32)
            #pragma unroll
            for (int t = 0; t < 4; ++t) {
                const int row = 16 * t + r16;
                const int sw  = row & 7;
                const bf16x8 v0 = ldf(&V[row * 64 + ((g16 ^ sw) * 8)]);
                const bf16x8 v1 = ldf(&V[row * 64 + (((4 + g16) ^ sw) * 8)]);
                o[t] = mfma16(v0, pf0, o[t]);
                o[t] = mfma16(v1, pf1, o[t]);
            }

            if (it + 1 < nt) {
                asm volatile("s_waitcnt vmcnt(0)" ::: "memory");
                __builtin_amdgcn_s_barrier();
            }
        }

        const float inv = 1.0f / lreg;
        u16* op = Ob + (seqb + q0w + r16) * 1024 + h * 64 + 4 * g16;
        #pragma unroll
        for (int t = 0; t < 4; ++t) {
            U4 st;
            #pragma unroll
            for (int r = 0; r < 4; ++r) st.v[r] = f2bf(o[t][r] * inv);
            *(U4*)(op + 16 * t) = st;
        }
    }
}

// ---------- launch ----------
extern "C" void kernel_launch(void* const* d_in, const int* in_sizes, int n_in,
                              void* d_out, int out_size, void* d_ws, size_t ws_size,
                              hipStream_t stream) {
    (void)in_sizes; (void)n_in; (void)out_size; (void)ws_size;
    constexpr int C = 1024, FF = 4096, M = 2 * 2048;   // B*T = 4096
    constexpr size_t MB = 1024 * 1024;

    const float* x      = (const float*)d_in[0];
    const float* ln1_w  = (const float*)d_in[1];
    const float* ln1_b  = (const float*)d_in[2];
    const float* qkv_w  = (const float*)d_in[3];
    const float* atto_w = (const float*)d_in[4];
    const float* ln2_w  = (const float*)d_in[5];
    const float* ln2_b  = (const float*)d_in[6];
    const float* mlpi_w = (const float*)d_in[7];
    const float* mlpg_w = (const float*)d_in[8];
    const float* mlpo_w = (const float*)d_in[9];
    float* out = (float*)d_out;

    char* ws = (char*)d_ws;
    size_t off = 0;
    auto alloc = [&](size_t bytes) {
        char* p = ws + off;
        off += (bytes + 255) & ~(size_t)255;
        return p;
    };
    u16*   wq   = (u16*)  alloc((size_t)3 * C * C * 2);   // qkv_w bf16 (Q,K rows then V)
    u16*   wo   = (u16*)  alloc((size_t)C * C * 2);
    u16*   wig  = (u16*)  alloc((size_t)2 * FF * C * 2);  // interleaved wi/wg [8192][1024]
    u16*   wm   = (u16*)  alloc((size_t)C * FF * 2);
    float* x1   = (float*)alloc((size_t)M * C * 4);
    u16*   h2   = (u16*)  alloc((size_t)M * C * 2);
    u16*   ab   = (u16*)  alloc((size_t)M * FF * 2);
    // region R (64 MB): attn-phase buffers; later reused for mlpo partials
    char*  R    = alloc(64 * MB);
    u16*   h1   = (u16*)R;                 //  8 MB
    u16*   qk_b = (u16*)(R + 8 * MB);      // 16 MB  [4096][2048] Q|K
    u16*   vt_b = (u16*)(R + 24 * MB);     //  8 MB  [1024][4096] V^T (PV-permuted)
    u16*   Ob   = (u16*)(R + 32 * MB);     //  8 MB
    u16*   aoP  = (u16*)(R + 40 * MB);     // 16 MB  attn_out bf16 partials (2 planes)
    u16*   pscr = (u16*)R;                 // 32 MB  mlpo bf16 partials (4 planes) — after attn

    // all weight casts (one kernel)
    cast_all_k<<<8192, 256, 0, stream>>>(qkv_w, atto_w, mlpo_w, mlpi_w, mlpg_w,
                                         wq, wo, wm, wig);

    // attention branch
    ln_fwd_k<<<M, 256, 0, stream>>>(x, ln1_w, ln1_b, h1);
    gemm_qkvt_k<<<768, 256, 0, stream>>>(h1, wq, qk_b, vt_b);
    attn_fwd_k<<<512, 256, 0, stream>>>(qk_b, vt_b, Ob);
    // attn_out: split-K=2 bf16 partials (512 blocks = 2/CU)
    gemm_btsplit_k<<<dim3(C / 128, M / 128, 2), 256, 0, stream>>>(
        Ob, wo, aoP, C, C, C / 2, M * C);
    // fused residual+LN2: x1 = x + p0 + p1 ; h2 = LN(x1)
    ln_resid_k<<<M, 256, 0, stream>>>(x, aoP, ln2_w, ln2_b, x1, h2, M * C);

    // MLP branch
    gemm256_k<2><<<dim3((2 * FF / 256) * (M / 256), 1, 1), 512, 0, stream>>>(
        h2, wig, ab, C, C, C, 2 * FF / 256, 8, FF, 0);
    gemm256_k<1><<<dim3((C / 256) * (M / 256), 1, 4), 512, 0, stream>>>(
        ab, wm, pscr, FF, FF, FF / 4, C / 256, 4, C, M * C);
    addreduce4_k<<<2048, 256, 0, stream>>>(x1, pscr, out, M * C / 4, M * C);
}